// Round 3
// baseline (4718.760 us; speedup 1.0000x reference)
//
#include <hip/hip_runtime.h>

#define NPART_MAX 2048

typedef __attribute__((ext_vector_type(8))) short short8;
typedef __attribute__((ext_vector_type(4))) float f32x4;

__device__ __forceinline__ float bf2f(uint u) {
    union { uint u; float f; } v; v.u = u << 16; return v.f;
}
__device__ __forceinline__ ushort f2bf(float f) {
    union { float f; uint u; } v; v.f = f;
    uint r = v.u + 0x7fffu + ((v.u >> 16) & 1u);
    return (ushort)(r >> 16);
}

// ---------------- phase 0: counting sort by dst ----------------
__global__ __launch_bounds__(256) void hist_kernel(const int* __restrict__ dst, int E,
                                                   int* __restrict__ cnt) {
    for (int e = blockIdx.x * 256 + threadIdx.x; e < E; e += gridDim.x * 256)
        atomicAdd(&cnt[dst[e]], 1);
}

// single-block exclusive scan: off[0..n] and cursor copy
__global__ __launch_bounds__(256) void scan_kernel(const int* __restrict__ cnt, int n,
                                                   int* __restrict__ off, int* __restrict__ cursor) {
    __shared__ int warpsums[4];
    __shared__ int s_carry;
    if (threadIdx.x == 0) s_carry = 0;
    __syncthreads();
    for (int base = 0; base < n; base += 256) {
        int i = base + threadIdx.x;
        int v = (i < n) ? cnt[i] : 0;
        int lane = threadIdx.x & 63, w = threadIdx.x >> 6;
        int x = v;
        for (int d = 1; d < 64; d <<= 1) {
            int y = __shfl_up(x, d);
            if (lane >= d) x += y;
        }
        if (lane == 63) warpsums[w] = x;
        __syncthreads();
        int woff = 0;
        for (int k = 0; k < w; ++k) woff += warpsums[k];
        int incl = x + woff + s_carry;
        int excl = incl - v;
        if (i < n) { off[i] = excl; cursor[i] = excl; }
        __syncthreads();
        if (threadIdx.x == 255) s_carry = incl;
        __syncthreads();
    }
    if (threadIdx.x == 0) off[n] = s_carry;
}

__global__ __launch_bounds__(256) void scatter_kernel(const int* __restrict__ src,
                                                      const int* __restrict__ dst, int E,
                                                      int* __restrict__ cursor,
                                                      int* __restrict__ perm,
                                                      int* __restrict__ ssrc,
                                                      int* __restrict__ sdst) {
    for (int e = blockIdx.x * 256 + threadIdx.x; e < E; e += gridDim.x * 256) {
        int d = dst[e];
        int p = atomicAdd(&cursor[d], 1);
        perm[p] = e;
        ssrc[p] = src[e];
        sdst[p] = d;
    }
}

// ---------------- column stats partials ----------------
__global__ __launch_bounds__(256) void colstats_f32_128(const float* __restrict__ x, int M,
                                                        float* __restrict__ psum, float* __restrict__ psq) {
    int c = threadIdx.x & 127, sub = threadIdx.x >> 7;
    float s = 0.f, q = 0.f;
    for (int r = blockIdx.x * 2 + sub; r < M; r += gridDim.x * 2) {
        float v = x[(size_t)r * 128 + c];
        s += v; q += v * v;
    }
    __shared__ float ss[256], qs[256];
    ss[threadIdx.x] = s; qs[threadIdx.x] = q;
    __syncthreads();
    if (sub == 0) {
        s += ss[threadIdx.x + 128]; q += qs[threadIdx.x + 128];
        psum[blockIdx.x * 128 + c] = s;
        psq [blockIdx.x * 128 + c] = q;
    }
}

template<int C>
__global__ __launch_bounds__(256) void colstats_bf16_direct(const ushort* __restrict__ x, int M,
                                                            float* __restrict__ psum, float* __restrict__ psq) {
    if constexpr (C == 128) {
        int c = threadIdx.x & 127, sub = threadIdx.x >> 7;
        float s = 0.f, q = 0.f;
        for (int r = blockIdx.x * 2 + sub; r < M; r += gridDim.x * 2) {
            float v = bf2f(x[(size_t)r * 128 + c]);
            s += v; q += v * v;
        }
        __shared__ float ss[256], qs[256];
        ss[threadIdx.x] = s; qs[threadIdx.x] = q;
        __syncthreads();
        if (sub == 0) {
            s += ss[threadIdx.x + 128]; q += qs[threadIdx.x + 128];
            psum[blockIdx.x * 128 + c] = s;
            psq [blockIdx.x * 128 + c] = q;
        }
    } else {
        int c = threadIdx.x;
        float s = 0.f, q = 0.f;
        for (int r = blockIdx.x; r < M; r += gridDim.x) {
            float v = bf2f(x[(size_t)r * C + c]);
            s += v; q += v * v;
        }
        psum[blockIdx.x * C + c] = s;
        psq [blockIdx.x * C + c] = q;
    }
}

// wave-per-edge gather stats: lane reads bf16x2 (uint) -> columns 2*lane, 2*lane+1
__global__ __launch_bounds__(256) void colstats_gather2(const uint* __restrict__ hu2,
                                                        const uint* __restrict__ hv2,
                                                        const int* __restrict__ sidx,
                                                        const int* __restrict__ didx, int E,
                                                        float* __restrict__ psum, float* __restrict__ psq) {
    const int lane = threadIdx.x & 63;
    const int w = threadIdx.x >> 6;
    const int gwave = (blockIdx.x * 256 + threadIdx.x) >> 6;
    const int nwave = (gridDim.x * 256) >> 6;
    float s0 = 0.f, s1 = 0.f, q0 = 0.f, q1 = 0.f;
    for (int base = gwave * 64; base < E; base += nwave * 64) {
        int e = base + lane;
        int su = (e < E) ? sidx[e] : 0;
        int dv = (e < E) ? didx[e] : 0;
        int cnt = min(64, E - base);
        #pragma unroll 4
        for (int j = 0; j < cnt; ++j) {
            int a = __shfl(su, j), b = __shfl(dv, j);
            uint uu = hu2[(size_t)a * 64 + lane];
            uint vv = hv2[(size_t)b * 64 + lane];
            float v0 = bf2f(uu & 0xffffu) + bf2f(vv & 0xffffu);
            float v1 = bf2f(uu >> 16) + bf2f(vv >> 16);
            s0 += v0; q0 += v0 * v0;
            s1 += v1; q1 += v1 * v1;
        }
    }
    __shared__ float red[4][64][4];
    red[w][lane][0] = s0; red[w][lane][1] = s1;
    red[w][lane][2] = q0; red[w][lane][3] = q1;
    __syncthreads();
    if (w == 0) {
        #pragma unroll
        for (int k = 1; k < 4; ++k) {
            s0 += red[k][lane][0]; s1 += red[k][lane][1];
            q0 += red[k][lane][2]; q1 += red[k][lane][3];
        }
        psum[blockIdx.x * 128 + 2 * lane]     = s0;
        psum[blockIdx.x * 128 + 2 * lane + 1] = s1;
        psq [blockIdx.x * 128 + 2 * lane]     = q0;
        psq [blockIdx.x * 128 + 2 * lane + 1] = q1;
    }
}

// ---------------- stats finalize + BN fold + MFMA-fragment pack (single block) ----------------
// Wpack[((dt*KT + kt)*64 + lane)*8 + i] = bf16( Weff[kt*32 + (lane>>4)*8 + i][dt*16 + (lane&15)] )
__global__ __launch_bounds__(256) void finalize_fold(
    const float* __restrict__ psum, const float* __restrict__ psq, int nblk, int M, int C,
    const float* __restrict__ W, const float* __restrict__ bias,
    const float* __restrict__ g, const float* __restrict__ b,
    ushort* __restrict__ Wp, float* __restrict__ beff) {
    __shared__ float sscale[256];   // rstd*g
    __shared__ float sshift[256];   // b - mean*rstd*g
    int c = threadIdx.x;
    if (c < C) {
        double s = 0.0, q = 0.0;
        for (int i = 0; i < nblk; ++i) {
            s += (double)psum[(size_t)i * C + c];
            q += (double)psq [(size_t)i * C + c];
        }
        double m = s / M;
        double v = q / M - m * m;
        if (v < 0.0) v = 0.0;
        float rs = (float)(1.0 / sqrt(v + 1e-5));
        float sc = rs * g[c];
        sscale[c] = sc;
        sshift[c] = b[c] - (float)m * sc;
    }
    __syncthreads();
    const int KT = C / 32;
    const int total = 8 * KT * 64;
    for (int f = threadIdx.x; f < total; f += 256) {
        int lane = f & 63;
        int t = f >> 6;
        int kt = t % KT, dt = t / KT;
        int d = dt * 16 + (lane & 15);
        int kb = kt * 32 + (lane >> 4) * 8;
        uint4 o;
        uint w0, w1;
        w0 = (uint)f2bf(W[(size_t)(kb+0)*128 + d] * sscale[kb+0]);
        w1 = (uint)f2bf(W[(size_t)(kb+1)*128 + d] * sscale[kb+1]);
        o.x = w0 | (w1 << 16);
        w0 = (uint)f2bf(W[(size_t)(kb+2)*128 + d] * sscale[kb+2]);
        w1 = (uint)f2bf(W[(size_t)(kb+3)*128 + d] * sscale[kb+3]);
        o.y = w0 | (w1 << 16);
        w0 = (uint)f2bf(W[(size_t)(kb+4)*128 + d] * sscale[kb+4]);
        w1 = (uint)f2bf(W[(size_t)(kb+5)*128 + d] * sscale[kb+5]);
        o.z = w0 | (w1 << 16);
        w0 = (uint)f2bf(W[(size_t)(kb+6)*128 + d] * sscale[kb+6]);
        w1 = (uint)f2bf(W[(size_t)(kb+7)*128 + d] * sscale[kb+7]);
        o.w = w0 | (w1 << 16);
        *(uint4*)(Wp + (size_t)f * 8) = o;
    }
    if (threadIdx.x < 128) {
        int d = threadIdx.x;
        float a = bias[d];
        for (int cc = 0; cc < C; ++cc) a += sshift[cc] * W[(size_t)cc * 128 + d];
        beff[d] = a;
    }
}

// ---------------- MFMA GEMM: Y[row][d] = relu( X[row] @ Weff + beff ) ----------------
template<int KT, bool TWO, bool PERMF32, bool OUTF32>
__global__ __launch_bounds__(256) void gemm_mfma(
    const ushort* __restrict__ X1, const ushort* __restrict__ X2,
    const float* __restrict__ XF,
    const int* __restrict__ g1, const int* __restrict__ g2,
    const ushort* __restrict__ Wp, const float* __restrict__ beff,
    ushort* __restrict__ Yb, float* __restrict__ Yf, int M) {
    constexpr int K = KT * 32;
    const int lane = threadIdx.x & 63;
    const int w = threadIdx.x >> 6;
    const int r0 = blockIdx.x * 128 + w * 32;
    const int rlo = lane & 15, khi = lane >> 4;

    f32x4 acc[2][8];
    #pragma unroll
    for (int rt = 0; rt < 2; ++rt)
        #pragma unroll
        for (int dt = 0; dt < 8; ++dt)
            acc[rt][dt] = (f32x4){0.f, 0.f, 0.f, 0.f};

    int row[2], idx1[2], idx2[2];
    bool ok[2];
    #pragma unroll
    for (int rt = 0; rt < 2; ++rt) {
        row[rt] = r0 + rt * 16 + rlo;
        ok[rt] = row[rt] < M;
        int rr = ok[rt] ? row[rt] : 0;
        idx1[rt] = g1 ? g1[rr] : rr;
        if constexpr (TWO) idx2[rt] = g2[rr];
    }

    for (int kt = 0; kt < KT; ++kt) {
        short8 wf[8];
        #pragma unroll
        for (int dt = 0; dt < 8; ++dt)
            wf[dt] = *(const short8*)(Wp + (size_t)((dt * KT + kt) * 64 + lane) * 8);
        #pragma unroll
        for (int rt = 0; rt < 2; ++rt) {
            short8 bv;
            if constexpr (PERMF32) {
                const float* p = XF + (size_t)idx1[rt] * K + kt * 32 + khi * 8;
                float4 xa = *(const float4*)(p);
                float4 xb = *(const float4*)(p + 4);
                bv[0] = (short)f2bf(xa.x); bv[1] = (short)f2bf(xa.y);
                bv[2] = (short)f2bf(xa.z); bv[3] = (short)f2bf(xa.w);
                bv[4] = (short)f2bf(xb.x); bv[5] = (short)f2bf(xb.y);
                bv[6] = (short)f2bf(xb.z); bv[7] = (short)f2bf(xb.w);
            } else {
                bv = *(const short8*)(X1 + (size_t)idx1[rt] * K + kt * 32 + khi * 8);
            }
            #pragma unroll
            for (int dt = 0; dt < 8; ++dt)
                acc[rt][dt] = __builtin_amdgcn_mfma_f32_16x16x32_bf16(wf[dt], bv, acc[rt][dt], 0, 0, 0);
            if constexpr (TWO) {
                short8 bv2 = *(const short8*)(X2 + (size_t)idx2[rt] * K + kt * 32 + khi * 8);
                #pragma unroll
                for (int dt = 0; dt < 8; ++dt)
                    acc[rt][dt] = __builtin_amdgcn_mfma_f32_16x16x32_bf16(wf[dt], bv2, acc[rt][dt], 0, 0, 0);
            }
        }
    }

    #pragma unroll
    for (int rt = 0; rt < 2; ++rt) {
        if (!ok[rt]) continue;
        #pragma unroll
        for (int dt = 0; dt < 8; ++dt) {
            const float4 bz = *(const float4*)(beff + dt * 16 + khi * 4);
            float v0 = fmaxf(acc[rt][dt][0] + bz.x, 0.f);
            float v1 = fmaxf(acc[rt][dt][1] + bz.y, 0.f);
            float v2 = fmaxf(acc[rt][dt][2] + bz.z, 0.f);
            float v3 = fmaxf(acc[rt][dt][3] + bz.w, 0.f);
            if constexpr (OUTF32) {
                *(float4*)(Yf + (size_t)row[rt] * 128 + dt * 16 + khi * 4) = make_float4(v0, v1, v2, v3);
            } else {
                uint2 pk;
                pk.x = (uint)f2bf(v0) | ((uint)f2bf(v1) << 16);
                pk.y = (uint)f2bf(v2) | ((uint)f2bf(v3) << 16);
                *(uint2*)(Yb + (size_t)row[rt] * 128 + dt * 16 + khi * 4) = pk;
            }
        }
    }
}

// ---------------- segmented mean over sorted runs; 64 lanes per node ----------------
template<bool FIRST>
__global__ __launch_bounds__(256) void reduce_half(
    const uint* __restrict__ Y2, const int* __restrict__ off,
    float2* __restrict__ hacc, uint* __restrict__ h2, uint* __restrict__ fh2,
    int fhsel, int N) {
    int lane = threadIdx.x & 63;
    int nn = blockIdx.x * 4 + (threadIdx.x >> 6);
    if (nn >= N) return;
    int a = off[nn], b = off[nn + 1];
    float s0 = 0.f, s1 = 0.f;
    for (int r = a; r < b; ++r) {
        uint u = Y2[(size_t)r * 64 + lane];
        s0 += bf2f(u & 0xffffu);
        s1 += bf2f(u >> 16);
    }
    float inv = 0.5f / fmaxf((float)(b - a), 1.f);
    s0 *= inv; s1 *= inv;
    if constexpr (FIRST) {
        hacc[(size_t)nn * 64 + lane] = make_float2(s0, s1);
    } else {
        float2 p = hacc[(size_t)nn * 64 + lane];
        float v0 = p.x + s0, v1 = p.y + s1;
        uint pk = (uint)f2bf(v0) | ((uint)f2bf(v1) << 16);
        h2[(size_t)nn * 64 + lane] = pk;
        if (fhsel >= 0) fh2[(size_t)nn * 128 + fhsel * 64 + lane] = pk;
    }
}

// ---------------- launch ----------------
extern "C" void kernel_launch(void* const* d_in, const int* in_sizes, int n_in,
                              void* d_out, int out_size, void* d_ws, size_t ws_size,
                              hipStream_t stream) {
    const float* win_f  = (const float*)d_in[0];
    const float* loss_f = (const float*)d_in[1];
    struct BP { const float *g, *b, *W, *bias; };
    auto bp = [&](int i) { return BP{ (const float*)d_in[i], (const float*)d_in[i+1],
                                      (const float*)d_in[i+2], (const float*)d_in[i+3] }; };
    BP wi = bp(2), li = bp(6), srcp = bp(10), dstp = bp(14), wl = bp(18), ll = bp(22), outp = bp(26);
    const int* win_src  = (const int*)d_in[30];
    const int* win_dst  = (const int*)d_in[31];
    const int* loss_src = (const int*)d_in[32];
    const int* loss_dst = (const int*)d_in[33];
    const int E = in_sizes[30];
    const int N = out_size / 128;
    (void)n_in;

    char* base = (char*)d_ws;
    size_t off_b = 0;
    auto alloc = [&](size_t bytes) {
        size_t cur = off_b;
        off_b += (bytes + 255) & ~(size_t)255;
        return (void*)(base + cur);
    };
    ushort* Y    = (ushort*)alloc((size_t)E * 128 * 2);
    float2* hacc = (float2*)alloc((size_t)N * 64 * 8);
    ushort* h    = (ushort*)alloc((size_t)N * 128 * 2);
    ushort* hu   = (ushort*)alloc((size_t)N * 128 * 2);
    ushort* hv   = (ushort*)alloc((size_t)N * 128 * 2);
    ushort* fh   = (ushort*)alloc((size_t)N * 256 * 2);
    int* cntw  = (int*)alloc((size_t)N * 4);
    int* cntl  = (int*)alloc((size_t)N * 4);
    int* offw  = (int*)alloc((size_t)(N + 1) * 4);
    int* offl  = (int*)alloc((size_t)(N + 1) * 4);
    int* curw  = (int*)alloc((size_t)N * 4);
    int* curl  = (int*)alloc((size_t)N * 4);
    int* permw = (int*)alloc((size_t)E * 4);
    int* ssrcw = (int*)alloc((size_t)E * 4);
    int* sdstw = (int*)alloc((size_t)E * 4);
    int* perml = (int*)alloc((size_t)E * 4);
    int* ssrcl = (int*)alloc((size_t)E * 4);
    int* sdstl = (int*)alloc((size_t)E * 4);
    float* psum = (float*)alloc((size_t)NPART_MAX * 256 * 4);
    float* psq  = (float*)alloc((size_t)NPART_MAX * 256 * 4);
    ushort* Wp  = (ushort*)alloc((size_t)256 * 128 * 2);
    float* beff = (float*)alloc(128 * 4);
    if (off_b > ws_size) return;

    const int gE = (E + 127) / 128;
    const int gN = (N + 127) / 128;
    const int gR = (N + 3) / 4;
    const int NBF = 1024;   // fp32 edge-stats partial blocks
    const int NBG = 1024;   // gather-stats partial blocks
    const int NBN = 512;    // node-stats partial blocks

    // phase 0: counting sort per etype
    hipMemsetAsync(cntw, 0, (size_t)N * 4, stream);
    hipMemsetAsync(cntl, 0, (size_t)N * 4, stream);
    hist_kernel<<<1024, 256, 0, stream>>>(win_dst,  E, cntw);
    hist_kernel<<<1024, 256, 0, stream>>>(loss_dst, E, cntl);
    scan_kernel<<<1, 256, 0, stream>>>(cntw, N, offw, curw);
    scan_kernel<<<1, 256, 0, stream>>>(cntl, N, offl, curl);
    scatter_kernel<<<1024, 256, 0, stream>>>(win_src,  win_dst,  E, curw, permw, ssrcw, sdstw);
    scatter_kernel<<<1024, 256, 0, stream>>>(loss_src, loss_dst, E, curl, perml, ssrcl, sdstl);

    // initial edge blocks
    colstats_f32_128<<<NBF, 256, 0, stream>>>(win_f, E, psum, psq);
    finalize_fold<<<1, 256, 0, stream>>>(psum, psq, NBF, E, 128, wi.W, wi.bias, wi.g, wi.b, Wp, beff);
    gemm_mfma<4, false, true, false><<<gE, 256, 0, stream>>>(
        nullptr, nullptr, win_f, permw, nullptr, Wp, beff, Y, nullptr, E);
    reduce_half<true><<<gR, 256, 0, stream>>>((const uint*)Y, offw, hacc, nullptr, nullptr, -1, N);

    colstats_f32_128<<<NBF, 256, 0, stream>>>(loss_f, E, psum, psq);
    finalize_fold<<<1, 256, 0, stream>>>(psum, psq, NBF, E, 128, li.W, li.bias, li.g, li.b, Wp, beff);
    gemm_mfma<4, false, true, false><<<gE, 256, 0, stream>>>(
        nullptr, nullptr, loss_f, perml, nullptr, Wp, beff, Y, nullptr, E);
    reduce_half<false><<<gR, 256, 0, stream>>>((const uint*)Y, offl, hacc, (uint*)h, (uint*)fh, 0, N);

    for (int it = 0; it < 3; ++it) {
        colstats_bf16_direct<128><<<NBN, 256, 0, stream>>>(h, N, psum, psq);
        finalize_fold<<<1, 256, 0, stream>>>(psum, psq, NBN, N, 128, srcp.W, srcp.bias, srcp.g, srcp.b, Wp, beff);
        gemm_mfma<4, false, false, false><<<gN, 256, 0, stream>>>(
            h, nullptr, nullptr, nullptr, nullptr, Wp, beff, hu, nullptr, N);
        finalize_fold<<<1, 256, 0, stream>>>(psum, psq, NBN, N, 128, dstp.W, dstp.bias, dstp.g, dstp.b, Wp, beff);
        gemm_mfma<4, false, false, false><<<gN, 256, 0, stream>>>(
            h, nullptr, nullptr, nullptr, nullptr, Wp, beff, hv, nullptr, N);

        colstats_gather2<<<NBG, 256, 0, stream>>>((const uint*)hu, (const uint*)hv,
                                                  win_src, win_dst, E, psum, psq);
        finalize_fold<<<1, 256, 0, stream>>>(psum, psq, NBG, E, 128, wl.W, wl.bias, wl.g, wl.b, Wp, beff);
        gemm_mfma<4, true, false, false><<<gE, 256, 0, stream>>>(
            hu, hv, nullptr, ssrcw, sdstw, Wp, beff, Y, nullptr, E);
        reduce_half<true><<<gR, 256, 0, stream>>>((const uint*)Y, offw, hacc, nullptr, nullptr, -1, N);

        colstats_gather2<<<NBG, 256, 0, stream>>>((const uint*)hu, (const uint*)hv,
                                                  loss_src, loss_dst, E, psum, psq);
        finalize_fold<<<1, 256, 0, stream>>>(psum, psq, NBG, E, 128, ll.W, ll.bias, ll.g, ll.b, Wp, beff);
        gemm_mfma<4, true, false, false><<<gE, 256, 0, stream>>>(
            hu, hv, nullptr, ssrcl, sdstl, Wp, beff, Y, nullptr, E);
        reduce_half<false><<<gR, 256, 0, stream>>>((const uint*)Y, offl, hacc, (uint*)h, (uint*)fh,
                                                   (it == 2) ? 1 : -1, N);
    }

    colstats_bf16_direct<256><<<NBN, 256, 0, stream>>>(fh, N, psum, psq);
    finalize_fold<<<1, 256, 0, stream>>>(psum, psq, NBN, N, 256, outp.W, outp.bias, outp.g, outp.b, Wp, beff);
    gemm_mfma<8, false, false, true><<<gN, 256, 0, stream>>>(
        fh, nullptr, nullptr, nullptr, nullptr, Wp, beff, nullptr, (float*)d_out, N);
}

// Round 4
// 1556.693 us; speedup vs baseline: 3.0313x; 3.0313x over previous
//
#include <hip/hip_runtime.h>

#define NPART_MAX 2048

typedef __attribute__((ext_vector_type(8))) short short8;
typedef __attribute__((ext_vector_type(4))) float f32x4;

__device__ __forceinline__ float bf2f(uint u) {
    union { uint u; float f; } v; v.u = u << 16; return v.f;
}
__device__ __forceinline__ ushort f2bf(float f) {
    union { float f; uint u; } v; v.f = f;
    uint r = v.u + 0x7fffu + ((v.u >> 16) & 1u);
    return (ushort)(r >> 16);
}

// ---------------- phase 0: counting sort by dst ----------------
__global__ __launch_bounds__(256) void hist_kernel(const int* __restrict__ dst, int E,
                                                   int* __restrict__ cnt) {
    for (int e = blockIdx.x * 256 + threadIdx.x; e < E; e += gridDim.x * 256)
        atomicAdd(&cnt[dst[e]], 1);
}

// single-block exclusive scan: off[0..n] and cursor copy
__global__ __launch_bounds__(256) void scan_kernel(const int* __restrict__ cnt, int n,
                                                   int* __restrict__ off, int* __restrict__ cursor) {
    __shared__ int warpsums[4];
    __shared__ int s_carry;
    if (threadIdx.x == 0) s_carry = 0;
    __syncthreads();
    for (int base = 0; base < n; base += 256) {
        int i = base + threadIdx.x;
        int v = (i < n) ? cnt[i] : 0;
        int lane = threadIdx.x & 63, w = threadIdx.x >> 6;
        int x = v;
        for (int d = 1; d < 64; d <<= 1) {
            int y = __shfl_up(x, d);
            if (lane >= d) x += y;
        }
        if (lane == 63) warpsums[w] = x;
        __syncthreads();
        int woff = 0;
        for (int k = 0; k < w; ++k) woff += warpsums[k];
        int incl = x + woff + s_carry;
        int excl = incl - v;
        if (i < n) { off[i] = excl; cursor[i] = excl; }
        __syncthreads();
        if (threadIdx.x == 255) s_carry = incl;
        __syncthreads();
    }
    if (threadIdx.x == 0) off[n] = s_carry;
}

__global__ __launch_bounds__(256) void scatter_kernel(const int* __restrict__ src,
                                                      const int* __restrict__ dst, int E,
                                                      int* __restrict__ cursor,
                                                      int* __restrict__ perm,
                                                      int* __restrict__ ssrc,
                                                      int* __restrict__ sdst) {
    for (int e = blockIdx.x * 256 + threadIdx.x; e < E; e += gridDim.x * 256) {
        int d = dst[e];
        int p = atomicAdd(&cursor[d], 1);
        perm[p] = e;
        ssrc[p] = src[e];
        sdst[p] = d;
    }
}

// ---------------- column stats partials ----------------
__global__ __launch_bounds__(256) void colstats_f32_128(const float* __restrict__ x, int M,
                                                        float* __restrict__ psum, float* __restrict__ psq) {
    int c = threadIdx.x & 127, sub = threadIdx.x >> 7;
    float s = 0.f, q = 0.f;
    for (int r = blockIdx.x * 2 + sub; r < M; r += gridDim.x * 2) {
        float v = x[(size_t)r * 128 + c];
        s += v; q += v * v;
    }
    __shared__ float ss[256], qs[256];
    ss[threadIdx.x] = s; qs[threadIdx.x] = q;
    __syncthreads();
    if (sub == 0) {
        s += ss[threadIdx.x + 128]; q += qs[threadIdx.x + 128];
        psum[blockIdx.x * 128 + c] = s;
        psq [blockIdx.x * 128 + c] = q;
    }
}

template<int C>
__global__ __launch_bounds__(256) void colstats_bf16_direct(const ushort* __restrict__ x, int M,
                                                            float* __restrict__ psum, float* __restrict__ psq) {
    if constexpr (C == 128) {
        int c = threadIdx.x & 127, sub = threadIdx.x >> 7;
        float s = 0.f, q = 0.f;
        for (int r = blockIdx.x * 2 + sub; r < M; r += gridDim.x * 2) {
            float v = bf2f(x[(size_t)r * 128 + c]);
            s += v; q += v * v;
        }
        __shared__ float ss[256], qs[256];
        ss[threadIdx.x] = s; qs[threadIdx.x] = q;
        __syncthreads();
        if (sub == 0) {
            s += ss[threadIdx.x + 128]; q += qs[threadIdx.x + 128];
            psum[blockIdx.x * 128 + c] = s;
            psq [blockIdx.x * 128 + c] = q;
        }
    } else {
        int c = threadIdx.x;
        float s = 0.f, q = 0.f;
        for (int r = blockIdx.x; r < M; r += gridDim.x) {
            float v = bf2f(x[(size_t)r * C + c]);
            s += v; q += v * v;
        }
        psum[blockIdx.x * C + c] = s;
        psq [blockIdx.x * C + c] = q;
    }
}

// wave-per-edge gather stats: lane reads bf16x2 (uint) -> columns 2*lane, 2*lane+1
__global__ __launch_bounds__(256) void colstats_gather2(const uint* __restrict__ hu2,
                                                        const uint* __restrict__ hv2,
                                                        const int* __restrict__ sidx,
                                                        const int* __restrict__ didx, int E,
                                                        float* __restrict__ psum, float* __restrict__ psq) {
    const int lane = threadIdx.x & 63;
    const int w = threadIdx.x >> 6;
    const int gwave = (blockIdx.x * 256 + threadIdx.x) >> 6;
    const int nwave = (gridDim.x * 256) >> 6;
    float s0 = 0.f, s1 = 0.f, q0 = 0.f, q1 = 0.f;
    for (int base = gwave * 64; base < E; base += nwave * 64) {
        int e = base + lane;
        int su = (e < E) ? sidx[e] : 0;
        int dv = (e < E) ? didx[e] : 0;
        int cnt = min(64, E - base);
        #pragma unroll 4
        for (int j = 0; j < cnt; ++j) {
            int a = __shfl(su, j), b = __shfl(dv, j);
            uint uu = hu2[(size_t)a * 64 + lane];
            uint vv = hv2[(size_t)b * 64 + lane];
            float v0 = bf2f(uu & 0xffffu) + bf2f(vv & 0xffffu);
            float v1 = bf2f(uu >> 16) + bf2f(vv >> 16);
            s0 += v0; q0 += v0 * v0;
            s1 += v1; q1 += v1 * v1;
        }
    }
    __shared__ float red[4][64][4];
    red[w][lane][0] = s0; red[w][lane][1] = s1;
    red[w][lane][2] = q0; red[w][lane][3] = q1;
    __syncthreads();
    if (w == 0) {
        #pragma unroll
        for (int k = 1; k < 4; ++k) {
            s0 += red[k][lane][0]; s1 += red[k][lane][1];
            q0 += red[k][lane][2]; q1 += red[k][lane][3];
        }
        psum[blockIdx.x * 128 + 2 * lane]     = s0;
        psum[blockIdx.x * 128 + 2 * lane + 1] = s1;
        psq [blockIdx.x * 128 + 2 * lane]     = q0;
        psq [blockIdx.x * 128 + 2 * lane + 1] = q1;
    }
}

// ---------------- stage 2: per-column reduce of partials -> scale/shift ----------------
__global__ __launch_bounds__(256) void reduce_stats(
    const float* __restrict__ psum, const float* __restrict__ psq,
    int nblk, int C, int M,
    const float* __restrict__ g, const float* __restrict__ b,
    float* __restrict__ scale, float* __restrict__ shift) {
    const int c = blockIdx.x;
    float s = 0.f, q = 0.f;
    for (int i = threadIdx.x; i < nblk; i += 256) {
        s += psum[(size_t)i * C + c];
        q += psq [(size_t)i * C + c];
    }
    __shared__ float ss[256], qs[256];
    ss[threadIdx.x] = s; qs[threadIdx.x] = q;
    __syncthreads();
    for (int d = 128; d > 0; d >>= 1) {
        if (threadIdx.x < d) {
            ss[threadIdx.x] += ss[threadIdx.x + d];
            qs[threadIdx.x] += qs[threadIdx.x + d];
        }
        __syncthreads();
    }
    if (threadIdx.x == 0) {
        float m = ss[0] / (float)M;
        float v = qs[0] / (float)M - m * m;
        v = fmaxf(v, 0.f);
        float rs = 1.f / sqrtf(v + 1e-5f);
        float sc = rs * g[c];
        scale[c] = sc;
        shift[c] = b[c] - m * sc;
    }
}

// ---------------- BN fold + MFMA-fragment pack (single block) ----------------
// Wpack[((dt*KT + kt)*64 + lane)*8 + i] = bf16( Weff[kt*32 + (lane>>4)*8 + i][dt*16 + (lane&15)] )
__global__ __launch_bounds__(256) void pack_fold(
    const float* __restrict__ scale, const float* __restrict__ shift, int C,
    const float* __restrict__ W, const float* __restrict__ bias,
    ushort* __restrict__ Wp, float* __restrict__ beff) {
    __shared__ float sscale[256];   // rstd*g
    __shared__ float sshift[256];   // b - mean*rstd*g
    if (threadIdx.x < C) {
        sscale[threadIdx.x] = scale[threadIdx.x];
        sshift[threadIdx.x] = shift[threadIdx.x];
    }
    __syncthreads();
    const int KT = C / 32;
    const int total = 8 * KT * 64;
    for (int f = threadIdx.x; f < total; f += 256) {
        int lane = f & 63;
        int t = f >> 6;
        int kt = t % KT, dt = t / KT;
        int d = dt * 16 + (lane & 15);
        int kb = kt * 32 + (lane >> 4) * 8;
        uint4 o;
        uint w0, w1;
        w0 = (uint)f2bf(W[(size_t)(kb+0)*128 + d] * sscale[kb+0]);
        w1 = (uint)f2bf(W[(size_t)(kb+1)*128 + d] * sscale[kb+1]);
        o.x = w0 | (w1 << 16);
        w0 = (uint)f2bf(W[(size_t)(kb+2)*128 + d] * sscale[kb+2]);
        w1 = (uint)f2bf(W[(size_t)(kb+3)*128 + d] * sscale[kb+3]);
        o.y = w0 | (w1 << 16);
        w0 = (uint)f2bf(W[(size_t)(kb+4)*128 + d] * sscale[kb+4]);
        w1 = (uint)f2bf(W[(size_t)(kb+5)*128 + d] * sscale[kb+5]);
        o.z = w0 | (w1 << 16);
        w0 = (uint)f2bf(W[(size_t)(kb+6)*128 + d] * sscale[kb+6]);
        w1 = (uint)f2bf(W[(size_t)(kb+7)*128 + d] * sscale[kb+7]);
        o.w = w0 | (w1 << 16);
        *(uint4*)(Wp + (size_t)f * 8) = o;
    }
    if (threadIdx.x < 128) {
        int d = threadIdx.x;
        float a = bias[d];
        for (int cc = 0; cc < C; ++cc) a += sshift[cc] * W[(size_t)cc * 128 + d];
        beff[d] = a;
    }
}

// ---------------- MFMA GEMM: Y[row][d] = relu( X[row] @ Weff + beff ) ----------------
template<int KT, bool TWO, bool PERMF32, bool OUTF32>
__global__ __launch_bounds__(256) void gemm_mfma(
    const ushort* __restrict__ X1, const ushort* __restrict__ X2,
    const float* __restrict__ XF,
    const int* __restrict__ g1, const int* __restrict__ g2,
    const ushort* __restrict__ Wp, const float* __restrict__ beff,
    ushort* __restrict__ Yb, float* __restrict__ Yf, int M) {
    constexpr int K = KT * 32;
    const int lane = threadIdx.x & 63;
    const int w = threadIdx.x >> 6;
    const int r0 = blockIdx.x * 128 + w * 32;
    const int rlo = lane & 15, khi = lane >> 4;

    f32x4 acc[2][8];
    #pragma unroll
    for (int rt = 0; rt < 2; ++rt)
        #pragma unroll
        for (int dt = 0; dt < 8; ++dt)
            acc[rt][dt] = (f32x4){0.f, 0.f, 0.f, 0.f};

    int row[2], idx1[2], idx2[2];
    bool ok[2];
    #pragma unroll
    for (int rt = 0; rt < 2; ++rt) {
        row[rt] = r0 + rt * 16 + rlo;
        ok[rt] = row[rt] < M;
        int rr = ok[rt] ? row[rt] : 0;
        idx1[rt] = g1 ? g1[rr] : rr;
        if constexpr (TWO) idx2[rt] = g2[rr];
    }

    for (int kt = 0; kt < KT; ++kt) {
        short8 wf[8];
        #pragma unroll
        for (int dt = 0; dt < 8; ++dt)
            wf[dt] = *(const short8*)(Wp + (size_t)((dt * KT + kt) * 64 + lane) * 8);
        #pragma unroll
        for (int rt = 0; rt < 2; ++rt) {
            short8 bv;
            if constexpr (PERMF32) {
                const float* p = XF + (size_t)idx1[rt] * K + kt * 32 + khi * 8;
                float4 xa = *(const float4*)(p);
                float4 xb = *(const float4*)(p + 4);
                bv[0] = (short)f2bf(xa.x); bv[1] = (short)f2bf(xa.y);
                bv[2] = (short)f2bf(xa.z); bv[3] = (short)f2bf(xa.w);
                bv[4] = (short)f2bf(xb.x); bv[5] = (short)f2bf(xb.y);
                bv[6] = (short)f2bf(xb.z); bv[7] = (short)f2bf(xb.w);
            } else {
                bv = *(const short8*)(X1 + (size_t)idx1[rt] * K + kt * 32 + khi * 8);
            }
            #pragma unroll
            for (int dt = 0; dt < 8; ++dt)
                acc[rt][dt] = __builtin_amdgcn_mfma_f32_16x16x32_bf16(wf[dt], bv, acc[rt][dt], 0, 0, 0);
            if constexpr (TWO) {
                short8 bv2 = *(const short8*)(X2 + (size_t)idx2[rt] * K + kt * 32 + khi * 8);
                #pragma unroll
                for (int dt = 0; dt < 8; ++dt)
                    acc[rt][dt] = __builtin_amdgcn_mfma_f32_16x16x32_bf16(wf[dt], bv2, acc[rt][dt], 0, 0, 0);
            }
        }
    }

    #pragma unroll
    for (int rt = 0; rt < 2; ++rt) {
        if (!ok[rt]) continue;
        #pragma unroll
        for (int dt = 0; dt < 8; ++dt) {
            const float4 bz = *(const float4*)(beff + dt * 16 + khi * 4);
            float v0 = fmaxf(acc[rt][dt][0] + bz.x, 0.f);
            float v1 = fmaxf(acc[rt][dt][1] + bz.y, 0.f);
            float v2 = fmaxf(acc[rt][dt][2] + bz.z, 0.f);
            float v3 = fmaxf(acc[rt][dt][3] + bz.w, 0.f);
            if constexpr (OUTF32) {
                *(float4*)(Yf + (size_t)row[rt] * 128 + dt * 16 + khi * 4) = make_float4(v0, v1, v2, v3);
            } else {
                uint2 pk;
                pk.x = (uint)f2bf(v0) | ((uint)f2bf(v1) << 16);
                pk.y = (uint)f2bf(v2) | ((uint)f2bf(v3) << 16);
                *(uint2*)(Yb + (size_t)row[rt] * 128 + dt * 16 + khi * 4) = pk;
            }
        }
    }
}

// ---------------- segmented mean over sorted runs; 64 lanes per node ----------------
template<bool FIRST>
__global__ __launch_bounds__(256) void reduce_half(
    const uint* __restrict__ Y2, const int* __restrict__ off,
    float2* __restrict__ hacc, uint* __restrict__ h2, uint* __restrict__ fh2,
    int fhsel, int N) {
    int lane = threadIdx.x & 63;
    int nn = blockIdx.x * 4 + (threadIdx.x >> 6);
    if (nn >= N) return;
    int a = off[nn], b = off[nn + 1];
    float s0 = 0.f, s1 = 0.f;
    for (int r = a; r < b; ++r) {
        uint u = Y2[(size_t)r * 64 + lane];
        s0 += bf2f(u & 0xffffu);
        s1 += bf2f(u >> 16);
    }
    float inv = 0.5f / fmaxf((float)(b - a), 1.f);
    s0 *= inv; s1 *= inv;
    if constexpr (FIRST) {
        hacc[(size_t)nn * 64 + lane] = make_float2(s0, s1);
    } else {
        float2 p = hacc[(size_t)nn * 64 + lane];
        float v0 = p.x + s0, v1 = p.y + s1;
        uint pk = (uint)f2bf(v0) | ((uint)f2bf(v1) << 16);
        h2[(size_t)nn * 64 + lane] = pk;
        if (fhsel >= 0) fh2[(size_t)nn * 128 + fhsel * 64 + lane] = pk;
    }
}

// ---------------- launch ----------------
extern "C" void kernel_launch(void* const* d_in, const int* in_sizes, int n_in,
                              void* d_out, int out_size, void* d_ws, size_t ws_size,
                              hipStream_t stream) {
    const float* win_f  = (const float*)d_in[0];
    const float* loss_f = (const float*)d_in[1];
    struct BP { const float *g, *b, *W, *bias; };
    auto bp = [&](int i) { return BP{ (const float*)d_in[i], (const float*)d_in[i+1],
                                      (const float*)d_in[i+2], (const float*)d_in[i+3] }; };
    BP wi = bp(2), li = bp(6), srcp = bp(10), dstp = bp(14), wl = bp(18), ll = bp(22), outp = bp(26);
    const int* win_src  = (const int*)d_in[30];
    const int* win_dst  = (const int*)d_in[31];
    const int* loss_src = (const int*)d_in[32];
    const int* loss_dst = (const int*)d_in[33];
    const int E = in_sizes[30];
    const int N = out_size / 128;
    (void)n_in;

    char* base = (char*)d_ws;
    size_t off_b = 0;
    auto alloc = [&](size_t bytes) {
        size_t cur = off_b;
        off_b += (bytes + 255) & ~(size_t)255;
        return (void*)(base + cur);
    };
    ushort* Y    = (ushort*)alloc((size_t)E * 128 * 2);
    float2* hacc = (float2*)alloc((size_t)N * 64 * 8);
    ushort* h    = (ushort*)alloc((size_t)N * 128 * 2);
    ushort* hu   = (ushort*)alloc((size_t)N * 128 * 2);
    ushort* hv   = (ushort*)alloc((size_t)N * 128 * 2);
    ushort* fh   = (ushort*)alloc((size_t)N * 256 * 2);
    int* cntw  = (int*)alloc((size_t)N * 4);
    int* cntl  = (int*)alloc((size_t)N * 4);
    int* offw  = (int*)alloc((size_t)(N + 1) * 4);
    int* offl  = (int*)alloc((size_t)(N + 1) * 4);
    int* curw  = (int*)alloc((size_t)N * 4);
    int* curl  = (int*)alloc((size_t)N * 4);
    int* permw = (int*)alloc((size_t)E * 4);
    int* ssrcw = (int*)alloc((size_t)E * 4);
    int* sdstw = (int*)alloc((size_t)E * 4);
    int* perml = (int*)alloc((size_t)E * 4);
    int* ssrcl = (int*)alloc((size_t)E * 4);
    int* sdstl = (int*)alloc((size_t)E * 4);
    float* psum = (float*)alloc((size_t)NPART_MAX * 256 * 4);
    float* psq  = (float*)alloc((size_t)NPART_MAX * 256 * 4);
    float* scal = (float*)alloc(256 * 4);
    float* shif = (float*)alloc(256 * 4);
    ushort* Wp  = (ushort*)alloc((size_t)256 * 128 * 2);
    float* beff = (float*)alloc(128 * 4);
    if (off_b > ws_size) return;

    const int gE = (E + 127) / 128;
    const int gN = (N + 127) / 128;
    const int gR = (N + 3) / 4;
    const int NBF = 1024;   // fp32 edge-stats partial blocks
    const int NBG = 1024;   // gather-stats partial blocks
    const int NBN = 512;    // node-stats partial blocks

    auto fold = [&](int nblk, int M, int C, const BP& p) {
        reduce_stats<<<C, 256, 0, stream>>>(psum, psq, nblk, C, M, p.g, p.b, scal, shif);
        pack_fold<<<1, 256, 0, stream>>>(scal, shif, C, p.W, p.bias, Wp, beff);
    };

    // phase 0: counting sort per etype
    hipMemsetAsync(cntw, 0, (size_t)N * 4, stream);
    hipMemsetAsync(cntl, 0, (size_t)N * 4, stream);
    hist_kernel<<<1024, 256, 0, stream>>>(win_dst,  E, cntw);
    hist_kernel<<<1024, 256, 0, stream>>>(loss_dst, E, cntl);
    scan_kernel<<<1, 256, 0, stream>>>(cntw, N, offw, curw);
    scan_kernel<<<1, 256, 0, stream>>>(cntl, N, offl, curl);
    scatter_kernel<<<1024, 256, 0, stream>>>(win_src,  win_dst,  E, curw, permw, ssrcw, sdstw);
    scatter_kernel<<<1024, 256, 0, stream>>>(loss_src, loss_dst, E, curl, perml, ssrcl, sdstl);

    // initial edge blocks
    colstats_f32_128<<<NBF, 256, 0, stream>>>(win_f, E, psum, psq);
    fold(NBF, E, 128, wi);
    gemm_mfma<4, false, true, false><<<gE, 256, 0, stream>>>(
        nullptr, nullptr, win_f, permw, nullptr, Wp, beff, Y, nullptr, E);
    reduce_half<true><<<gR, 256, 0, stream>>>((const uint*)Y, offw, hacc, nullptr, nullptr, -1, N);

    colstats_f32_128<<<NBF, 256, 0, stream>>>(loss_f, E, psum, psq);
    fold(NBF, E, 128, li);
    gemm_mfma<4, false, true, false><<<gE, 256, 0, stream>>>(
        nullptr, nullptr, loss_f, perml, nullptr, Wp, beff, Y, nullptr, E);
    reduce_half<false><<<gR, 256, 0, stream>>>((const uint*)Y, offl, hacc, (uint*)h, (uint*)fh, 0, N);

    for (int it = 0; it < 3; ++it) {
        colstats_bf16_direct<128><<<NBN, 256, 0, stream>>>(h, N, psum, psq);
        fold(NBN, N, 128, srcp);
        gemm_mfma<4, false, false, false><<<gN, 256, 0, stream>>>(
            h, nullptr, nullptr, nullptr, nullptr, Wp, beff, hu, nullptr, N);
        fold(NBN, N, 128, dstp);
        gemm_mfma<4, false, false, false><<<gN, 256, 0, stream>>>(
            h, nullptr, nullptr, nullptr, nullptr, Wp, beff, hv, nullptr, N);

        colstats_gather2<<<NBG, 256, 0, stream>>>((const uint*)hu, (const uint*)hv,
                                                  win_src, win_dst, E, psum, psq);
        fold(NBG, E, 128, wl);
        gemm_mfma<4, true, false, false><<<gE, 256, 0, stream>>>(
            hu, hv, nullptr, ssrcw, sdstw, Wp, beff, Y, nullptr, E);
        reduce_half<true><<<gR, 256, 0, stream>>>((const uint*)Y, offw, hacc, nullptr, nullptr, -1, N);

        colstats_gather2<<<NBG, 256, 0, stream>>>((const uint*)hu, (const uint*)hv,
                                                  loss_src, loss_dst, E, psum, psq);
        fold(NBG, E, 128, ll);
        gemm_mfma<4, true, false, false><<<gE, 256, 0, stream>>>(
            hu, hv, nullptr, ssrcl, sdstl, Wp, beff, Y, nullptr, E);
        reduce_half<false><<<gR, 256, 0, stream>>>((const uint*)Y, offl, hacc, (uint*)h, (uint*)fh,
                                                   (it == 2) ? 1 : -1, N);
    }

    colstats_bf16_direct<256><<<NBN, 256, 0, stream>>>(fh, N, psum, psq);
    fold(NBN, N, 256, outp);
    gemm_mfma<8, false, false, true><<<gN, 256, 0, stream>>>(
        fh, nullptr, nullptr, nullptr, nullptr, Wp, beff, nullptr, (float*)d_out, N);
}

// Round 5
// 1539.712 us; speedup vs baseline: 3.0647x; 1.0110x over previous
//
#include <hip/hip_runtime.h>

#define NPART_MAX 2048

typedef __attribute__((ext_vector_type(8))) short short8;
typedef __attribute__((ext_vector_type(4))) float f32x4;

__device__ __forceinline__ float bf2f(uint u) {
    union { uint u; float f; } v; v.u = u << 16; return v.f;
}
__device__ __forceinline__ ushort f2bf(float f) {
    union { float f; uint u; } v; v.f = f;
    uint r = v.u + 0x7fffu + ((v.u >> 16) & 1u);
    return (ushort)(r >> 16);
}

// ---------------- phase 0: counting sort by dst ----------------
__global__ __launch_bounds__(256) void hist_kernel(const int* __restrict__ dst, int E,
                                                   int* __restrict__ cnt) {
    for (int e = blockIdx.x * 256 + threadIdx.x; e < E; e += gridDim.x * 256)
        atomicAdd(&cnt[dst[e]], 1);
}

__global__ __launch_bounds__(256) void scan_kernel(const int* __restrict__ cnt, int n,
                                                   int* __restrict__ off, int* __restrict__ cursor) {
    __shared__ int warpsums[4];
    __shared__ int s_carry;
    if (threadIdx.x == 0) s_carry = 0;
    __syncthreads();
    for (int base = 0; base < n; base += 256) {
        int i = base + threadIdx.x;
        int v = (i < n) ? cnt[i] : 0;
        int lane = threadIdx.x & 63, w = threadIdx.x >> 6;
        int x = v;
        for (int d = 1; d < 64; d <<= 1) {
            int y = __shfl_up(x, d);
            if (lane >= d) x += y;
        }
        if (lane == 63) warpsums[w] = x;
        __syncthreads();
        int woff = 0;
        for (int k = 0; k < w; ++k) woff += warpsums[k];
        int incl = x + woff + s_carry;
        int excl = incl - v;
        if (i < n) { off[i] = excl; cursor[i] = excl; }
        __syncthreads();
        if (threadIdx.x == 255) s_carry = incl;
        __syncthreads();
    }
    if (threadIdx.x == 0) off[n] = s_carry;
}

__global__ __launch_bounds__(256) void scatter_kernel(const int* __restrict__ src,
                                                      const int* __restrict__ dst, int E,
                                                      int* __restrict__ cursor,
                                                      int* __restrict__ perm,
                                                      int* __restrict__ iperm,
                                                      int* __restrict__ ssrc,
                                                      int* __restrict__ sdst) {
    for (int e = blockIdx.x * 256 + threadIdx.x; e < E; e += gridDim.x * 256) {
        int d = dst[e];
        int p = atomicAdd(&cursor[d], 1);
        perm[p] = e;
        iperm[e] = p;
        ssrc[p] = src[e];
        sdst[p] = d;
    }
}

// ---------------- fused fp32 col-stats + bf16 convert into sorted slots ----------------
__global__ __launch_bounds__(256) void convert_stats_f32(
    const float4* __restrict__ x4, const int* __restrict__ iperm, int M,
    uint2* __restrict__ xb4, float* __restrict__ psum, float* __restrict__ psq) {
    const int cg = threadIdx.x & 31;    // col group of 4
    const int sub = threadIdx.x >> 5;   // 0..7 row sub-stream
    float s0=0,s1=0,s2=0,s3=0,q0=0,q1=0,q2=0,q3=0;
    for (int r = blockIdx.x * 8 + sub; r < M; r += gridDim.x * 8) {
        float4 v = x4[(size_t)r * 32 + cg];
        int p = iperm[r];
        uint2 o;
        o.x = (uint)f2bf(v.x) | ((uint)f2bf(v.y) << 16);
        o.y = (uint)f2bf(v.z) | ((uint)f2bf(v.w) << 16);
        xb4[(size_t)p * 32 + cg] = o;
        s0 += v.x; q0 += v.x * v.x;
        s1 += v.y; q1 += v.y * v.y;
        s2 += v.z; q2 += v.z * v.z;
        s3 += v.w; q3 += v.w * v.w;
    }
    __shared__ float rs[256][4], rq[256][4];
    rs[threadIdx.x][0]=s0; rs[threadIdx.x][1]=s1; rs[threadIdx.x][2]=s2; rs[threadIdx.x][3]=s3;
    rq[threadIdx.x][0]=q0; rq[threadIdx.x][1]=q1; rq[threadIdx.x][2]=q2; rq[threadIdx.x][3]=q3;
    __syncthreads();
    if (sub == 0) {
        #pragma unroll
        for (int k = 1; k < 8; ++k) {
            s0 += rs[k*32+cg][0]; s1 += rs[k*32+cg][1];
            s2 += rs[k*32+cg][2]; s3 += rs[k*32+cg][3];
            q0 += rq[k*32+cg][0]; q1 += rq[k*32+cg][1];
            q2 += rq[k*32+cg][2]; q3 += rq[k*32+cg][3];
        }
        psum[blockIdx.x*128 + cg*4+0] = s0; psq[blockIdx.x*128 + cg*4+0] = q0;
        psum[blockIdx.x*128 + cg*4+1] = s1; psq[blockIdx.x*128 + cg*4+1] = q1;
        psum[blockIdx.x*128 + cg*4+2] = s2; psq[blockIdx.x*128 + cg*4+2] = q2;
        psum[blockIdx.x*128 + cg*4+3] = s3; psq[blockIdx.x*128 + cg*4+3] = q3;
    }
}

// fallback fp32 stats (no convert)
__global__ __launch_bounds__(256) void colstats_f32_128(const float* __restrict__ x, int M,
                                                        float* __restrict__ psum, float* __restrict__ psq) {
    int c = threadIdx.x & 127, sub = threadIdx.x >> 7;
    float s = 0.f, q = 0.f;
    for (int r = blockIdx.x * 2 + sub; r < M; r += gridDim.x * 2) {
        float v = x[(size_t)r * 128 + c];
        s += v; q += v * v;
    }
    __shared__ float ss[256], qs[256];
    ss[threadIdx.x] = s; qs[threadIdx.x] = q;
    __syncthreads();
    if (sub == 0) {
        s += ss[threadIdx.x + 128]; q += qs[threadIdx.x + 128];
        psum[blockIdx.x * 128 + c] = s;
        psq [blockIdx.x * 128 + c] = q;
    }
}

template<int C>
__global__ __launch_bounds__(256) void colstats_bf16_direct(const ushort* __restrict__ x, int M,
                                                            float* __restrict__ psum, float* __restrict__ psq) {
    if constexpr (C == 128) {
        int c = threadIdx.x & 127, sub = threadIdx.x >> 7;
        float s = 0.f, q = 0.f;
        for (int r = blockIdx.x * 2 + sub; r < M; r += gridDim.x * 2) {
            float v = bf2f(x[(size_t)r * 128 + c]);
            s += v; q += v * v;
        }
        __shared__ float ss[256], qs[256];
        ss[threadIdx.x] = s; qs[threadIdx.x] = q;
        __syncthreads();
        if (sub == 0) {
            s += ss[threadIdx.x + 128]; q += qs[threadIdx.x + 128];
            psum[blockIdx.x * 128 + c] = s;
            psq [blockIdx.x * 128 + c] = q;
        }
    } else {
        int c = threadIdx.x;
        float s = 0.f, q = 0.f;
        for (int r = blockIdx.x; r < M; r += gridDim.x) {
            float v = bf2f(x[(size_t)r * C + c]);
            s += v; q += v * v;
        }
        psum[blockIdx.x * C + c] = s;
        psq [blockIdx.x * C + c] = q;
    }
}

// wave-per-edge gather stats (+ optional fused bf16 edge-feature write in iteration order)
__global__ __launch_bounds__(256) void colstats_gather2(const uint* __restrict__ hu2,
                                                        const uint* __restrict__ hv2,
                                                        const int* __restrict__ sidx,
                                                        const int* __restrict__ didx, int E,
                                                        uint* __restrict__ xout,
                                                        float* __restrict__ psum, float* __restrict__ psq) {
    const int lane = threadIdx.x & 63;
    const int w = threadIdx.x >> 6;
    const int gwave = (blockIdx.x * 256 + threadIdx.x) >> 6;
    const int nwave = (gridDim.x * 256) >> 6;
    float s0 = 0.f, s1 = 0.f, q0 = 0.f, q1 = 0.f;
    for (int base = gwave * 64; base < E; base += nwave * 64) {
        int e = base + lane;
        int su = (e < E) ? sidx[e] : 0;
        int dv = (e < E) ? didx[e] : 0;
        int cnt = min(64, E - base);
        #pragma unroll 4
        for (int j = 0; j < cnt; ++j) {
            int a = __shfl(su, j), b = __shfl(dv, j);
            uint uu = hu2[(size_t)a * 64 + lane];
            uint vv = hv2[(size_t)b * 64 + lane];
            float v0 = bf2f(uu & 0xffffu) + bf2f(vv & 0xffffu);
            float v1 = bf2f(uu >> 16) + bf2f(vv >> 16);
            if (xout)
                xout[(size_t)(base + j) * 64 + lane] = (uint)f2bf(v0) | ((uint)f2bf(v1) << 16);
            s0 += v0; q0 += v0 * v0;
            s1 += v1; q1 += v1 * v1;
        }
    }
    __shared__ float red[4][64][4];
    red[w][lane][0] = s0; red[w][lane][1] = s1;
    red[w][lane][2] = q0; red[w][lane][3] = q1;
    __syncthreads();
    if (w == 0) {
        #pragma unroll
        for (int k = 1; k < 4; ++k) {
            s0 += red[k][lane][0]; s1 += red[k][lane][1];
            q0 += red[k][lane][2]; q1 += red[k][lane][3];
        }
        psum[blockIdx.x * 128 + 2 * lane]     = s0;
        psum[blockIdx.x * 128 + 2 * lane + 1] = s1;
        psq [blockIdx.x * 128 + 2 * lane]     = q0;
        psq [blockIdx.x * 128 + 2 * lane + 1] = q1;
    }
}

// ---------------- per-column reduce of partials -> scale/shift (double accum) ----------------
__global__ __launch_bounds__(256) void reduce_stats(
    const float* __restrict__ psum, const float* __restrict__ psq,
    int nblk, int C, int M,
    const float* __restrict__ g, const float* __restrict__ b,
    float* __restrict__ scale, float* __restrict__ shift) {
    const int c = blockIdx.x;
    double s = 0.0, q = 0.0;
    for (int i = threadIdx.x; i < nblk; i += 256) {
        s += (double)psum[(size_t)i * C + c];
        q += (double)psq [(size_t)i * C + c];
    }
    __shared__ double ss[256], qs[256];
    ss[threadIdx.x] = s; qs[threadIdx.x] = q;
    __syncthreads();
    for (int d = 128; d > 0; d >>= 1) {
        if (threadIdx.x < d) {
            ss[threadIdx.x] += ss[threadIdx.x + d];
            qs[threadIdx.x] += qs[threadIdx.x + d];
        }
        __syncthreads();
    }
    if (threadIdx.x == 0) {
        double m = ss[0] / (double)M;
        double v = qs[0] / (double)M - m * m;
        if (v < 0.0) v = 0.0;
        double rs = 1.0 / sqrt(v + 1e-5);
        float sc = (float)(rs * (double)g[c]);
        scale[c] = sc;
        shift[c] = b[c] - (float)m * sc;
    }
}

// ---------------- BN fold + MFMA-fragment pack (single block) ----------------
__global__ __launch_bounds__(256) void pack_fold(
    const float* __restrict__ scale, const float* __restrict__ shift, int C,
    const float* __restrict__ W, const float* __restrict__ bias,
    ushort* __restrict__ Wp, float* __restrict__ beff) {
    __shared__ float sscale[256];
    __shared__ float sshift[256];
    if (threadIdx.x < C) {
        sscale[threadIdx.x] = scale[threadIdx.x];
        sshift[threadIdx.x] = shift[threadIdx.x];
    }
    __syncthreads();
    const int KT = C / 32;
    const int total = 8 * KT * 64;
    for (int f = threadIdx.x; f < total; f += 256) {
        int lane = f & 63;
        int t = f >> 6;
        int kt = t % KT, dt = t / KT;
        int d = dt * 16 + (lane & 15);
        int kb = kt * 32 + (lane >> 4) * 8;
        uint4 o;
        uint w0, w1;
        w0 = (uint)f2bf(W[(size_t)(kb+0)*128 + d] * sscale[kb+0]);
        w1 = (uint)f2bf(W[(size_t)(kb+1)*128 + d] * sscale[kb+1]);
        o.x = w0 | (w1 << 16);
        w0 = (uint)f2bf(W[(size_t)(kb+2)*128 + d] * sscale[kb+2]);
        w1 = (uint)f2bf(W[(size_t)(kb+3)*128 + d] * sscale[kb+3]);
        o.y = w0 | (w1 << 16);
        w0 = (uint)f2bf(W[(size_t)(kb+4)*128 + d] * sscale[kb+4]);
        w1 = (uint)f2bf(W[(size_t)(kb+5)*128 + d] * sscale[kb+5]);
        o.z = w0 | (w1 << 16);
        w0 = (uint)f2bf(W[(size_t)(kb+6)*128 + d] * sscale[kb+6]);
        w1 = (uint)f2bf(W[(size_t)(kb+7)*128 + d] * sscale[kb+7]);
        o.w = w0 | (w1 << 16);
        *(uint4*)(Wp + (size_t)f * 8) = o;
    }
    if (threadIdx.x < 128) {
        int d = threadIdx.x;
        float a = bias[d];
        for (int cc = 0; cc < C; ++cc) a += sshift[cc] * W[(size_t)cc * 128 + d];
        beff[d] = a;
    }
}

// ---------------- MFMA GEMM: Y[row][d] = relu( X[row] @ Weff + beff ) ----------------
template<int KT, bool TWO, bool PERMF32, bool OUTF32>
__global__ __launch_bounds__(256) void gemm_mfma(
    const ushort* __restrict__ X1, const ushort* __restrict__ X2,
    const float* __restrict__ XF,
    const int* __restrict__ g1, const int* __restrict__ g2,
    const ushort* __restrict__ Wp, const float* __restrict__ beff,
    ushort* __restrict__ Yb, float* __restrict__ Yf, int M) {
    constexpr int K = KT * 32;
    const int lane = threadIdx.x & 63;
    const int w = threadIdx.x >> 6;
    const int r0 = blockIdx.x * 128 + w * 32;
    const int rlo = lane & 15, khi = lane >> 4;

    f32x4 acc[2][8];
    #pragma unroll
    for (int rt = 0; rt < 2; ++rt)
        #pragma unroll
        for (int dt = 0; dt < 8; ++dt)
            acc[rt][dt] = (f32x4){0.f, 0.f, 0.f, 0.f};

    int row[2], idx1[2], idx2[2];
    bool ok[2];
    #pragma unroll
    for (int rt = 0; rt < 2; ++rt) {
        row[rt] = r0 + rt * 16 + rlo;
        ok[rt] = row[rt] < M;
        int rr = ok[rt] ? row[rt] : 0;
        idx1[rt] = g1 ? g1[rr] : rr;
        if constexpr (TWO) idx2[rt] = g2[rr];
    }

    for (int kt = 0; kt < KT; ++kt) {
        short8 wf[8];
        #pragma unroll
        for (int dt = 0; dt < 8; ++dt)
            wf[dt] = *(const short8*)(Wp + (size_t)((dt * KT + kt) * 64 + lane) * 8);
        #pragma unroll
        for (int rt = 0; rt < 2; ++rt) {
            short8 bv;
            if constexpr (PERMF32) {
                const float* p = XF + (size_t)idx1[rt] * K + kt * 32 + khi * 8;
                float4 xa = *(const float4*)(p);
                float4 xb = *(const float4*)(p + 4);
                bv[0] = (short)f2bf(xa.x); bv[1] = (short)f2bf(xa.y);
                bv[2] = (short)f2bf(xa.z); bv[3] = (short)f2bf(xa.w);
                bv[4] = (short)f2bf(xb.x); bv[5] = (short)f2bf(xb.y);
                bv[6] = (short)f2bf(xb.z); bv[7] = (short)f2bf(xb.w);
            } else {
                bv = *(const short8*)(X1 + (size_t)idx1[rt] * K + kt * 32 + khi * 8);
            }
            #pragma unroll
            for (int dt = 0; dt < 8; ++dt)
                acc[rt][dt] = __builtin_amdgcn_mfma_f32_16x16x32_bf16(wf[dt], bv, acc[rt][dt], 0, 0, 0);
            if constexpr (TWO) {
                short8 bv2 = *(const short8*)(X2 + (size_t)idx2[rt] * K + kt * 32 + khi * 8);
                #pragma unroll
                for (int dt = 0; dt < 8; ++dt)
                    acc[rt][dt] = __builtin_amdgcn_mfma_f32_16x16x32_bf16(wf[dt], bv2, acc[rt][dt], 0, 0, 0);
            }
        }
    }

    #pragma unroll
    for (int rt = 0; rt < 2; ++rt) {
        if (!ok[rt]) continue;
        #pragma unroll
        for (int dt = 0; dt < 8; ++dt) {
            const float4 bz = *(const float4*)(beff + dt * 16 + khi * 4);
            float v0 = fmaxf(acc[rt][dt][0] + bz.x, 0.f);
            float v1 = fmaxf(acc[rt][dt][1] + bz.y, 0.f);
            float v2 = fmaxf(acc[rt][dt][2] + bz.z, 0.f);
            float v3 = fmaxf(acc[rt][dt][3] + bz.w, 0.f);
            if constexpr (OUTF32) {
                *(float4*)(Yf + (size_t)row[rt] * 128 + dt * 16 + khi * 4) = make_float4(v0, v1, v2, v3);
            } else {
                uint2 pk;
                pk.x = (uint)f2bf(v0) | ((uint)f2bf(v1) << 16);
                pk.y = (uint)f2bf(v2) | ((uint)f2bf(v3) << 16);
                *(uint2*)(Yb + (size_t)row[rt] * 128 + dt * 16 + khi * 4) = pk;
            }
        }
    }
}

// ---------------- segmented mean over sorted runs; 64 lanes per node ----------------
template<bool FIRST>
__global__ __launch_bounds__(256) void reduce_half(
    const uint* __restrict__ Y2, const int* __restrict__ off,
    float2* __restrict__ hacc, uint* __restrict__ h2, uint* __restrict__ fh2,
    int fhsel, int N) {
    int lane = threadIdx.x & 63;
    int nn = blockIdx.x * 4 + (threadIdx.x >> 6);
    if (nn >= N) return;
    int a = off[nn], b = off[nn + 1];
    float s0 = 0.f, s1 = 0.f;
    for (int r = a; r < b; ++r) {
        uint u = Y2[(size_t)r * 64 + lane];
        s0 += bf2f(u & 0xffffu);
        s1 += bf2f(u >> 16);
    }
    float inv = 0.5f / fmaxf((float)(b - a), 1.f);
    s0 *= inv; s1 *= inv;
    if constexpr (FIRST) {
        hacc[(size_t)nn * 64 + lane] = make_float2(s0, s1);
    } else {
        float2 p = hacc[(size_t)nn * 64 + lane];
        float v0 = p.x + s0, v1 = p.y + s1;
        uint pk = (uint)f2bf(v0) | ((uint)f2bf(v1) << 16);
        h2[(size_t)nn * 64 + lane] = pk;
        if (fhsel >= 0) fh2[(size_t)nn * 128 + fhsel * 64 + lane] = pk;
    }
}

// ---------------- launch ----------------
extern "C" void kernel_launch(void* const* d_in, const int* in_sizes, int n_in,
                              void* d_out, int out_size, void* d_ws, size_t ws_size,
                              hipStream_t stream) {
    const float* win_f  = (const float*)d_in[0];
    const float* loss_f = (const float*)d_in[1];
    struct BP { const float *g, *b, *W, *bias; };
    auto bp = [&](int i) { return BP{ (const float*)d_in[i], (const float*)d_in[i+1],
                                      (const float*)d_in[i+2], (const float*)d_in[i+3] }; };
    BP wi = bp(2), li = bp(6), srcp = bp(10), dstp = bp(14), wl = bp(18), ll = bp(22), outp = bp(26);
    const int* win_src  = (const int*)d_in[30];
    const int* win_dst  = (const int*)d_in[31];
    const int* loss_src = (const int*)d_in[32];
    const int* loss_dst = (const int*)d_in[33];
    const int E = in_sizes[30];
    const int N = out_size / 128;
    (void)n_in;

    char* base = (char*)d_ws;
    size_t off_b = 0;
    auto alloc = [&](size_t bytes) {
        size_t cur = off_b;
        off_b += (bytes + 255) & ~(size_t)255;
        return (void*)(base + cur);
    };
    ushort* Y    = (ushort*)alloc((size_t)E * 128 * 2);
    float2* hacc = (float2*)alloc((size_t)N * 64 * 8);
    ushort* h    = (ushort*)alloc((size_t)N * 128 * 2);
    ushort* hu   = (ushort*)alloc((size_t)N * 128 * 2);
    ushort* hv   = (ushort*)alloc((size_t)N * 128 * 2);
    ushort* fh   = (ushort*)alloc((size_t)N * 256 * 2);
    int* cntw  = (int*)alloc((size_t)N * 4);
    int* cntl  = (int*)alloc((size_t)N * 4);
    int* offw  = (int*)alloc((size_t)(N + 1) * 4);
    int* offl  = (int*)alloc((size_t)(N + 1) * 4);
    int* curw  = (int*)alloc((size_t)N * 4);
    int* curl  = (int*)alloc((size_t)N * 4);
    int* permw = (int*)alloc((size_t)E * 4);
    int* ipermw= (int*)alloc((size_t)E * 4);
    int* ssrcw = (int*)alloc((size_t)E * 4);
    int* sdstw = (int*)alloc((size_t)E * 4);
    int* perml = (int*)alloc((size_t)E * 4);
    int* iperml= (int*)alloc((size_t)E * 4);
    int* ssrcl = (int*)alloc((size_t)E * 4);
    int* sdstl = (int*)alloc((size_t)E * 4);
    float* psum = (float*)alloc((size_t)NPART_MAX * 256 * 4);
    float* psq  = (float*)alloc((size_t)NPART_MAX * 256 * 4);
    float* scal = (float*)alloc(256 * 4);
    float* shif = (float*)alloc(256 * 4);
    ushort* Wp  = (ushort*)alloc((size_t)256 * 128 * 2);
    float* beff = (float*)alloc(128 * 4);
    size_t off_noxbf = off_b;
    ushort* Xbf = (ushort*)alloc((size_t)E * 128 * 2);
    bool have_xbf = (off_b <= ws_size);
    if (off_noxbf > ws_size) return;   // even base layout doesn't fit

    const int gE = (E + 127) / 128;
    const int gN = (N + 127) / 128;
    const int gR = (N + 3) / 4;
    const int NBF = 1024;
    const int NBG = 1024;
    const int NBN = 512;

    auto fold = [&](int nblk, int M, int C, const BP& p) {
        reduce_stats<<<C, 256, 0, stream>>>(psum, psq, nblk, C, M, p.g, p.b, scal, shif);
        pack_fold<<<1, 256, 0, stream>>>(scal, shif, C, p.W, p.bias, Wp, beff);
    };

    // phase 0: counting sort per etype
    hipMemsetAsync(cntw, 0, (size_t)N * 4, stream);
    hipMemsetAsync(cntl, 0, (size_t)N * 4, stream);
    hist_kernel<<<1024, 256, 0, stream>>>(win_dst,  E, cntw);
    hist_kernel<<<1024, 256, 0, stream>>>(loss_dst, E, cntl);
    scan_kernel<<<1, 256, 0, stream>>>(cntw, N, offw, curw);
    scan_kernel<<<1, 256, 0, stream>>>(cntl, N, offl, curl);
    scatter_kernel<<<1024, 256, 0, stream>>>(win_src,  win_dst,  E, curw, permw, ipermw, ssrcw, sdstw);
    scatter_kernel<<<1024, 256, 0, stream>>>(loss_src, loss_dst, E, curl, perml, iperml, ssrcl, sdstl);

    // initial edge blocks
    if (have_xbf) {
        convert_stats_f32<<<NBF, 256, 0, stream>>>((const float4*)win_f, ipermw, E,
                                                   (uint2*)Xbf, psum, psq);
        fold(NBF, E, 128, wi);
        gemm_mfma<4, false, false, false><<<gE, 256, 0, stream>>>(
            Xbf, nullptr, nullptr, nullptr, nullptr, Wp, beff, Y, nullptr, E);
        reduce_half<true><<<gR, 256, 0, stream>>>((const uint*)Y, offw, hacc, nullptr, nullptr, -1, N);

        convert_stats_f32<<<NBF, 256, 0, stream>>>((const float4*)loss_f, iperml, E,
                                                   (uint2*)Xbf, psum, psq);
        fold(NBF, E, 128, li);
        gemm_mfma<4, false, false, false><<<gE, 256, 0, stream>>>(
            Xbf, nullptr, nullptr, nullptr, nullptr, Wp, beff, Y, nullptr, E);
        reduce_half<false><<<gR, 256, 0, stream>>>((const uint*)Y, offl, hacc, (uint*)h, (uint*)fh, 0, N);
    } else {
        colstats_f32_128<<<NBF, 256, 0, stream>>>(win_f, E, psum, psq);
        fold(NBF, E, 128, wi);
        gemm_mfma<4, false, true, false><<<gE, 256, 0, stream>>>(
            nullptr, nullptr, win_f, permw, nullptr, Wp, beff, Y, nullptr, E);
        reduce_half<true><<<gR, 256, 0, stream>>>((const uint*)Y, offw, hacc, nullptr, nullptr, -1, N);

        colstats_f32_128<<<NBF, 256, 0, stream>>>(loss_f, E, psum, psq);
        fold(NBF, E, 128, li);
        gemm_mfma<4, false, true, false><<<gE, 256, 0, stream>>>(
            nullptr, nullptr, loss_f, perml, nullptr, Wp, beff, Y, nullptr, E);
        reduce_half<false><<<gR, 256, 0, stream>>>((const uint*)Y, offl, hacc, (uint*)h, (uint*)fh, 0, N);
    }

    for (int it = 0; it < 3; ++it) {
        colstats_bf16_direct<128><<<NBN, 256, 0, stream>>>(h, N, psum, psq);
        fold(NBN, N, 128, srcp);
        gemm_mfma<4, false, false, false><<<gN, 256, 0, stream>>>(
            h, nullptr, nullptr, nullptr, nullptr, Wp, beff, hu, nullptr, N);
        fold(NBN, N, 128, dstp);
        gemm_mfma<4, false, false, false><<<gN, 256, 0, stream>>>(
            h, nullptr, nullptr, nullptr, nullptr, Wp, beff, hv, nullptr, N);

        if (have_xbf) {
            colstats_gather2<<<NBG, 256, 0, stream>>>((const uint*)hu, (const uint*)hv,
                                                      ssrcw, sdstw, E, (uint*)Xbf, psum, psq);
            fold(NBG, E, 128, wl);
            gemm_mfma<4, false, false, false><<<gE, 256, 0, stream>>>(
                Xbf, nullptr, nullptr, nullptr, nullptr, Wp, beff, Y, nullptr, E);
            reduce_half<true><<<gR, 256, 0, stream>>>((const uint*)Y, offw, hacc, nullptr, nullptr, -1, N);

            colstats_gather2<<<NBG, 256, 0, stream>>>((const uint*)hu, (const uint*)hv,
                                                      ssrcl, sdstl, E, (uint*)Xbf, psum, psq);
            fold(NBG, E, 128, ll);
            gemm_mfma<4, false, false, false><<<gE, 256, 0, stream>>>(
                Xbf, nullptr, nullptr, nullptr, nullptr, Wp, beff, Y, nullptr, E);
            reduce_half<false><<<gR, 256, 0, stream>>>((const uint*)Y, offl, hacc, (uint*)h, (uint*)fh,
                                                       (it == 2) ? 1 : -1, N);
        } else {
            colstats_gather2<<<NBG, 256, 0, stream>>>((const uint*)hu, (const uint*)hv,
                                                      ssrcw, sdstw, E, nullptr, psum, psq);
            fold(NBG, E, 128, wl);
            gemm_mfma<4, true, false, false><<<gE, 256, 0, stream>>>(
                hu, hv, nullptr, ssrcw, sdstw, Wp, beff, Y, nullptr, E);
            reduce_half<true><<<gR, 256, 0, stream>>>((const uint*)Y, offw, hacc, nullptr, nullptr, -1, N);

            colstats_gather2<<<NBG, 256, 0, stream>>>((const uint*)hu, (const uint*)hv,
                                                      ssrcl, sdstl, E, nullptr, psum, psq);
            fold(NBG, E, 128, ll);
            gemm_mfma<4, true, false, false><<<gE, 256, 0, stream>>>(
                hu, hv, nullptr, ssrcl, sdstl, Wp, beff, Y, nullptr, E);
            reduce_half<false><<<gR, 256, 0, stream>>>((const uint*)Y, offl, hacc, (uint*)h, (uint*)fh,
                                                       (it == 2) ? 1 : -1, N);
        }
    }

    colstats_bf16_direct<256><<<NBN, 256, 0, stream>>>(fh, N, psum, psq);
    fold(NBN, N, 256, outp);
    gemm_mfma<8, false, false, true><<<gN, 256, 0, stream>>>(
        fh, nullptr, nullptr, nullptr, nullptr, Wp, beff, nullptr, (float*)d_out, N);
}

// Round 7
// 1509.384 us; speedup vs baseline: 3.1263x; 1.0201x over previous
//
#include <hip/hip_runtime.h>

#define NPART_MAX 2048

typedef __attribute__((ext_vector_type(8))) short short8;
typedef __attribute__((ext_vector_type(4))) float f32x4;

__device__ __forceinline__ float bf2f(uint u) {
    union { uint u; float f; } v; v.u = u << 16; return v.f;
}
__device__ __forceinline__ ushort f2bf(float f) {
    union { float f; uint u; } v; v.f = f;
    uint r = v.u + 0x7fffu + ((v.u >> 16) & 1u);
    return (ushort)(r >> 16);
}

// ---------------- phase 0: counting sort by dst ----------------
__global__ __launch_bounds__(256) void hist_kernel(const int* __restrict__ dst, int E,
                                                   int* __restrict__ cnt) {
    for (int e = blockIdx.x * 256 + threadIdx.x; e < E; e += gridDim.x * 256)
        atomicAdd(&cnt[dst[e]], 1);
}

__global__ __launch_bounds__(256) void scan_kernel(const int* __restrict__ cnt, int n,
                                                   int* __restrict__ off, int* __restrict__ cursor) {
    __shared__ int warpsums[4];
    __shared__ int s_carry;
    if (threadIdx.x == 0) s_carry = 0;
    __syncthreads();
    for (int base = 0; base < n; base += 256) {
        int i = base + threadIdx.x;
        int v = (i < n) ? cnt[i] : 0;
        int lane = threadIdx.x & 63, w = threadIdx.x >> 6;
        int x = v;
        for (int d = 1; d < 64; d <<= 1) {
            int y = __shfl_up(x, d);
            if (lane >= d) x += y;
        }
        if (lane == 63) warpsums[w] = x;
        __syncthreads();
        int woff = 0;
        for (int k = 0; k < w; ++k) woff += warpsums[k];
        int incl = x + woff + s_carry;
        int excl = incl - v;
        if (i < n) { off[i] = excl; cursor[i] = excl; }
        __syncthreads();
        if (threadIdx.x == 255) s_carry = incl;
        __syncthreads();
    }
    if (threadIdx.x == 0) off[n] = s_carry;
}

__global__ __launch_bounds__(256) void scatter_kernel(const int* __restrict__ src,
                                                      const int* __restrict__ dst, int E,
                                                      int* __restrict__ cursor,
                                                      int* __restrict__ perm,
                                                      int* __restrict__ iperm,
                                                      int* __restrict__ ssrc,
                                                      int* __restrict__ sdst) {
    for (int e = blockIdx.x * 256 + threadIdx.x; e < E; e += gridDim.x * 256) {
        int d = dst[e];
        int p = atomicAdd(&cursor[d], 1);
        perm[p] = e;
        iperm[e] = p;
        ssrc[p] = src[e];
        sdst[p] = d;
    }
}

// ---------------- fused fp32 col-stats + bf16 convert into sorted slots ----------------
__global__ __launch_bounds__(256) void convert_stats_f32(
    const float4* __restrict__ x4, const int* __restrict__ iperm, int M,
    uint2* __restrict__ xb4, float* __restrict__ psum, float* __restrict__ psq) {
    const int cg = threadIdx.x & 31;
    const int sub = threadIdx.x >> 5;
    float s0=0,s1=0,s2=0,s3=0,q0=0,q1=0,q2=0,q3=0;
    for (int r = blockIdx.x * 8 + sub; r < M; r += gridDim.x * 8) {
        float4 v = x4[(size_t)r * 32 + cg];
        int p = iperm[r];
        uint2 o;
        o.x = (uint)f2bf(v.x) | ((uint)f2bf(v.y) << 16);
        o.y = (uint)f2bf(v.z) | ((uint)f2bf(v.w) << 16);
        xb4[(size_t)p * 32 + cg] = o;
        s0 += v.x; q0 += v.x * v.x;
        s1 += v.y; q1 += v.y * v.y;
        s2 += v.z; q2 += v.z * v.z;
        s3 += v.w; q3 += v.w * v.w;
    }
    __shared__ float rs[256][4], rq[256][4];
    rs[threadIdx.x][0]=s0; rs[threadIdx.x][1]=s1; rs[threadIdx.x][2]=s2; rs[threadIdx.x][3]=s3;
    rq[threadIdx.x][0]=q0; rq[threadIdx.x][1]=q1; rq[threadIdx.x][2]=q2; rq[threadIdx.x][3]=q3;
    __syncthreads();
    if (sub == 0) {
        #pragma unroll
        for (int k = 1; k < 8; ++k) {
            s0 += rs[k*32+cg][0]; s1 += rs[k*32+cg][1];
            s2 += rs[k*32+cg][2]; s3 += rs[k*32+cg][3];
            q0 += rq[k*32+cg][0]; q1 += rq[k*32+cg][1];
            q2 += rq[k*32+cg][2]; q3 += rq[k*32+cg][3];
        }
        psum[blockIdx.x*128 + cg*4+0] = s0; psq[blockIdx.x*128 + cg*4+0] = q0;
        psum[blockIdx.x*128 + cg*4+1] = s1; psq[blockIdx.x*128 + cg*4+1] = q1;
        psum[blockIdx.x*128 + cg*4+2] = s2; psq[blockIdx.x*128 + cg*4+2] = q2;
        psum[blockIdx.x*128 + cg*4+3] = s3; psq[blockIdx.x*128 + cg*4+3] = q3;
    }
}

// fallback fp32 stats (no convert)
__global__ __launch_bounds__(256) void colstats_f32_128(const float* __restrict__ x, int M,
                                                        float* __restrict__ psum, float* __restrict__ psq) {
    int c = threadIdx.x & 127, sub = threadIdx.x >> 7;
    float s = 0.f, q = 0.f;
    for (int r = blockIdx.x * 2 + sub; r < M; r += gridDim.x * 2) {
        float v = x[(size_t)r * 128 + c];
        s += v; q += v * v;
    }
    __shared__ float ss[256], qs[256];
    ss[threadIdx.x] = s; qs[threadIdx.x] = q;
    __syncthreads();
    if (sub == 0) {
        s += ss[threadIdx.x + 128]; q += qs[threadIdx.x + 128];
        psum[blockIdx.x * 128 + c] = s;
        psq [blockIdx.x * 128 + c] = q;
    }
}

template<int C>
__global__ __launch_bounds__(256) void colstats_bf16_direct(const ushort* __restrict__ x, int M,
                                                            float* __restrict__ psum, float* __restrict__ psq) {
    if constexpr (C == 128) {
        int c = threadIdx.x & 127, sub = threadIdx.x >> 7;
        float s = 0.f, q = 0.f;
        for (int r = blockIdx.x * 2 + sub; r < M; r += gridDim.x * 2) {
            float v = bf2f(x[(size_t)r * 128 + c]);
            s += v; q += v * v;
        }
        __shared__ float ss[256], qs[256];
        ss[threadIdx.x] = s; qs[threadIdx.x] = q;
        __syncthreads();
        if (sub == 0) {
            s += ss[threadIdx.x + 128]; q += qs[threadIdx.x + 128];
            psum[blockIdx.x * 128 + c] = s;
            psq [blockIdx.x * 128 + c] = q;
        }
    } else {
        int c = threadIdx.x;
        float s = 0.f, q = 0.f;
        for (int r = blockIdx.x; r < M; r += gridDim.x) {
            float v = bf2f(x[(size_t)r * C + c]);
            s += v; q += v * v;
        }
        psum[blockIdx.x * C + c] = s;
        psq [blockIdx.x * C + c] = q;
    }
}

// wave-per-edge gather stats (+ optional fused bf16 edge-feature write in iteration order)
__global__ __launch_bounds__(256) void colstats_gather2(const uint* __restrict__ hu2,
                                                        const uint* __restrict__ hv2,
                                                        const int* __restrict__ sidx,
                                                        const int* __restrict__ didx, int E,
                                                        uint* __restrict__ xout,
                                                        float* __restrict__ psum, float* __restrict__ psq) {
    const int lane = threadIdx.x & 63;
    const int w = threadIdx.x >> 6;
    const int gwave = (blockIdx.x * 256 + threadIdx.x) >> 6;
    const int nwave = (gridDim.x * 256) >> 6;
    float s0 = 0.f, s1 = 0.f, q0 = 0.f, q1 = 0.f;
    for (int base = gwave * 64; base < E; base += nwave * 64) {
        int e = base + lane;
        int su = (e < E) ? sidx[e] : 0;
        int dv = (e < E) ? didx[e] : 0;
        int cnt = min(64, E - base);
        #pragma unroll 4
        for (int j = 0; j < cnt; ++j) {
            int a = __shfl(su, j), b = __shfl(dv, j);
            uint uu = hu2[(size_t)a * 64 + lane];
            uint vv = hv2[(size_t)b * 64 + lane];
            float v0 = bf2f(uu & 0xffffu) + bf2f(vv & 0xffffu);
            float v1 = bf2f(uu >> 16) + bf2f(vv >> 16);
            if (xout)
                xout[(size_t)(base + j) * 64 + lane] = (uint)f2bf(v0) | ((uint)f2bf(v1) << 16);
            s0 += v0; q0 += v0 * v0;
            s1 += v1; q1 += v1 * v1;
        }
    }
    __shared__ float red[4][64][4];
    red[w][lane][0] = s0; red[w][lane][1] = s1;
    red[w][lane][2] = q0; red[w][lane][3] = q1;
    __syncthreads();
    if (w == 0) {
        #pragma unroll
        for (int k = 1; k < 4; ++k) {
            s0 += red[k][lane][0]; s1 += red[k][lane][1];
            q0 += red[k][lane][2]; q1 += red[k][lane][3];
        }
        psum[blockIdx.x * 128 + 2 * lane]     = s0;
        psum[blockIdx.x * 128 + 2 * lane + 1] = s1;
        psq [blockIdx.x * 128 + 2 * lane]     = q0;
        psq [blockIdx.x * 128 + 2 * lane + 1] = q1;
    }
}

// ---------------- per-column reduce of partials -> scale/shift (double accum) ----------------
__global__ __launch_bounds__(256) void reduce_stats(
    const float* __restrict__ psum, const float* __restrict__ psq,
    int nblk, int C, int M,
    const float* __restrict__ g, const float* __restrict__ b,
    float* __restrict__ scale, float* __restrict__ shift) {
    const int c = blockIdx.x;
    double s = 0.0, q = 0.0;
    for (int i = threadIdx.x; i < nblk; i += 256) {
        s += (double)psum[(size_t)i * C + c];
        q += (double)psq [(size_t)i * C + c];
    }
    __shared__ double ss[256], qs[256];
    ss[threadIdx.x] = s; qs[threadIdx.x] = q;
    __syncthreads();
    for (int d = 128; d > 0; d >>= 1) {
        if (threadIdx.x < d) {
            ss[threadIdx.x] += ss[threadIdx.x + d];
            qs[threadIdx.x] += qs[threadIdx.x + d];
        }
        __syncthreads();
    }
    if (threadIdx.x == 0) {
        double m = ss[0] / (double)M;
        double v = qs[0] / (double)M - m * m;
        if (v < 0.0) v = 0.0;
        double rs = 1.0 / sqrt(v + 1e-5);
        float sc = (float)(rs * (double)g[c]);
        scale[c] = sc;
        shift[c] = b[c] - (float)m * sc;
    }
}

// ---------------- BN fold + MFMA-fragment pack (single block) ----------------
__global__ __launch_bounds__(256) void pack_fold(
    const float* __restrict__ scale, const float* __restrict__ shift, int C,
    const float* __restrict__ W, const float* __restrict__ bias,
    ushort* __restrict__ Wp, float* __restrict__ beff) {
    __shared__ float sscale[256];
    __shared__ float sshift[256];
    if (threadIdx.x < C) {
        sscale[threadIdx.x] = scale[threadIdx.x];
        sshift[threadIdx.x] = shift[threadIdx.x];
    }
    __syncthreads();
    const int KT = C / 32;
    const int total = 8 * KT * 64;
    for (int f = threadIdx.x; f < total; f += 256) {
        int lane = f & 63;
        int t = f >> 6;
        int kt = t % KT, dt = t / KT;
        int d = dt * 16 + (lane & 15);
        int kb = kt * 32 + (lane >> 4) * 8;
        uint4 o;
        uint w0, w1;
        w0 = (uint)f2bf(W[(size_t)(kb+0)*128 + d] * sscale[kb+0]);
        w1 = (uint)f2bf(W[(size_t)(kb+1)*128 + d] * sscale[kb+1]);
        o.x = w0 | (w1 << 16);
        w0 = (uint)f2bf(W[(size_t)(kb+2)*128 + d] * sscale[kb+2]);
        w1 = (uint)f2bf(W[(size_t)(kb+3)*128 + d] * sscale[kb+3]);
        o.y = w0 | (w1 << 16);
        w0 = (uint)f2bf(W[(size_t)(kb+4)*128 + d] * sscale[kb+4]);
        w1 = (uint)f2bf(W[(size_t)(kb+5)*128 + d] * sscale[kb+5]);
        o.z = w0 | (w1 << 16);
        w0 = (uint)f2bf(W[(size_t)(kb+6)*128 + d] * sscale[kb+6]);
        w1 = (uint)f2bf(W[(size_t)(kb+7)*128 + d] * sscale[kb+7]);
        o.w = w0 | (w1 << 16);
        *(uint4*)(Wp + (size_t)f * 8) = o;
    }
    if (threadIdx.x < 128) {
        int d = threadIdx.x;
        float a = bias[d];
        for (int cc = 0; cc < C; ++cc) a += sshift[cc] * W[(size_t)cc * 128 + d];
        beff[d] = a;
    }
}

// ---------------- MFMA GEMM: Y[row][d] = relu( X[row] @ Weff + beff ) ----------------
template<int KT, bool TWO, bool PERMF32, bool OUTF32>
__global__ __launch_bounds__(256) void gemm_mfma(
    const ushort* __restrict__ X1, const ushort* __restrict__ X2,
    const float* __restrict__ XF,
    const int* __restrict__ g1, const int* __restrict__ g2,
    const ushort* __restrict__ Wp, const float* __restrict__ beff,
    ushort* __restrict__ Yb, float* __restrict__ Yf, int M) {
    constexpr int K = KT * 32;
    const int lane = threadIdx.x & 63;
    const int w = threadIdx.x >> 6;
    const int r0 = blockIdx.x * 128 + w * 32;
    const int rlo = lane & 15, khi = lane >> 4;

    f32x4 acc[2][8];
    #pragma unroll
    for (int rt = 0; rt < 2; ++rt)
        #pragma unroll
        for (int dt = 0; dt < 8; ++dt)
            acc[rt][dt] = (f32x4){0.f, 0.f, 0.f, 0.f};

    int row[2], idx1[2], idx2[2];
    bool ok[2];
    #pragma unroll
    for (int rt = 0; rt < 2; ++rt) {
        row[rt] = r0 + rt * 16 + rlo;
        ok[rt] = row[rt] < M;
        int rr = ok[rt] ? row[rt] : 0;
        idx1[rt] = g1 ? g1[rr] : rr;
        if constexpr (TWO) idx2[rt] = g2[rr];
    }

    for (int kt = 0; kt < KT; ++kt) {
        short8 wf[8];
        #pragma unroll
        for (int dt = 0; dt < 8; ++dt)
            wf[dt] = *(const short8*)(Wp + (size_t)((dt * KT + kt) * 64 + lane) * 8);
        #pragma unroll
        for (int rt = 0; rt < 2; ++rt) {
            short8 bv;
            if constexpr (PERMF32) {
                const float* p = XF + (size_t)idx1[rt] * K + kt * 32 + khi * 8;
                float4 xa = *(const float4*)(p);
                float4 xb = *(const float4*)(p + 4);
                bv[0] = (short)f2bf(xa.x); bv[1] = (short)f2bf(xa.y);
                bv[2] = (short)f2bf(xa.z); bv[3] = (short)f2bf(xa.w);
                bv[4] = (short)f2bf(xb.x); bv[5] = (short)f2bf(xb.y);
                bv[6] = (short)f2bf(xb.z); bv[7] = (short)f2bf(xb.w);
            } else {
                bv = *(const short8*)(X1 + (size_t)idx1[rt] * K + kt * 32 + khi * 8);
            }
            #pragma unroll
            for (int dt = 0; dt < 8; ++dt)
                acc[rt][dt] = __builtin_amdgcn_mfma_f32_16x16x32_bf16(wf[dt], bv, acc[rt][dt], 0, 0, 0);
            if constexpr (TWO) {
                short8 bv2 = *(const short8*)(X2 + (size_t)idx2[rt] * K + kt * 32 + khi * 8);
                #pragma unroll
                for (int dt = 0; dt < 8; ++dt)
                    acc[rt][dt] = __builtin_amdgcn_mfma_f32_16x16x32_bf16(wf[dt], bv2, acc[rt][dt], 0, 0, 0);
            }
        }
    }

    #pragma unroll
    for (int rt = 0; rt < 2; ++rt) {
        if (!ok[rt]) continue;
        #pragma unroll
        for (int dt = 0; dt < 8; ++dt) {
            const float4 bz = *(const float4*)(beff + dt * 16 + khi * 4);
            float v0 = fmaxf(acc[rt][dt][0] + bz.x, 0.f);
            float v1 = fmaxf(acc[rt][dt][1] + bz.y, 0.f);
            float v2 = fmaxf(acc[rt][dt][2] + bz.z, 0.f);
            float v3 = fmaxf(acc[rt][dt][3] + bz.w, 0.f);
            if constexpr (OUTF32) {
                *(float4*)(Yf + (size_t)row[rt] * 128 + dt * 16 + khi * 4) = make_float4(v0, v1, v2, v3);
            } else {
                uint2 pk;
                pk.x = (uint)f2bf(v0) | ((uint)f2bf(v1) << 16);
                pk.y = (uint)f2bf(v2) | ((uint)f2bf(v3) << 16);
                *(uint2*)(Yb + (size_t)row[rt] * 128 + dt * 16 + khi * 4) = pk;
            }
        }
    }
}

// ---------------- MFMA GEMM with fused segmented-mean epilogue ----------------
// Rows sorted by dst. Block reduces contiguous runs in LDS, then one scaled
// fp32 atomicAdd per (node-run, column) into hacc[N][128].
__global__ __launch_bounds__(256) void gemm_mfma_seg(
    const ushort* __restrict__ X, const int* __restrict__ sdst,
    const int* __restrict__ cnt,
    const ushort* __restrict__ Wp, const float* __restrict__ beff,
    float* __restrict__ hacc, int M) {
    constexpr int KT = 4;
    __shared__ ushort tile[128 * 132];   // stride 132: conflict-free writes & reads
    __shared__ int   s_node[128];
    __shared__ float s_scale[128];
    const int tid = threadIdx.x;
    const int lane = tid & 63;
    const int w = tid >> 6;
    const int rb = blockIdx.x * 128;
    const int r0 = rb + w * 32;
    const int rlo = lane & 15, khi = lane >> 4;

    if (tid < 128) {
        int r = rb + tid;
        int nd = (r < M) ? sdst[r] : -1;
        s_node[tid] = nd;
        s_scale[tid] = (nd >= 0) ? 0.5f / fmaxf((float)cnt[nd], 1.f) : 0.f;
    }

    f32x4 acc[2][8];
    #pragma unroll
    for (int rt = 0; rt < 2; ++rt)
        #pragma unroll
        for (int dt = 0; dt < 8; ++dt)
            acc[rt][dt] = (f32x4){0.f, 0.f, 0.f, 0.f};

    int row[2], idx[2];
    bool ok[2];
    #pragma unroll
    for (int rt = 0; rt < 2; ++rt) {
        row[rt] = r0 + rt * 16 + rlo;
        ok[rt] = row[rt] < M;
        idx[rt] = ok[rt] ? row[rt] : 0;
    }

    for (int kt = 0; kt < KT; ++kt) {
        short8 wf[8];
        #pragma unroll
        for (int dt = 0; dt < 8; ++dt)
            wf[dt] = *(const short8*)(Wp + (size_t)((dt * KT + kt) * 64 + lane) * 8);
        #pragma unroll
        for (int rt = 0; rt < 2; ++rt) {
            short8 bv = *(const short8*)(X + (size_t)idx[rt] * 128 + kt * 32 + khi * 8);
            #pragma unroll
            for (int dt = 0; dt < 8; ++dt)
                acc[rt][dt] = __builtin_amdgcn_mfma_f32_16x16x32_bf16(wf[dt], bv, acc[rt][dt], 0, 0, 0);
        }
    }

    // deposit bf16 outputs into LDS tile (LDS row = w*32 + rt*16 + rlo — block-local row!)
    #pragma unroll
    for (int rt = 0; rt < 2; ++rt) {
        const int rl = w * 32 + rt * 16 + rlo;
        #pragma unroll
        for (int dt = 0; dt < 8; ++dt) {
            const float4 bz = *(const float4*)(beff + dt * 16 + khi * 4);
            float v0 = 0.f, v1 = 0.f, v2 = 0.f, v3 = 0.f;
            if (ok[rt]) {
                v0 = fmaxf(acc[rt][dt][0] + bz.x, 0.f);
                v1 = fmaxf(acc[rt][dt][1] + bz.y, 0.f);
                v2 = fmaxf(acc[rt][dt][2] + bz.z, 0.f);
                v3 = fmaxf(acc[rt][dt][3] + bz.w, 0.f);
            }
            uint2 pk;
            pk.x = (uint)f2bf(v0) | ((uint)f2bf(v1) << 16);
            pk.y = (uint)f2bf(v2) | ((uint)f2bf(v3) << 16);
            *(uint2*)&tile[rl * 132 + dt * 16 + khi * 4] = pk;
        }
    }
    __syncthreads();

    // per-column segmented reduce over sorted runs; one atomic per (run, col)
    const int col = tid & 127;
    const int rs = (tid >> 7) * 64;
    int cur = s_node[rs];
    float scl = s_scale[rs];
    float sum = 0.f;
    for (int r = rs; r < rs + 64; ++r) {
        int nd = s_node[r];
        if (nd != cur) {
            if (cur >= 0)
                atomicAdd(&hacc[(size_t)cur * 128 + col], sum * scl);
            cur = nd; scl = s_scale[r]; sum = 0.f;
        }
        sum += bf2f(tile[r * 132 + col]);
    }
    if (cur >= 0)
        atomicAdd(&hacc[(size_t)cur * 128 + col], sum * scl);
}

// ---------------- hacc (fp32 sums of both etypes) -> bf16 h (+fh half), re-zero hacc ----------------
__global__ __launch_bounds__(256) void finalize_hacc(
    float2* __restrict__ hacc2, uint* __restrict__ h2, uint* __restrict__ fh2,
    int fhsel, int N) {
    const int total = N * 64;
    for (int i = blockIdx.x * 256 + threadIdx.x; i < total; i += gridDim.x * 256) {
        float2 v = hacc2[i];
        uint pk = (uint)f2bf(v.x) | ((uint)f2bf(v.y) << 16);
        h2[i] = pk;
        if (fhsel >= 0) fh2[((size_t)(i >> 6)) * 128 + fhsel * 64 + (i & 63)] = pk;
        hacc2[i] = make_float2(0.f, 0.f);
    }
}

// ---------------- fallback: segmented mean over sorted runs (Y path) ----------------
template<bool FIRST>
__global__ __launch_bounds__(256) void reduce_half(
    const uint* __restrict__ Y2, const int* __restrict__ off,
    float2* __restrict__ hacc, uint* __restrict__ h2, uint* __restrict__ fh2,
    int fhsel, int N) {
    int lane = threadIdx.x & 63;
    int nn = blockIdx.x * 4 + (threadIdx.x >> 6);
    if (nn >= N) return;
    int a = off[nn], b = off[nn + 1];
    float s0 = 0.f, s1 = 0.f;
    for (int r = a; r < b; ++r) {
        uint u = Y2[(size_t)r * 64 + lane];
        s0 += bf2f(u & 0xffffu);
        s1 += bf2f(u >> 16);
    }
    float inv = 0.5f / fmaxf((float)(b - a), 1.f);
    s0 *= inv; s1 *= inv;
    if constexpr (FIRST) {
        hacc[(size_t)nn * 64 + lane] = make_float2(s0, s1);
    } else {
        float2 p = hacc[(size_t)nn * 64 + lane];
        float v0 = p.x + s0, v1 = p.y + s1;
        uint pk = (uint)f2bf(v0) | ((uint)f2bf(v1) << 16);
        h2[(size_t)nn * 64 + lane] = pk;
        if (fhsel >= 0) fh2[(size_t)nn * 128 + fhsel * 64 + lane] = pk;
    }
}

// ---------------- launch ----------------
extern "C" void kernel_launch(void* const* d_in, const int* in_sizes, int n_in,
                              void* d_out, int out_size, void* d_ws, size_t ws_size,
                              hipStream_t stream) {
    const float* win_f  = (const float*)d_in[0];
    const float* loss_f = (const float*)d_in[1];
    struct BP { const float *g, *b, *W, *bias; };
    auto bp = [&](int i) { return BP{ (const float*)d_in[i], (const float*)d_in[i+1],
                                      (const float*)d_in[i+2], (const float*)d_in[i+3] }; };
    BP wi = bp(2), li = bp(6), srcp = bp(10), dstp = bp(14), wl = bp(18), ll = bp(22), outp = bp(26);
    const int* win_src  = (const int*)d_in[30];
    const int* win_dst  = (const int*)d_in[31];
    const int* loss_src = (const int*)d_in[32];
    const int* loss_dst = (const int*)d_in[33];
    const int E = in_sizes[30];
    const int N = out_size / 128;
    (void)n_in;

    char* base = (char*)d_ws;
    size_t off_b = 0;
    auto alloc = [&](size_t bytes) {
        size_t cur = off_b;
        off_b += (bytes + 255) & ~(size_t)255;
        return (void*)(base + cur);
    };
    ushort* Y    = (ushort*)alloc((size_t)E * 128 * 2);
    float*  hacc = (float*)alloc((size_t)N * 128 * 4);
    ushort* h    = (ushort*)alloc((size_t)N * 128 * 2);
    ushort* hu   = (ushort*)alloc((size_t)N * 128 * 2);
    ushort* hv   = (ushort*)alloc((size_t)N * 128 * 2);
    ushort* fh   = (ushort*)alloc((size_t)N * 256 * 2);
    int* cntw  = (int*)alloc((size_t)N * 4);
    int* cntl  = (int*)alloc((size_t)N * 4);
    int* offw  = (int*)alloc((size_t)(N + 1) * 4);
    int* offl  = (int*)alloc((size_t)(N + 1) * 4);
    int* curw  = (int*)alloc((size_t)N * 4);
    int* curl  = (int*)alloc((size_t)N * 4);
    int* permw = (int*)alloc((size_t)E * 4);
    int* ipermw= (int*)alloc((size_t)E * 4);
    int* ssrcw = (int*)alloc((size_t)E * 4);
    int* sdstw = (int*)alloc((size_t)E * 4);
    int* perml = (int*)alloc((size_t)E * 4);
    int* iperml= (int*)alloc((size_t)E * 4);
    int* ssrcl = (int*)alloc((size_t)E * 4);
    int* sdstl = (int*)alloc((size_t)E * 4);
    float* psum = (float*)alloc((size_t)NPART_MAX * 256 * 4);
    float* psq  = (float*)alloc((size_t)NPART_MAX * 256 * 4);
    float* scal = (float*)alloc(256 * 4);
    float* shif = (float*)alloc(256 * 4);
    ushort* Wp  = (ushort*)alloc((size_t)256 * 128 * 2);
    float* beff = (float*)alloc(128 * 4);
    size_t off_noxbf = off_b;
    ushort* Xbf = (ushort*)alloc((size_t)E * 128 * 2);
    bool have_xbf = (off_b <= ws_size);
    if (off_noxbf > ws_size) return;   // even base layout doesn't fit

    const int gE = (E + 127) / 128;
    const int gN = (N + 127) / 128;
    const int gR = (N + 3) / 4;
    const int NBF = 1024;
    const int NBG = 1024;
    const int NBN = 512;

    auto fold = [&](int nblk, int M, int C, const BP& p) {
        reduce_stats<<<C, 256, 0, stream>>>(psum, psq, nblk, C, M, p.g, p.b, scal, shif);
        pack_fold<<<1, 256, 0, stream>>>(scal, shif, C, p.W, p.bias, Wp, beff);
    };

    // phase 0: counting sort per etype
    hipMemsetAsync(cntw, 0, (size_t)N * 4, stream);
    hipMemsetAsync(cntl, 0, (size_t)N * 4, stream);
    hipMemsetAsync(hacc, 0, (size_t)N * 128 * 4, stream);
    hist_kernel<<<1024, 256, 0, stream>>>(win_dst,  E, cntw);
    hist_kernel<<<1024, 256, 0, stream>>>(loss_dst, E, cntl);
    scan_kernel<<<1, 256, 0, stream>>>(cntw, N, offw, curw);
    scan_kernel<<<1, 256, 0, stream>>>(cntl, N, offl, curl);
    scatter_kernel<<<1024, 256, 0, stream>>>(win_src,  win_dst,  E, curw, permw, ipermw, ssrcw, sdstw);
    scatter_kernel<<<1024, 256, 0, stream>>>(loss_src, loss_dst, E, curl, perml, iperml, ssrcl, sdstl);

    if (have_xbf) {
        // initial edge blocks (fused segmented-mean epilogue)
        convert_stats_f32<<<NBF, 256, 0, stream>>>((const float4*)win_f, ipermw, E,
                                                   (uint2*)Xbf, psum, psq);
        fold(NBF, E, 128, wi);
        gemm_mfma_seg<<<gE, 256, 0, stream>>>(Xbf, sdstw, cntw, Wp, beff, hacc, E);

        convert_stats_f32<<<NBF, 256, 0, stream>>>((const float4*)loss_f, iperml, E,
                                                   (uint2*)Xbf, psum, psq);
        fold(NBF, E, 128, li);
        gemm_mfma_seg<<<gE, 256, 0, stream>>>(Xbf, sdstl, cntl, Wp, beff, hacc, E);
        finalize_hacc<<<512, 256, 0, stream>>>((float2*)hacc, (uint*)h, (uint*)fh, 0, N);

        for (int it = 0; it < 3; ++it) {
            colstats_bf16_direct<128><<<NBN, 256, 0, stream>>>(h, N, psum, psq);
            fold(NBN, N, 128, srcp);
            gemm_mfma<4, false, false, false><<<gN, 256, 0, stream>>>(
                h, nullptr, nullptr, nullptr, nullptr, Wp, beff, hu, nullptr, N);
            fold(NBN, N, 128, dstp);
            gemm_mfma<4, false, false, false><<<gN, 256, 0, stream>>>(
                h, nullptr, nullptr, nullptr, nullptr, Wp, beff, hv, nullptr, N);

            colstats_gather2<<<NBG, 256, 0, stream>>>((const uint*)hu, (const uint*)hv,
                                                      ssrcw, sdstw, E, (uint*)Xbf, psum, psq);
            fold(NBG, E, 128, wl);
            gemm_mfma_seg<<<gE, 256, 0, stream>>>(Xbf, sdstw, cntw, Wp, beff, hacc, E);

            colstats_gather2<<<NBG, 256, 0, stream>>>((const uint*)hu, (const uint*)hv,
                                                      ssrcl, sdstl, E, (uint*)Xbf, psum, psq);
            fold(NBG, E, 128, ll);
            gemm_mfma_seg<<<gE, 256, 0, stream>>>(Xbf, sdstl, cntl, Wp, beff, hacc, E);
            finalize_hacc<<<512, 256, 0, stream>>>((float2*)hacc, (uint*)h, (uint*)fh,
                                                   (it == 2) ? 1 : -1, N);
        }
    } else {
        // fallback: Y + reduce_half path (no Xbf)
        colstats_f32_128<<<NBF, 256, 0, stream>>>(win_f, E, psum, psq);
        fold(NBF, E, 128, wi);
        gemm_mfma<4, false, true, false><<<gE, 256, 0, stream>>>(
            nullptr, nullptr, win_f, permw, nullptr, Wp, beff, Y, nullptr, E);
        reduce_half<true><<<gR, 256, 0, stream>>>((const uint*)Y, offw, (float2*)hacc, nullptr, nullptr, -1, N);

        colstats_f32_128<<<NBF, 256, 0, stream>>>(loss_f, E, psum, psq);
        fold(NBF, E, 128, li);
        gemm_mfma<4, false, true, false><<<gE, 256, 0, stream>>>(
            nullptr, nullptr, loss_f, perml, nullptr, Wp, beff, Y, nullptr, E);
        reduce_half<false><<<gR, 256, 0, stream>>>((const uint*)Y, offl, (float2*)hacc, (uint*)h, (uint*)fh, 0, N);

        for (int it = 0; it < 3; ++it) {
            colstats_bf16_direct<128><<<NBN, 256, 0, stream>>>(h, N, psum, psq);
            fold(NBN, N, 128, srcp);
            gemm_mfma<4, false, false, false><<<gN, 256, 0, stream>>>(
                h, nullptr, nullptr, nullptr, nullptr, Wp, beff, hu, nullptr, N);
            fold(NBN, N, 128, dstp);
            gemm_mfma<4, false, false, false><<<gN, 256, 0, stream>>>(
                h, nullptr, nullptr, nullptr, nullptr, Wp, beff, hv, nullptr, N);

            colstats_gather2<<<NBG, 256, 0, stream>>>((const uint*)hu, (const uint*)hv,
                                                      ssrcw, sdstw, E, nullptr, psum, psq);
            fold(NBG, E, 128, wl);
            gemm_mfma<4, true, false, false><<<gE, 256, 0, stream>>>(
                hu, hv, nullptr, ssrcw, sdstw, Wp, beff, Y, nullptr, E);
            reduce_half<true><<<gR, 256, 0, stream>>>((const uint*)Y, offw, (float2*)hacc, nullptr, nullptr, -1, N);

            colstats_gather2<<<NBG, 256, 0, stream>>>((const uint*)hu, (const uint*)hv,
                                                      ssrcl, sdstl, E, nullptr, psum, psq);
            fold(NBG, E, 128, ll);
            gemm_mfma<4, true, false, false><<<gE, 256, 0, stream>>>(
                hu, hv, nullptr, ssrcl, sdstl, Wp, beff, Y, nullptr, E);
            reduce_half<false><<<gR, 256, 0, stream>>>((const uint*)Y, offl, (float2*)hacc, (uint*)h, (uint*)fh,
                                                       (it == 2) ? 1 : -1, N);
        }
    }

    colstats_bf16_direct<256><<<NBN, 256, 0, stream>>>(fh, N, psum, psq);
    fold(NBN, N, 256, outp);
    gemm_mfma<8, false, false, true><<<gN, 256, 0, stream>>>(
        fh, nullptr, nullptr, nullptr, nullptr, Wp, beff, nullptr, (float*)d_out, N);
}

// Round 8
// 1110.105 us; speedup vs baseline: 4.2507x; 1.3597x over previous
//
#include <hip/hip_runtime.h>

#define NPART_MAX 2048

typedef __attribute__((ext_vector_type(8))) short short8;
typedef __attribute__((ext_vector_type(4))) float f32x4;

__device__ __forceinline__ float bf2f(uint u) {
    union { uint u; float f; } v; v.u = u << 16; return v.f;
}
__device__ __forceinline__ ushort f2bf(float f) {
    union { float f; uint u; } v; v.f = f;
    uint r = v.u + 0x7fffu + ((v.u >> 16) & 1u);
    return (ushort)(r >> 16);
}

// ---------------- phase 0: counting sort by dst (both etypes per launch) ----------------
__global__ __launch_bounds__(256) void hist2(const int* __restrict__ dw, const int* __restrict__ dl,
                                             int E, int* __restrict__ cw, int* __restrict__ cl) {
    const int half = gridDim.x >> 1;
    const bool second = (int)blockIdx.x >= half;
    const int* dst = second ? dl : dw;
    int* cnt = second ? cl : cw;
    const int b = second ? blockIdx.x - half : blockIdx.x;
    for (int e = b * 256 + threadIdx.x; e < E; e += half * 256)
        atomicAdd(&cnt[dst[e]], 1);
}

// 2 blocks: block 0 scans win counts, block 1 loss; 4 elems/thread/chunk
__global__ __launch_bounds__(256) void scan2(const int* __restrict__ cw, const int* __restrict__ cl,
                                             int n, int* offw, int* curw, int* offl, int* curl) {
    const int* cnt = blockIdx.x ? cl : cw;
    int* off = blockIdx.x ? offl : offw;
    int* cur = blockIdx.x ? curl : curw;
    __shared__ int warpsums[4];
    __shared__ int s_carry;
    if (threadIdx.x == 0) s_carry = 0;
    __syncthreads();
    for (int base = 0; base < n; base += 1024) {
        int i0 = base + threadIdx.x * 4;
        int v0 = (i0 + 0 < n) ? cnt[i0 + 0] : 0;
        int v1 = (i0 + 1 < n) ? cnt[i0 + 1] : 0;
        int v2 = (i0 + 2 < n) ? cnt[i0 + 2] : 0;
        int v3 = (i0 + 3 < n) ? cnt[i0 + 3] : 0;
        int tsum = v0 + v1 + v2 + v3;
        int lane = threadIdx.x & 63, w = threadIdx.x >> 6;
        int x = tsum;
        for (int d = 1; d < 64; d <<= 1) {
            int y = __shfl_up(x, d);
            if (lane >= d) x += y;
        }
        if (lane == 63) warpsums[w] = x;
        __syncthreads();
        int woff = 0;
        for (int k = 0; k < w; ++k) woff += warpsums[k];
        int excl = x - tsum + woff + s_carry;
        if (i0 + 0 < n) { off[i0 + 0] = excl; cur[i0 + 0] = excl; } excl += v0;
        if (i0 + 1 < n) { off[i0 + 1] = excl; cur[i0 + 1] = excl; } excl += v1;
        if (i0 + 2 < n) { off[i0 + 2] = excl; cur[i0 + 2] = excl; } excl += v2;
        if (i0 + 3 < n) { off[i0 + 3] = excl; cur[i0 + 3] = excl; } excl += v3;
        __syncthreads();
        if (threadIdx.x == 255) s_carry = excl;
        __syncthreads();
    }
    if (threadIdx.x == 0) off[n] = s_carry;
}

__global__ __launch_bounds__(256) void scatter2(
    const int* __restrict__ sw, const int* __restrict__ dw,
    const int* __restrict__ sl, const int* __restrict__ dl, int E,
    int* __restrict__ curw, int* __restrict__ curl,
    int* __restrict__ ipermw, int* __restrict__ ssrcw, int* __restrict__ sdstw,
    int* __restrict__ iperml, int* __restrict__ ssrcl, int* __restrict__ sdstl) {
    const int half = gridDim.x >> 1;
    const bool second = (int)blockIdx.x >= half;
    const int* src = second ? sl : sw;
    const int* dst = second ? dl : dw;
    int* cursor = second ? curl : curw;
    int* iperm = second ? iperml : ipermw;
    int* ssrc = second ? ssrcl : ssrcw;
    int* sdst = second ? sdstl : sdstw;
    const int b = second ? blockIdx.x - half : blockIdx.x;
    for (int e = b * 256 + threadIdx.x; e < E; e += half * 256) {
        int d = dst[e];
        int p = atomicAdd(&cursor[d], 1);
        iperm[e] = p;
        ssrc[p] = src[e];
        sdst[p] = d;
    }
}

// ---------------- fused fp32 col-stats + bf16 convert into sorted slots ----------------
__global__ __launch_bounds__(256) void convert_stats_f32(
    const float4* __restrict__ x4, const int* __restrict__ iperm, int M,
    uint2* __restrict__ xb4, float* __restrict__ psum, float* __restrict__ psq) {
    const int cg = threadIdx.x & 31;
    const int sub = threadIdx.x >> 5;
    float s0=0,s1=0,s2=0,s3=0,q0=0,q1=0,q2=0,q3=0;
    for (int r = blockIdx.x * 8 + sub; r < M; r += gridDim.x * 8) {
        float4 v = x4[(size_t)r * 32 + cg];
        int p = iperm[r];
        uint2 o;
        o.x = (uint)f2bf(v.x) | ((uint)f2bf(v.y) << 16);
        o.y = (uint)f2bf(v.z) | ((uint)f2bf(v.w) << 16);
        xb4[(size_t)p * 32 + cg] = o;
        s0 += v.x; q0 += v.x * v.x;
        s1 += v.y; q1 += v.y * v.y;
        s2 += v.z; q2 += v.z * v.z;
        s3 += v.w; q3 += v.w * v.w;
    }
    __shared__ float rs[256][4], rq[256][4];
    rs[threadIdx.x][0]=s0; rs[threadIdx.x][1]=s1; rs[threadIdx.x][2]=s2; rs[threadIdx.x][3]=s3;
    rq[threadIdx.x][0]=q0; rq[threadIdx.x][1]=q1; rq[threadIdx.x][2]=q2; rq[threadIdx.x][3]=q3;
    __syncthreads();
    if (sub == 0) {
        #pragma unroll
        for (int k = 1; k < 8; ++k) {
            s0 += rs[k*32+cg][0]; s1 += rs[k*32+cg][1];
            s2 += rs[k*32+cg][2]; s3 += rs[k*32+cg][3];
            q0 += rq[k*32+cg][0]; q1 += rq[k*32+cg][1];
            q2 += rq[k*32+cg][2]; q3 += rq[k*32+cg][3];
        }
        psum[blockIdx.x*128 + cg*4+0] = s0; psq[blockIdx.x*128 + cg*4+0] = q0;
        psum[blockIdx.x*128 + cg*4+1] = s1; psq[blockIdx.x*128 + cg*4+1] = q1;
        psum[blockIdx.x*128 + cg*4+2] = s2; psq[blockIdx.x*128 + cg*4+2] = q2;
        psum[blockIdx.x*128 + cg*4+3] = s3; psq[blockIdx.x*128 + cg*4+3] = q3;
    }
}

// ---------------- vectorized bf16 col-stats (C=128, uint loads) ----------------
__global__ __launch_bounds__(256) void colstats_b128(const uint* __restrict__ x2, int M,
                                                     float* __restrict__ psum, float* __restrict__ psq) {
    const int cl = threadIdx.x & 63;
    const int sub = threadIdx.x >> 6;
    float s0=0,s1=0,q0=0,q1=0;
    for (int r = blockIdx.x * 4 + sub; r < M; r += gridDim.x * 4) {
        uint u = x2[(size_t)r * 64 + cl];
        float a = bf2f(u & 0xffffu), b = bf2f(u >> 16);
        s0 += a; q0 += a * a;
        s1 += b; q1 += b * b;
    }
    __shared__ float red[4][64][4];
    red[sub][cl][0]=s0; red[sub][cl][1]=s1; red[sub][cl][2]=q0; red[sub][cl][3]=q1;
    __syncthreads();
    if (sub == 0) {
        #pragma unroll
        for (int k = 1; k < 4; ++k) {
            s0 += red[k][cl][0]; s1 += red[k][cl][1];
            q0 += red[k][cl][2]; q1 += red[k][cl][3];
        }
        psum[blockIdx.x*128 + 2*cl]   = s0; psq[blockIdx.x*128 + 2*cl]   = q0;
        psum[blockIdx.x*128 + 2*cl+1] = s1; psq[blockIdx.x*128 + 2*cl+1] = q1;
    }
}

// C=256 variant (for fh)
__global__ __launch_bounds__(256) void colstats_b256(const uint* __restrict__ x2, int M,
                                                     float* __restrict__ psum, float* __restrict__ psq) {
    const int cl = threadIdx.x & 127;
    const int sub = threadIdx.x >> 7;
    float s0=0,s1=0,q0=0,q1=0;
    for (int r = blockIdx.x * 2 + sub; r < M; r += gridDim.x * 2) {
        uint u = x2[(size_t)r * 128 + cl];
        float a = bf2f(u & 0xffffu), b = bf2f(u >> 16);
        s0 += a; q0 += a * a;
        s1 += b; q1 += b * b;
    }
    __shared__ float red[2][128][4];
    red[sub][cl][0]=s0; red[sub][cl][1]=s1; red[sub][cl][2]=q0; red[sub][cl][3]=q1;
    __syncthreads();
    if (sub == 0) {
        s0 += red[1][cl][0]; s1 += red[1][cl][1];
        q0 += red[1][cl][2]; q1 += red[1][cl][3];
        psum[blockIdx.x*256 + 2*cl]   = s0; psq[blockIdx.x*256 + 2*cl]   = q0;
        psum[blockIdx.x*256 + 2*cl+1] = s1; psq[blockIdx.x*256 + 2*cl+1] = q1;
    }
}

// ---------------- gather stats v2: 2 edges/step, uint2 loads, fused Xbf write ----------------
__global__ __launch_bounds__(256) void colstats_gather2(
    const uint2* __restrict__ hu4, const uint2* __restrict__ hv4,
    const int* __restrict__ sidx, const int* __restrict__ didx, int E,
    uint2* __restrict__ xout, float* __restrict__ psum, float* __restrict__ psq) {
    const int lane = threadIdx.x & 63;
    const int w = threadIdx.x >> 6;
    const int half = lane >> 5;
    const int cg = lane & 31;
    const int gwave = (blockIdx.x * 256 + threadIdx.x) >> 6;
    const int nwave = (gridDim.x * 256) >> 6;
    float s0=0,s1=0,s2=0,s3=0,q0=0,q1=0,q2=0,q3=0;
    for (int base = gwave * 64; base < E; base += nwave * 64) {
        int e = base + lane;
        int su = (e < E) ? sidx[e] : 0;
        int dv = (e < E) ? didx[e] : 0;
        int cnt = min(64, E - base);
        #pragma unroll 4
        for (int j = 0; j < 32; ++j) {
            int eidx = 2 * j + half;
            int a = __shfl(su, eidx), b = __shfl(dv, eidx);
            if (eidx < cnt) {
                uint2 uu = hu4[(size_t)a * 32 + cg];
                uint2 vv = hv4[(size_t)b * 32 + cg];
                float v0 = bf2f(uu.x & 0xffffu) + bf2f(vv.x & 0xffffu);
                float v1 = bf2f(uu.x >> 16)     + bf2f(vv.x >> 16);
                float v2 = bf2f(uu.y & 0xffffu) + bf2f(vv.y & 0xffffu);
                float v3 = bf2f(uu.y >> 16)     + bf2f(vv.y >> 16);
                uint2 o;
                o.x = (uint)f2bf(v0) | ((uint)f2bf(v1) << 16);
                o.y = (uint)f2bf(v2) | ((uint)f2bf(v3) << 16);
                xout[(size_t)(base + eidx) * 32 + cg] = o;
                s0 += v0; q0 += v0 * v0;
                s1 += v1; q1 += v1 * v1;
                s2 += v2; q2 += v2 * v2;
                s3 += v3; q3 += v3 * v3;
            }
        }
    }
    __shared__ float redS[8][32][4], redQ[8][32][4];
    const int ri = w * 2 + half;
    redS[ri][cg][0]=s0; redS[ri][cg][1]=s1; redS[ri][cg][2]=s2; redS[ri][cg][3]=s3;
    redQ[ri][cg][0]=q0; redQ[ri][cg][1]=q1; redQ[ri][cg][2]=q2; redQ[ri][cg][3]=q3;
    __syncthreads();
    if (threadIdx.x < 128) {
        int c = threadIdx.x;
        int cgg = c >> 2, k = c & 3;
        float s = 0.f, q = 0.f;
        #pragma unroll
        for (int i = 0; i < 8; ++i) { s += redS[i][cgg][k]; q += redQ[i][cgg][k]; }
        psum[(size_t)blockIdx.x * 128 + c] = s;
        psq [(size_t)blockIdx.x * 128 + c] = q;
    }
}

// ---------------- per-column reduce of partials -> scale/shift (double accum, dual g/b) ----------------
__global__ __launch_bounds__(256) void reduce_stats(
    const float* __restrict__ psum, const float* __restrict__ psq,
    int nblk, int C, int M,
    const float* __restrict__ g1, const float* __restrict__ b1,
    float* __restrict__ scale1, float* __restrict__ shift1,
    const float* g2, const float* b2, float* scale2, float* shift2) {
    const int c = blockIdx.x;
    double s = 0.0, q = 0.0;
    for (int i = threadIdx.x; i < nblk; i += 256) {
        s += (double)psum[(size_t)i * C + c];
        q += (double)psq [(size_t)i * C + c];
    }
    __shared__ double ss[256], qs[256];
    ss[threadIdx.x] = s; qs[threadIdx.x] = q;
    __syncthreads();
    for (int d = 128; d > 0; d >>= 1) {
        if (threadIdx.x < d) {
            ss[threadIdx.x] += ss[threadIdx.x + d];
            qs[threadIdx.x] += qs[threadIdx.x + d];
        }
        __syncthreads();
    }
    if (threadIdx.x == 0) {
        double m = ss[0] / (double)M;
        double v = qs[0] / (double)M - m * m;
        if (v < 0.0) v = 0.0;
        double rs = 1.0 / sqrt(v + 1e-5);
        float mf = (float)m;
        float sc1 = (float)(rs * (double)g1[c]);
        scale1[c] = sc1;
        shift1[c] = b1[c] - mf * sc1;
        if (g2) {
            float sc2 = (float)(rs * (double)g2[c]);
            scale2[c] = sc2;
            shift2[c] = b2[c] - mf * sc2;
        }
    }
}

// ---------------- parallel BN fold + MFMA-fragment pack ----------------
// grid = KT + 8: first KT blocks pack fragments via LDS slab; last 8 compute beff (16 d each)
__global__ __launch_bounds__(256) void pack_fold_par(
    const float* __restrict__ scale, const float* __restrict__ shift, int C,
    const float* __restrict__ W, const float* __restrict__ bias,
    ushort* __restrict__ Wp, float* __restrict__ beff) {
    const int KT = C / 32;
    if ((int)blockIdx.x < KT) {
        const int kt = blockIdx.x;
        __shared__ float slab[32 * 128];
        for (int i = threadIdx.x; i < 32 * 128; i += 256) {
            int kr = i >> 7, d = i & 127;
            int c = kt * 32 + kr;
            slab[i] = W[(size_t)c * 128 + d] * scale[c];
        }
        __syncthreads();
        #pragma unroll
        for (int t0 = 0; t0 < 512; t0 += 256) {
            int t = t0 + threadIdx.x;
            int lane = t & 63, dt = t >> 6;
            int d = dt * 16 + (lane & 15);
            int kb = (lane >> 4) * 8;
            uint4 o;
            o.x = (uint)f2bf(slab[(kb+0)*128 + d]) | ((uint)f2bf(slab[(kb+1)*128 + d]) << 16);
            o.y = (uint)f2bf(slab[(kb+2)*128 + d]) | ((uint)f2bf(slab[(kb+3)*128 + d]) << 16);
            o.z = (uint)f2bf(slab[(kb+4)*128 + d]) | ((uint)f2bf(slab[(kb+5)*128 + d]) << 16);
            o.w = (uint)f2bf(slab[(kb+6)*128 + d]) | ((uint)f2bf(slab[(kb+7)*128 + d]) << 16);
            *(uint4*)(Wp + (size_t)((dt * KT + kt) * 64 + lane) * 8) = o;
        }
    } else {
        const int bb = blockIdx.x - KT;          // 0..7 -> d = bb*16..+15
        const int dl = threadIdx.x & 15, ci = threadIdx.x >> 4;
        const int d = bb * 16 + dl;
        float a = 0.f;
        for (int c = ci; c < C; c += 16)
            a += shift[c] * W[(size_t)c * 128 + d];
        __shared__ float red[256];
        red[threadIdx.x] = a;
        __syncthreads();
        if (ci == 0) {
            #pragma unroll
            for (int k = 1; k < 16; ++k) a += red[k * 16 + dl];
            beff[d] = bias[d] + a;
        }
    }
}

// ---------------- MFMA GEMM: Y[row][d] = relu( X[row] @ Weff + beff ) ----------------
template<int KT, bool OUTF32>
__global__ __launch_bounds__(256) void gemm_mfma(
    const ushort* __restrict__ X,
    const ushort* __restrict__ Wp, const float* __restrict__ beff,
    ushort* __restrict__ Yb, float* __restrict__ Yf, int M) {
    constexpr int K = KT * 32;
    const int lane = threadIdx.x & 63;
    const int w = threadIdx.x >> 6;
    const int r0 = blockIdx.x * 128 + w * 32;
    const int rlo = lane & 15, khi = lane >> 4;

    f32x4 acc[2][8];
    #pragma unroll
    for (int rt = 0; rt < 2; ++rt)
        #pragma unroll
        for (int dt = 0; dt < 8; ++dt)
            acc[rt][dt] = (f32x4){0.f, 0.f, 0.f, 0.f};

    int row[2], idx[2];
    bool ok[2];
    #pragma unroll
    for (int rt = 0; rt < 2; ++rt) {
        row[rt] = r0 + rt * 16 + rlo;
        ok[rt] = row[rt] < M;
        idx[rt] = ok[rt] ? row[rt] : 0;
    }

    for (int kt = 0; kt < KT; ++kt) {
        short8 wf[8];
        #pragma unroll
        for (int dt = 0; dt < 8; ++dt)
            wf[dt] = *(const short8*)(Wp + (size_t)((dt * KT + kt) * 64 + lane) * 8);
        #pragma unroll
        for (int rt = 0; rt < 2; ++rt) {
            short8 bv = *(const short8*)(X + (size_t)idx[rt] * K + kt * 32 + khi * 8);
            #pragma unroll
            for (int dt = 0; dt < 8; ++dt)
                acc[rt][dt] = __builtin_amdgcn_mfma_f32_16x16x32_bf16(wf[dt], bv, acc[rt][dt], 0, 0, 0);
        }
    }

    #pragma unroll
    for (int rt = 0; rt < 2; ++rt) {
        if (!ok[rt]) continue;
        #pragma unroll
        for (int dt = 0; dt < 8; ++dt) {
            const float4 bz = *(const float4*)(beff + dt * 16 + khi * 4);
            float v0 = fmaxf(acc[rt][dt][0] + bz.x, 0.f);
            float v1 = fmaxf(acc[rt][dt][1] + bz.y, 0.f);
            float v2 = fmaxf(acc[rt][dt][2] + bz.z, 0.f);
            float v3 = fmaxf(acc[rt][dt][3] + bz.w, 0.f);
            if constexpr (OUTF32) {
                *(float4*)(Yf + (size_t)row[rt] * 128 + dt * 16 + khi * 4) = make_float4(v0, v1, v2, v3);
            } else {
                uint2 pk;
                pk.x = (uint)f2bf(v0) | ((uint)f2bf(v1) << 16);
                pk.y = (uint)f2bf(v2) | ((uint)f2bf(v3) << 16);
                *(uint2*)(Yb + (size_t)row[rt] * 128 + dt * 16 + khi * 4) = pk;
            }
        }
    }
}

// ---------------- MFMA GEMM with fused segmented-mean epilogue ----------------
__global__ __launch_bounds__(256) void gemm_mfma_seg(
    const ushort* __restrict__ X, const int* __restrict__ sdst,
    const int* __restrict__ cnt,
    const ushort* __restrict__ Wp, const float* __restrict__ beff,
    float* __restrict__ hacc, int M) {
    constexpr int KT = 4;
    __shared__ ushort tile[128 * 132];
    __shared__ int   s_node[128];
    __shared__ float s_scale[128];
    const int tid = threadIdx.x;
    const int lane = tid & 63;
    const int w = tid >> 6;
    const int rb = blockIdx.x * 128;
    const int r0 = rb + w * 32;
    const int rlo = lane & 15, khi = lane >> 4;

    if (tid < 128) {
        int r = rb + tid;
        int nd = (r < M) ? sdst[r] : -1;
        s_node[tid] = nd;
        s_scale[tid] = (nd >= 0) ? 0.5f / fmaxf((float)cnt[nd], 1.f) : 0.f;
    }

    f32x4 acc[2][8];
    #pragma unroll
    for (int rt = 0; rt < 2; ++rt)
        #pragma unroll
        for (int dt = 0; dt < 8; ++dt)
            acc[rt][dt] = (f32x4){0.f, 0.f, 0.f, 0.f};

    int row[2], idx[2];
    bool ok[2];
    #pragma unroll
    for (int rt = 0; rt < 2; ++rt) {
        row[rt] = r0 + rt * 16 + rlo;
        ok[rt] = row[rt] < M;
        idx[rt] = ok[rt] ? row[rt] : 0;
    }

    for (int kt = 0; kt < KT; ++kt) {
        short8 wf[8];
        #pragma unroll
        for (int dt = 0; dt < 8; ++dt)
            wf[dt] = *(const short8*)(Wp + (size_t)((dt * KT + kt) * 64 + lane) * 8);
        #pragma unroll
        for (int rt = 0; rt < 2; ++rt) {
            short8 bv = *(const short8*)(X + (size_t)idx[rt] * 128 + kt * 32 + khi * 8);
            #pragma unroll
            for (int dt = 0; dt < 8; ++dt)
                acc[rt][dt] = __builtin_amdgcn_mfma_f32_16x16x32_bf16(wf[dt], bv, acc[rt][dt], 0, 0, 0);
        }
    }

    // deposit bf16 outputs into LDS tile (block-local row = w*32 + rt*16 + rlo)
    #pragma unroll
    for (int rt = 0; rt < 2; ++rt) {
        const int rl = w * 32 + rt * 16 + rlo;
        #pragma unroll
        for (int dt = 0; dt < 8; ++dt) {
            const float4 bz = *(const float4*)(beff + dt * 16 + khi * 4);
            float v0 = 0.f, v1 = 0.f, v2 = 0.f, v3 = 0.f;
            if (ok[rt]) {
                v0 = fmaxf(acc[rt][dt][0] + bz.x, 0.f);
                v1 = fmaxf(acc[rt][dt][1] + bz.y, 0.f);
                v2 = fmaxf(acc[rt][dt][2] + bz.z, 0.f);
                v3 = fmaxf(acc[rt][dt][3] + bz.w, 0.f);
            }
            uint2 pk;
            pk.x = (uint)f2bf(v0) | ((uint)f2bf(v1) << 16);
            pk.y = (uint)f2bf(v2) | ((uint)f2bf(v3) << 16);
            *(uint2*)&tile[rl * 132 + dt * 16 + khi * 4] = pk;
        }
    }
    __syncthreads();

    // per-column segmented reduce over sorted runs; one atomic per (run, col)
    const int col = tid & 127;
    const int rs = (tid >> 7) * 64;
    int cur = s_node[rs];
    float scl = s_scale[rs];
    float sum = 0.f;
    for (int r = rs; r < rs + 64; ++r) {
        int nd = s_node[r];
        if (nd != cur) {
            if (cur >= 0)
                atomicAdd(&hacc[(size_t)cur * 128 + col], sum * scl);
            cur = nd; scl = s_scale[r]; sum = 0.f;
        }
        sum += bf2f(tile[r * 132 + col]);
    }
    if (cur >= 0)
        atomicAdd(&hacc[(size_t)cur * 128 + col], sum * scl);
}

// ---------------- hacc -> bf16 h (+fh half), re-zero hacc ----------------
__global__ __launch_bounds__(256) void finalize_hacc(
    float2* __restrict__ hacc2, uint* __restrict__ h2, uint* __restrict__ fh2,
    int fhsel, int N) {
    const int total = N * 64;
    for (int i = blockIdx.x * 256 + threadIdx.x; i < total; i += gridDim.x * 256) {
        float2 v = hacc2[i];
        uint pk = (uint)f2bf(v.x) | ((uint)f2bf(v.y) << 16);
        h2[i] = pk;
        if (fhsel >= 0) fh2[((size_t)(i >> 6)) * 128 + fhsel * 64 + (i & 63)] = pk;
        hacc2[i] = make_float2(0.f, 0.f);
    }
}

// ---------------- launch ----------------
extern "C" void kernel_launch(void* const* d_in, const int* in_sizes, int n_in,
                              void* d_out, int out_size, void* d_ws, size_t ws_size,
                              hipStream_t stream) {
    const float* win_f  = (const float*)d_in[0];
    const float* loss_f = (const float*)d_in[1];
    struct BP { const float *g, *b, *W, *bias; };
    auto bp = [&](int i) { return BP{ (const float*)d_in[i], (const float*)d_in[i+1],
                                      (const float*)d_in[i+2], (const float*)d_in[i+3] }; };
    BP wi = bp(2), li = bp(6), srcp = bp(10), dstp = bp(14), wl = bp(18), ll = bp(22), outp = bp(26);
    const int* win_src  = (const int*)d_in[30];
    const int* win_dst  = (const int*)d_in[31];
    const int* loss_src = (const int*)d_in[32];
    const int* loss_dst = (const int*)d_in[33];
    const int E = in_sizes[30];
    const int N = out_size / 128;
    (void)n_in;

    char* base = (char*)d_ws;
    size_t off_b = 0;
    auto alloc = [&](size_t bytes) {
        size_t cur = off_b;
        off_b += (bytes + 255) & ~(size_t)255;
        return (void*)(base + cur);
    };
    float*  hacc = (float*)alloc((size_t)N * 128 * 4);
    ushort* h    = (ushort*)alloc((size_t)N * 128 * 2);
    ushort* hu   = (ushort*)alloc((size_t)N * 128 * 2);
    ushort* hv   = (ushort*)alloc((size_t)N * 128 * 2);
    ushort* fh   = (ushort*)alloc((size_t)N * 256 * 2);
    int* cntw  = (int*)alloc((size_t)N * 4);
    int* cntl  = (int*)alloc((size_t)N * 4);
    int* offw  = (int*)alloc((size_t)(N + 1) * 4);
    int* offl  = (int*)alloc((size_t)(N + 1) * 4);
    int* curw  = (int*)alloc((size_t)N * 4);
    int* curl  = (int*)alloc((size_t)N * 4);
    int* ipermw= (int*)alloc((size_t)E * 4);
    int* ssrcw = (int*)alloc((size_t)E * 4);
    int* sdstw = (int*)alloc((size_t)E * 4);
    int* iperml= (int*)alloc((size_t)E * 4);
    int* ssrcl = (int*)alloc((size_t)E * 4);
    int* sdstl = (int*)alloc((size_t)E * 4);
    float* psum = (float*)alloc((size_t)NPART_MAX * 256 * 4);
    float* psq  = (float*)alloc((size_t)NPART_MAX * 256 * 4);
    float* scal1 = (float*)alloc(256 * 4);
    float* shif1 = (float*)alloc(256 * 4);
    float* scal2 = (float*)alloc(256 * 4);
    float* shif2 = (float*)alloc(256 * 4);
    ushort* Wp1 = (ushort*)alloc((size_t)256 * 128 * 2);
    ushort* Wp2 = (ushort*)alloc((size_t)256 * 128 * 2);
    float* beff1 = (float*)alloc(128 * 4);
    float* beff2 = (float*)alloc(128 * 4);
    ushort* Xbf = (ushort*)alloc((size_t)E * 128 * 2);
    if (off_b > ws_size) return;   // workspace too small: bail

    const int gE = (E + 127) / 128;
    const int gN = (N + 127) / 128;
    const int NBF = 1024;   // fp32 convert-stats blocks
    const int NBG = 2048;   // gather-stats blocks
    const int NBN = 512;    // node-stats blocks

    // phase 0: counting sort per etype (both etypes per launch)
    hipMemsetAsync(cntw, 0, (size_t)N * 4, stream);
    hipMemsetAsync(cntl, 0, (size_t)N * 4, stream);
    hipMemsetAsync(hacc, 0, (size_t)N * 128 * 4, stream);
    hist2<<<2048, 256, 0, stream>>>(win_dst, loss_dst, E, cntw, cntl);
    scan2<<<2, 256, 0, stream>>>(cntw, cntl, N, offw, curw, offl, curl);
    scatter2<<<2048, 256, 0, stream>>>(win_src, win_dst, loss_src, loss_dst, E,
                                       curw, curl, ipermw, ssrcw, sdstw, iperml, ssrcl, sdstl);

    // initial edge blocks (fused segmented-mean epilogue)
    convert_stats_f32<<<NBF, 256, 0, stream>>>((const float4*)win_f, ipermw, E,
                                               (uint2*)Xbf, psum, psq);
    reduce_stats<<<128, 256, 0, stream>>>(psum, psq, NBF, 128, E, wi.g, wi.b, scal1, shif1,
                                          nullptr, nullptr, nullptr, nullptr);
    pack_fold_par<<<12, 256, 0, stream>>>(scal1, shif1, 128, wi.W, wi.bias, Wp1, beff1);
    gemm_mfma_seg<<<gE, 256, 0, stream>>>(Xbf, sdstw, cntw, Wp1, beff1, hacc, E);

    convert_stats_f32<<<NBF, 256, 0, stream>>>((const float4*)loss_f, iperml, E,
                                               (uint2*)Xbf, psum, psq);
    reduce_stats<<<128, 256, 0, stream>>>(psum, psq, NBF, 128, E, li.g, li.b, scal1, shif1,
                                          nullptr, nullptr, nullptr, nullptr);
    pack_fold_par<<<12, 256, 0, stream>>>(scal1, shif1, 128, li.W, li.bias, Wp1, beff1);
    gemm_mfma_seg<<<gE, 256, 0, stream>>>(Xbf, sdstl, cntl, Wp1, beff1, hacc, E);
    finalize_hacc<<<512, 256, 0, stream>>>((float2*)hacc, (uint*)h, (uint*)fh, 0, N);

    for (int it = 0; it < 3; ++it) {
        colstats_b128<<<NBN, 256, 0, stream>>>((const uint*)h, N, psum, psq);
        reduce_stats<<<128, 256, 0, stream>>>(psum, psq, NBN, 128, N, srcp.g, srcp.b, scal1, shif1,
                                              dstp.g, dstp.b, scal2, shif2);
        pack_fold_par<<<12, 256, 0, stream>>>(scal1, shif1, 128, srcp.W, srcp.bias, Wp1, beff1);
        pack_fold_par<<<12, 256, 0, stream>>>(scal2, shif2, 128, dstp.W, dstp.bias, Wp2, beff2);
        gemm_mfma<4, false><<<gN, 256, 0, stream>>>(h, Wp1, beff1, hu, nullptr, N);
        gemm_mfma<4, false><<<gN, 256, 0, stream>>>(h, Wp2, beff2, hv, nullptr, N);

        colstats_gather2<<<NBG, 256, 0, stream>>>((const uint2*)hu, (const uint2*)hv,
                                                  ssrcw, sdstw, E, (uint2*)Xbf, psum, psq);
        reduce_stats<<<128, 256, 0, stream>>>(psum, psq, NBG, 128, E, wl.g, wl.b, scal1, shif1,
                                              nullptr, nullptr, nullptr, nullptr);
        pack_fold_par<<<12, 256, 0, stream>>>(scal1, shif1, 128, wl.W, wl.bias, Wp1, beff1);
        gemm_mfma_seg<<<gE, 256, 0, stream>>>(Xbf, sdstw, cntw, Wp1, beff1, hacc, E);

        colstats_gather2<<<NBG, 256, 0, stream>>>((const uint2*)hu, (const uint2*)hv,
                                                  ssrcl, sdstl, E, (uint2*)Xbf, psum, psq);
        reduce_stats<<<128, 256, 0, stream>>>(psum, psq, NBG, 128, E, ll.g, ll.b, scal1, shif1,
                                              nullptr, nullptr, nullptr, nullptr);
        pack_fold_par<<<12, 256, 0, stream>>>(scal1, shif1, 128, ll.W, ll.bias, Wp1, beff1);
        gemm_mfma_seg<<<gE, 256, 0, stream>>>(Xbf, sdstl, cntl, Wp1, beff1, hacc, E);
        finalize_hacc<<<512, 256, 0, stream>>>((float2*)hacc, (uint*)h, (uint*)fh,
                                               (it == 2) ? 1 : -1, N);
    }

    colstats_b256<<<NBN, 256, 0, stream>>>((const uint*)fh, N, psum, psq);
    reduce_stats<<<256, 256, 0, stream>>>(psum, psq, NBN, 256, N, outp.g, outp.b, scal1, shif1,
                                          nullptr, nullptr, nullptr, nullptr);
    pack_fold_par<<<16, 256, 0, stream>>>(scal1, shif1, 256, outp.W, outp.bias, Wp1, beff1);
    gemm_mfma<8, true><<<gN, 256, 0, stream>>>(fh, Wp1, beff1, nullptr, (float*)d_out, N);
}

// Round 9
// 989.083 us; speedup vs baseline: 4.7708x; 1.1224x over previous
//
#include <hip/hip_runtime.h>

#define NPART_MAX 2048

typedef __attribute__((ext_vector_type(8))) short short8;
typedef __attribute__((ext_vector_type(4))) float f32x4;

__device__ __forceinline__ float bf2f(uint u) {
    union { uint u; float f; } v; v.u = u << 16; return v.f;
}
__device__ __forceinline__ ushort f2bf(float f) {
    union { float f; uint u; } v; v.f = f;
    uint r = v.u + 0x7fffu + ((v.u >> 16) & 1u);
    return (ushort)(r >> 16);
}

// ---------------- phase 0: counting sort by dst (both etypes per launch) ----------------
__global__ __launch_bounds__(256) void hist2(const int* __restrict__ dw, const int* __restrict__ dl,
                                             int E, int* __restrict__ cw, int* __restrict__ cl) {
    const int half = gridDim.x >> 1;
    const bool second = (int)blockIdx.x >= half;
    const int* dst = second ? dl : dw;
    int* cnt = second ? cl : cw;
    const int b = second ? blockIdx.x - half : blockIdx.x;
    for (int e = b * 256 + threadIdx.x; e < E; e += half * 256)
        atomicAdd(&cnt[dst[e]], 1);
}

__global__ __launch_bounds__(256) void scan2(const int* __restrict__ cw, const int* __restrict__ cl,
                                             int n, int* offw, int* curw, int* offl, int* curl) {
    const int* cnt = blockIdx.x ? cl : cw;
    int* off = blockIdx.x ? offl : offw;
    int* cur = blockIdx.x ? curl : curw;
    __shared__ int warpsums[4];
    __shared__ int s_carry;
    if (threadIdx.x == 0) s_carry = 0;
    __syncthreads();
    for (int base = 0; base < n; base += 1024) {
        int i0 = base + threadIdx.x * 4;
        int v0 = (i0 + 0 < n) ? cnt[i0 + 0] : 0;
        int v1 = (i0 + 1 < n) ? cnt[i0 + 1] : 0;
        int v2 = (i0 + 2 < n) ? cnt[i0 + 2] : 0;
        int v3 = (i0 + 3 < n) ? cnt[i0 + 3] : 0;
        int tsum = v0 + v1 + v2 + v3;
        int lane = threadIdx.x & 63, w = threadIdx.x >> 6;
        int x = tsum;
        for (int d = 1; d < 64; d <<= 1) {
            int y = __shfl_up(x, d);
            if (lane >= d) x += y;
        }
        if (lane == 63) warpsums[w] = x;
        __syncthreads();
        int woff = 0;
        for (int k = 0; k < w; ++k) woff += warpsums[k];
        int excl = x - tsum + woff + s_carry;
        if (i0 + 0 < n) { off[i0 + 0] = excl; cur[i0 + 0] = excl; } excl += v0;
        if (i0 + 1 < n) { off[i0 + 1] = excl; cur[i0 + 1] = excl; } excl += v1;
        if (i0 + 2 < n) { off[i0 + 2] = excl; cur[i0 + 2] = excl; } excl += v2;
        if (i0 + 3 < n) { off[i0 + 3] = excl; cur[i0 + 3] = excl; } excl += v3;
        __syncthreads();
        if (threadIdx.x == 255) s_carry = excl;
        __syncthreads();
    }
    if (threadIdx.x == 0) off[n] = s_carry;
}

__global__ __launch_bounds__(256) void scatter2(
    const int* __restrict__ sw, const int* __restrict__ dw,
    const int* __restrict__ sl, const int* __restrict__ dl, int E,
    int* __restrict__ curw, int* __restrict__ curl,
    int* __restrict__ ipermw, int* __restrict__ ssrcw, int* __restrict__ sdstw,
    int* __restrict__ iperml, int* __restrict__ ssrcl, int* __restrict__ sdstl) {
    const int half = gridDim.x >> 1;
    const bool second = (int)blockIdx.x >= half;
    const int* src = second ? sl : sw;
    const int* dst = second ? dl : dw;
    int* cursor = second ? curl : curw;
    int* iperm = second ? iperml : ipermw;
    int* ssrc = second ? ssrcl : ssrcw;
    int* sdst = second ? sdstl : sdstw;
    const int b = second ? blockIdx.x - half : blockIdx.x;
    for (int e = b * 256 + threadIdx.x; e < E; e += half * 256) {
        int d = dst[e];
        int p = atomicAdd(&cursor[d], 1);
        iperm[e] = p;
        ssrc[p] = src[e];
        sdst[p] = d;
    }
}

// ---------------- fused fp32 col-stats + bf16 convert into sorted slots ----------------
__device__ __forceinline__ void convert_body(
    int b, int nb, const float4* __restrict__ x4, const int* __restrict__ iperm, int M,
    uint2* __restrict__ xb4, float* __restrict__ psum, float* __restrict__ psq) {
    const int cg = threadIdx.x & 31;
    const int sub = threadIdx.x >> 5;
    float s0=0,s1=0,s2=0,s3=0,q0=0,q1=0,q2=0,q3=0;
    for (int r = b * 8 + sub; r < M; r += nb * 8) {
        float4 v = x4[(size_t)r * 32 + cg];
        int p = iperm[r];
        uint2 o;
        o.x = (uint)f2bf(v.x) | ((uint)f2bf(v.y) << 16);
        o.y = (uint)f2bf(v.z) | ((uint)f2bf(v.w) << 16);
        xb4[(size_t)p * 32 + cg] = o;
        s0 += v.x; q0 += v.x * v.x;
        s1 += v.y; q1 += v.y * v.y;
        s2 += v.z; q2 += v.z * v.z;
        s3 += v.w; q3 += v.w * v.w;
    }
    __shared__ float rs[256][4], rq[256][4];
    rs[threadIdx.x][0]=s0; rs[threadIdx.x][1]=s1; rs[threadIdx.x][2]=s2; rs[threadIdx.x][3]=s3;
    rq[threadIdx.x][0]=q0; rq[threadIdx.x][1]=q1; rq[threadIdx.x][2]=q2; rq[threadIdx.x][3]=q3;
    __syncthreads();
    if (sub == 0) {
        #pragma unroll
        for (int k = 1; k < 8; ++k) {
            s0 += rs[k*32+cg][0]; s1 += rs[k*32+cg][1];
            s2 += rs[k*32+cg][2]; s3 += rs[k*32+cg][3];
            q0 += rq[k*32+cg][0]; q1 += rq[k*32+cg][1];
            q2 += rq[k*32+cg][2]; q3 += rq[k*32+cg][3];
        }
        psum[b*128 + cg*4+0] = s0; psq[b*128 + cg*4+0] = q0;
        psum[b*128 + cg*4+1] = s1; psq[b*128 + cg*4+1] = q1;
        psum[b*128 + cg*4+2] = s2; psq[b*128 + cg*4+2] = q2;
        psum[b*128 + cg*4+3] = s3; psq[b*128 + cg*4+3] = q3;
    }
}

__global__ __launch_bounds__(256) void convert_one(
    const float4* x4, const int* iperm, int M, uint2* xb4, float* psum, float* psq) {
    convert_body(blockIdx.x, gridDim.x, x4, iperm, M, xb4, psum, psq);
}

__global__ __launch_bounds__(256) void convert_two(
    const float4* x4a, const int* iperma, uint2* xb4a, float* psuma, float* psqa,
    const float4* x4b, const int* ipermb, uint2* xb4b, float* psumb, float* psqb, int M) {
    const int half = gridDim.x >> 1;
    const bool second = (int)blockIdx.x >= half;
    const int b = second ? blockIdx.x - half : blockIdx.x;
    convert_body(b, half,
                 second ? x4b : x4a, second ? ipermb : iperma, M,
                 second ? xb4b : xb4a, second ? psumb : psuma, second ? psqb : psqa);
}

// ---------------- vectorized bf16 col-stats ----------------
__global__ __launch_bounds__(256) void colstats_b128(const uint* __restrict__ x2, int M,
                                                     float* __restrict__ psum, float* __restrict__ psq) {
    const int cl = threadIdx.x & 63;
    const int sub = threadIdx.x >> 6;
    float s0=0,s1=0,q0=0,q1=0;
    for (int r = blockIdx.x * 4 + sub; r < M; r += gridDim.x * 4) {
        uint u = x2[(size_t)r * 64 + cl];
        float a = bf2f(u & 0xffffu), b = bf2f(u >> 16);
        s0 += a; q0 += a * a;
        s1 += b; q1 += b * b;
    }
    __shared__ float red[4][64][4];
    red[sub][cl][0]=s0; red[sub][cl][1]=s1; red[sub][cl][2]=q0; red[sub][cl][3]=q1;
    __syncthreads();
    if (sub == 0) {
        #pragma unroll
        for (int k = 1; k < 4; ++k) {
            s0 += red[k][cl][0]; s1 += red[k][cl][1];
            q0 += red[k][cl][2]; q1 += red[k][cl][3];
        }
        psum[blockIdx.x*128 + 2*cl]   = s0; psq[blockIdx.x*128 + 2*cl]   = q0;
        psum[blockIdx.x*128 + 2*cl+1] = s1; psq[blockIdx.x*128 + 2*cl+1] = q1;
    }
}

__global__ __launch_bounds__(256) void colstats_b256(const uint* __restrict__ x2, int M,
                                                     float* __restrict__ psum, float* __restrict__ psq) {
    const int cl = threadIdx.x & 127;
    const int sub = threadIdx.x >> 7;
    float s0=0,s1=0,q0=0,q1=0;
    for (int r = blockIdx.x * 2 + sub; r < M; r += gridDim.x * 2) {
        uint u = x2[(size_t)r * 128 + cl];
        float a = bf2f(u & 0xffffu), b = bf2f(u >> 16);
        s0 += a; q0 += a * a;
        s1 += b; q1 += b * b;
    }
    __shared__ float red[2][128][4];
    red[sub][cl][0]=s0; red[sub][cl][1]=s1; red[sub][cl][2]=q0; red[sub][cl][3]=q1;
    __syncthreads();
    if (sub == 0) {
        s0 += red[1][cl][0]; s1 += red[1][cl][1];
        q0 += red[1][cl][2]; q1 += red[1][cl][3];
        psum[blockIdx.x*256 + 2*cl]   = s0; psq[blockIdx.x*256 + 2*cl]   = q0;
        psum[blockIdx.x*256 + 2*cl+1] = s1; psq[blockIdx.x*256 + 2*cl+1] = q1;
    }
}

// ---------------- dual gather stats (pure stats, no edge-feature write) ----------------
__global__ __launch_bounds__(256) void gather_stats2(
    const uint2* __restrict__ hu4, const uint2* __restrict__ hv4,
    const int* __restrict__ sw, const int* __restrict__ dw,
    float* __restrict__ psumW, float* __restrict__ psqW,
    const int* __restrict__ sl, const int* __restrict__ dl,
    float* __restrict__ psumL, float* __restrict__ psqL, int E) {
    const int gh = gridDim.x >> 1;
    const bool second = (int)blockIdx.x >= gh;
    const int* sidx = second ? sl : sw;
    const int* didx = second ? dl : dw;
    float* psum = second ? psumL : psumW;
    float* psq  = second ? psqL  : psqW;
    const int b = second ? blockIdx.x - gh : blockIdx.x;

    const int lane = threadIdx.x & 63;
    const int w = threadIdx.x >> 6;
    const int half = lane >> 5;
    const int cg = lane & 31;
    const int gwave = (b * 256 + threadIdx.x) >> 6;
    const int nwave = (gh * 256) >> 6;
    float s0=0,s1=0,s2=0,s3=0,q0=0,q1=0,q2=0,q3=0;
    for (int base = gwave * 64; base < E; base += nwave * 64) {
        int e = base + lane;
        int su = (e < E) ? sidx[e] : 0;
        int dv = (e < E) ? didx[e] : 0;
        int cnt = min(64, E - base);
        #pragma unroll 4
        for (int j = 0; j < 32; ++j) {
            int eidx = 2 * j + half;
            int a = __shfl(su, eidx), bb = __shfl(dv, eidx);
            if (eidx < cnt) {
                uint2 uu = hu4[(size_t)a * 32 + cg];
                uint2 vv = hv4[(size_t)bb * 32 + cg];
                float v0 = bf2f(uu.x & 0xffffu) + bf2f(vv.x & 0xffffu);
                float v1 = bf2f(uu.x >> 16)     + bf2f(vv.x >> 16);
                float v2 = bf2f(uu.y & 0xffffu) + bf2f(vv.y & 0xffffu);
                float v3 = bf2f(uu.y >> 16)     + bf2f(vv.y >> 16);
                s0 += v0; q0 += v0 * v0;
                s1 += v1; q1 += v1 * v1;
                s2 += v2; q2 += v2 * v2;
                s3 += v3; q3 += v3 * v3;
            }
        }
    }
    __shared__ float redS[8][32][4], redQ[8][32][4];
    const int ri = w * 2 + half;
    redS[ri][cg][0]=s0; redS[ri][cg][1]=s1; redS[ri][cg][2]=s2; redS[ri][cg][3]=s3;
    redQ[ri][cg][0]=q0; redQ[ri][cg][1]=q1; redQ[ri][cg][2]=q2; redQ[ri][cg][3]=q3;
    __syncthreads();
    if (threadIdx.x < 128) {
        int c = threadIdx.x;
        int cgg = c >> 2, k = c & 3;
        float s = 0.f, q = 0.f;
        #pragma unroll
        for (int i = 0; i < 8; ++i) { s += redS[i][cgg][k]; q += redQ[i][cgg][k]; }
        psum[(size_t)b * 128 + c] = s;
        psq [(size_t)b * 128 + c] = q;
    }
}

// ---------------- per-column reduce of partials -> scale/shift ----------------
__device__ __forceinline__ void reduce_body(
    int c, const float* __restrict__ psum, const float* __restrict__ psq,
    int nblk, int C, int M,
    const float* __restrict__ g1, const float* __restrict__ b1,
    float* __restrict__ scale1, float* __restrict__ shift1,
    const float* g2, const float* b2, float* scale2, float* shift2) {
    double s = 0.0, q = 0.0;
    for (int i = threadIdx.x; i < nblk; i += 256) {
        s += (double)psum[(size_t)i * C + c];
        q += (double)psq [(size_t)i * C + c];
    }
    __shared__ double ss[256], qs[256];
    ss[threadIdx.x] = s; qs[threadIdx.x] = q;
    __syncthreads();
    for (int d = 128; d > 0; d >>= 1) {
        if (threadIdx.x < d) {
            ss[threadIdx.x] += ss[threadIdx.x + d];
            qs[threadIdx.x] += qs[threadIdx.x + d];
        }
        __syncthreads();
    }
    if (threadIdx.x == 0) {
        double m = ss[0] / (double)M;
        double v = qs[0] / (double)M - m * m;
        if (v < 0.0) v = 0.0;
        double rs = 1.0 / sqrt(v + 1e-5);
        float mf = (float)m;
        float sc1 = (float)(rs * (double)g1[c]);
        scale1[c] = sc1;
        shift1[c] = b1[c] - mf * sc1;
        if (g2) {
            float sc2 = (float)(rs * (double)g2[c]);
            scale2[c] = sc2;
            shift2[c] = b2[c] - mf * sc2;
        }
    }
}

// one stats set, 1-2 folds (same stats)
__global__ __launch_bounds__(256) void reduce_stats(
    const float* psum, const float* psq, int nblk, int C, int M,
    const float* g1, const float* b1, float* scale1, float* shift1,
    const float* g2, const float* b2, float* scale2, float* shift2) {
    reduce_body(blockIdx.x, psum, psq, nblk, C, M, g1, b1, scale1, shift1, g2, b2, scale2, shift2);
}

// two independent stats sets (grid = CA + CB)
__global__ __launch_bounds__(256) void reduce_stats2(
    const float* psumA, const float* psqA, int nblkA, int CA, int MA,
    const float* gA, const float* bA, float* scaleA, float* shiftA,
    const float* psumB, const float* psqB, int nblkB, int CB, int MB,
    const float* gB, const float* bB, float* scaleB, float* shiftB) {
    if ((int)blockIdx.x < CA)
        reduce_body(blockIdx.x, psumA, psqA, nblkA, CA, MA, gA, bA, scaleA, shiftA,
                    nullptr, nullptr, nullptr, nullptr);
    else
        reduce_body(blockIdx.x - CA, psumB, psqB, nblkB, CB, MB, gB, bB, scaleB, shiftB,
                    nullptr, nullptr, nullptr, nullptr);
}

// ---------------- parallel BN fold + MFMA-fragment pack ----------------
__device__ __forceinline__ void fold_body(
    int b, const float* __restrict__ scale, const float* __restrict__ shift, int C,
    const float* __restrict__ W, const float* __restrict__ bias,
    ushort* __restrict__ Wp, float* __restrict__ beff) {
    const int KT = C / 32;
    __shared__ float slab[32 * 128];
    if (b < KT) {
        const int kt = b;
        for (int i = threadIdx.x; i < 32 * 128; i += 256) {
            int kr = i >> 7, d = i & 127;
            int c = kt * 32 + kr;
            slab[i] = W[(size_t)c * 128 + d] * scale[c];
        }
        __syncthreads();
        #pragma unroll
        for (int t0 = 0; t0 < 512; t0 += 256) {
            int t = t0 + threadIdx.x;
            int lane = t & 63, dt = t >> 6;
            int d = dt * 16 + (lane & 15);
            int kb = (lane >> 4) * 8;
            uint4 o;
            o.x = (uint)f2bf(slab[(kb+0)*128 + d]) | ((uint)f2bf(slab[(kb+1)*128 + d]) << 16);
            o.y = (uint)f2bf(slab[(kb+2)*128 + d]) | ((uint)f2bf(slab[(kb+3)*128 + d]) << 16);
            o.z = (uint)f2bf(slab[(kb+4)*128 + d]) | ((uint)f2bf(slab[(kb+5)*128 + d]) << 16);
            o.w = (uint)f2bf(slab[(kb+6)*128 + d]) | ((uint)f2bf(slab[(kb+7)*128 + d]) << 16);
            *(uint4*)(Wp + (size_t)((dt * KT + kt) * 64 + lane) * 8) = o;
        }
    } else {
        const int bb = b - KT;
        const int dl = threadIdx.x & 15, ci = threadIdx.x >> 4;
        const int d = bb * 16 + dl;
        float a = 0.f;
        for (int c = ci; c < C; c += 16)
            a += shift[c] * W[(size_t)c * 128 + d];
        float* red = slab;
        red[threadIdx.x] = a;
        __syncthreads();
        if (ci == 0) {
            #pragma unroll
            for (int k = 1; k < 16; ++k) a += red[k * 16 + dl];
            beff[d] = bias[d] + a;
        }
    }
}

__global__ __launch_bounds__(256) void pack_fold_par(
    const float* scale, const float* shift, int C,
    const float* W, const float* bias, ushort* Wp, float* beff) {
    fold_body(blockIdx.x, scale, shift, C, W, bias, Wp, beff);
}

// dual fold: grid = (CA/32+8) + (CB/32+8)
__global__ __launch_bounds__(256) void pack_fold2(
    const float* scaleA, const float* shiftA, int CA, const float* WA, const float* biasA,
    ushort* WpA, float* beffA,
    const float* scaleB, const float* shiftB, int CB, const float* WB, const float* biasB,
    ushort* WpB, float* beffB) {
    const int nA = CA / 32 + 8;
    const bool second = (int)blockIdx.x >= nA;
    fold_body(second ? blockIdx.x - nA : blockIdx.x,
              second ? scaleB : scaleA, second ? shiftB : shiftA, second ? CB : CA,
              second ? WB : WA, second ? biasB : biasA,
              second ? WpB : WpA, second ? beffB : beffA);
}

// ---------------- plain MFMA GEMM (final layer + dual hu/hv) ----------------
template<int KT, bool OUTF32>
__device__ __forceinline__ void gemm_body(
    int b, const ushort* __restrict__ X,
    const ushort* __restrict__ Wp, const float* __restrict__ beff,
    ushort* __restrict__ Yb, float* __restrict__ Yf, int M) {
    constexpr int K = KT * 32;
    const int lane = threadIdx.x & 63;
    const int w = threadIdx.x >> 6;
    const int r0 = b * 128 + w * 32;
    const int rlo = lane & 15, khi = lane >> 4;

    f32x4 acc[2][8];
    #pragma unroll
    for (int rt = 0; rt < 2; ++rt)
        #pragma unroll
        for (int dt = 0; dt < 8; ++dt)
            acc[rt][dt] = (f32x4){0.f, 0.f, 0.f, 0.f};

    int row[2], idx[2];
    bool ok[2];
    #pragma unroll
    for (int rt = 0; rt < 2; ++rt) {
        row[rt] = r0 + rt * 16 + rlo;
        ok[rt] = row[rt] < M;
        idx[rt] = ok[rt] ? row[rt] : 0;
    }

    for (int kt = 0; kt < KT; ++kt) {
        short8 wf[8];
        #pragma unroll
        for (int dt = 0; dt < 8; ++dt)
            wf[dt] = *(const short8*)(Wp + (size_t)((dt * KT + kt) * 64 + lane) * 8);
        #pragma unroll
        for (int rt = 0; rt < 2; ++rt) {
            short8 bv = *(const short8*)(X + (size_t)idx[rt] * K + kt * 32 + khi * 8);
            #pragma unroll
            for (int dt = 0; dt < 8; ++dt)
                acc[rt][dt] = __builtin_amdgcn_mfma_f32_16x16x32_bf16(wf[dt], bv, acc[rt][dt], 0, 0, 0);
        }
    }

    #pragma unroll
    for (int rt = 0; rt < 2; ++rt) {
        if (!ok[rt]) continue;
        #pragma unroll
        for (int dt = 0; dt < 8; ++dt) {
            const float4 bz = *(const float4*)(beff + dt * 16 + khi * 4);
            float v0 = fmaxf(acc[rt][dt][0] + bz.x, 0.f);
            float v1 = fmaxf(acc[rt][dt][1] + bz.y, 0.f);
            float v2 = fmaxf(acc[rt][dt][2] + bz.z, 0.f);
            float v3 = fmaxf(acc[rt][dt][3] + bz.w, 0.f);
            if constexpr (OUTF32) {
                *(float4*)(Yf + (size_t)row[rt] * 128 + dt * 16 + khi * 4) = make_float4(v0, v1, v2, v3);
            } else {
                uint2 pk;
                pk.x = (uint)f2bf(v0) | ((uint)f2bf(v1) << 16);
                pk.y = (uint)f2bf(v2) | ((uint)f2bf(v3) << 16);
                *(uint2*)(Yb + (size_t)row[rt] * 128 + dt * 16 + khi * 4) = pk;
            }
        }
    }
}

__global__ __launch_bounds__(256) void gemm_final(
    const ushort* X, const ushort* Wp, const float* beff, float* Yf, int M) {
    gemm_body<8, true>(blockIdx.x, X, Wp, beff, nullptr, Yf, M);
}

// dual hu/hv GEMM: grid = 2*gN
__global__ __launch_bounds__(256) void gemm_dual(
    const ushort* X,
    const ushort* Wp1, const float* beff1, ushort* Y1,
    const ushort* Wp2, const float* beff2, ushort* Y2, int M) {
    const int half = gridDim.x >> 1;
    const bool second = (int)blockIdx.x >= half;
    gemm_body<4, false>(second ? blockIdx.x - half : blockIdx.x, X,
                        second ? Wp2 : Wp1, second ? beff2 : beff1,
                        second ? Y2 : Y1, nullptr, M);
}

// ---------------- seg-GEMM (fused segmented-mean epilogue), dual grid-split ----------------
// TWO=false: X linear (sorted edge features). TWO=true: rows gathered hu[s1]+hv[s2] (two MFMAs).
template<bool TWO>
__device__ __forceinline__ void gemm_seg_body(
    int b, const ushort* __restrict__ X,
    const ushort* __restrict__ HU, const ushort* __restrict__ HV,
    const int* __restrict__ s1, const int* __restrict__ s2,
    const int* __restrict__ cnt,
    const ushort* __restrict__ Wp, const float* __restrict__ beff,
    float* __restrict__ hacc, int M) {
    constexpr int KT = 4;
    __shared__ ushort tile[128 * 132];
    __shared__ int   s_node[128];
    __shared__ float s_scale[128];
    const int tid = threadIdx.x;
    const int lane = tid & 63;
    const int w = tid >> 6;
    const int rb = b * 128;
    const int r0 = rb + w * 32;
    const int rlo = lane & 15, khi = lane >> 4;

    if (tid < 128) {
        int r = rb + tid;
        int nd = (r < M) ? s2[r] : -1;
        s_node[tid] = nd;
        s_scale[tid] = (nd >= 0) ? 0.5f / fmaxf((float)cnt[nd], 1.f) : 0.f;
    }

    f32x4 acc[2][8];
    #pragma unroll
    for (int rt = 0; rt < 2; ++rt)
        #pragma unroll
        for (int dt = 0; dt < 8; ++dt)
            acc[rt][dt] = (f32x4){0.f, 0.f, 0.f, 0.f};

    int row[2], idx1[2], idx2[2];
    bool ok[2];
    #pragma unroll
    for (int rt = 0; rt < 2; ++rt) {
        row[rt] = r0 + rt * 16 + rlo;
        ok[rt] = row[rt] < M;
        int rr = ok[rt] ? row[rt] : 0;
        if constexpr (TWO) {
            idx1[rt] = (M > 0) ? s1[rr] : 0;
            idx2[rt] = (M > 0) ? s2[rr] : 0;
        } else {
            idx1[rt] = rr;
        }
    }

    for (int kt = 0; kt < KT; ++kt) {
        short8 wf[8];
        #pragma unroll
        for (int dt = 0; dt < 8; ++dt)
            wf[dt] = *(const short8*)(Wp + (size_t)((dt * KT + kt) * 64 + lane) * 8);
        #pragma unroll
        for (int rt = 0; rt < 2; ++rt) {
            if constexpr (TWO) {
                short8 bu = *(const short8*)(HU + (size_t)idx1[rt] * 128 + kt * 32 + khi * 8);
                short8 bv = *(const short8*)(HV + (size_t)idx2[rt] * 128 + kt * 32 + khi * 8);
                #pragma unroll
                for (int dt = 0; dt < 8; ++dt)
                    acc[rt][dt] = __builtin_amdgcn_mfma_f32_16x16x32_bf16(wf[dt], bu, acc[rt][dt], 0, 0, 0);
                #pragma unroll
                for (int dt = 0; dt < 8; ++dt)
                    acc[rt][dt] = __builtin_amdgcn_mfma_f32_16x16x32_bf16(wf[dt], bv, acc[rt][dt], 0, 0, 0);
            } else {
                short8 bv = *(const short8*)(X + (size_t)idx1[rt] * 128 + kt * 32 + khi * 8);
                #pragma unroll
                for (int dt = 0; dt < 8; ++dt)
                    acc[rt][dt] = __builtin_amdgcn_mfma_f32_16x16x32_bf16(wf[dt], bv, acc[rt][dt], 0, 0, 0);
            }
        }
    }

    #pragma unroll
    for (int rt = 0; rt < 2; ++rt) {
        const int rl = w * 32 + rt * 16 + rlo;
        #pragma unroll
        for (int dt = 0; dt < 8; ++dt) {
            const float4 bz = *(const float4*)(beff + dt * 16 + khi * 4);
            float v0 = 0.f, v1 = 0.f, v2 = 0.f, v3 = 0.f;
            if (ok[rt]) {
                v0 = fmaxf(acc[rt][dt][0] + bz.x, 0.f);
                v1 = fmaxf(acc[rt][dt][1] + bz.y, 0.f);
                v2 = fmaxf(acc[rt][dt][2] + bz.z, 0.f);
                v3 = fmaxf(acc[rt][dt][3] + bz.w, 0.f);
            }
            uint2 pk;
            pk.x = (uint)f2bf(v0) | ((uint)f2bf(v1) << 16);
            pk.y = (uint)f2bf(v2) | ((uint)f2bf(v3) << 16);
            *(uint2*)&tile[rl * 132 + dt * 16 + khi * 4] = pk;
        }
    }
    __syncthreads();

    const int col = tid & 127;
    const int rs = (tid >> 7) * 64;
    int cur = s_node[rs];
    float scl = s_scale[rs];
    float sum = 0.f;
    for (int r = rs; r < rs + 64; ++r) {
        int nd = s_node[r];
        if (nd != cur) {
            if (cur >= 0)
                atomicAdd(&hacc[(size_t)cur * 128 + col], sum * scl);
            cur = nd; scl = s_scale[r]; sum = 0.f;
        }
        sum += bf2f(tile[r * 132 + col]);
    }
    if (cur >= 0)
        atomicAdd(&hacc[(size_t)cur * 128 + col], sum * scl);
}

template<bool TWO>
__global__ __launch_bounds__(256) void gemm_seg2(
    const ushort* XA, const int* s1A, const int* s2A, const int* cntA,
    const ushort* WpA, const float* beffA, int MA,
    const ushort* XB, const int* s1B, const int* s2B, const int* cntB,
    const ushort* WpB, const float* beffB, int MB,
    const ushort* HU, const ushort* HV, float* hacc) {
    const int half = gridDim.x >> 1;
    const bool second = (int)blockIdx.x >= half;
    gemm_seg_body<TWO>(second ? blockIdx.x - half : blockIdx.x,
                       second ? XB : XA, HU, HV,
                       second ? s1B : s1A, second ? s2B : s2A, second ? cntB : cntA,
                       second ? WpB : WpA, second ? beffB : beffA,
                       hacc, second ? MB : MA);
}

// ---------------- hacc -> bf16 h (+fh half), re-zero hacc ----------------
__global__ __launch_bounds__(256) void finalize_hacc(
    float2* __restrict__ hacc2, uint* __restrict__ h2, uint* __restrict__ fh2,
    int fhsel, int N) {
    const int total = N * 64;
    for (int i = blockIdx.x * 256 + threadIdx.x; i < total; i += gridDim.x * 256) {
        float2 v = hacc2[i];
        uint pk = (uint)f2bf(v.x) | ((uint)f2bf(v.y) << 16);
        h2[i] = pk;
        if (fhsel >= 0) fh2[((size_t)(i >> 6)) * 128 + fhsel * 64 + (i & 63)] = pk;
        hacc2[i] = make_float2(0.f, 0.f);
    }
}

// ---------------- launch ----------------
extern "C" void kernel_launch(void* const* d_in, const int* in_sizes, int n_in,
                              void* d_out, int out_size, void* d_ws, size_t ws_size,
                              hipStream_t stream) {
    const float* win_f  = (const float*)d_in[0];
    const float* loss_f = (const float*)d_in[1];
    struct BP { const float *g, *b, *W, *bias; };
    auto bp = [&](int i) { return BP{ (const float*)d_in[i], (const float*)d_in[i+1],
                                      (const float*)d_in[i+2], (const float*)d_in[i+3] }; };
    BP wi = bp(2), li = bp(6), srcp = bp(10), dstp = bp(14), wl = bp(18), ll = bp(22), outp = bp(26);
    const int* win_src  = (const int*)d_in[30];
    const int* win_dst  = (const int*)d_in[31];
    const int* loss_src = (const int*)d_in[32];
    const int* loss_dst = (const int*)d_in[33];
    const int E = in_sizes[30];
    const int N = out_size / 128;
    (void)n_in;

    char* base = (char*)d_ws;
    size_t off_b = 0;
    auto alloc = [&](size_t bytes) {
        size_t cur = off_b;
        off_b += (bytes + 255) & ~(size_t)255;
        return (void*)(base + cur);
    };
    float*  hacc = (float*)alloc((size_t)N * 128 * 4);
    ushort* h    = (ushort*)alloc((size_t)N * 128 * 2);
    ushort* hu   = (ushort*)alloc((size_t)N * 128 * 2);
    ushort* hv   = (ushort*)alloc((size_t)N * 128 * 2);
    ushort* fh   = (ushort*)alloc((size_t)N * 256 * 2);
    int* cntw  = (int*)alloc((size_t)N * 4);
    int* cntl  = (int*)alloc((size_t)N * 4);
    int* offw  = (int*)alloc((size_t)(N + 1) * 4);
    int* offl  = (int*)alloc((size_t)(N + 1) * 4);
    int* curw  = (int*)alloc((size_t)N * 4);
    int* curl  = (int*)alloc((size_t)N * 4);
    int* ipermw= (int*)alloc((size_t)E * 4);
    int* ssrcw = (int*)alloc((size_t)E * 4);
    int* sdstw = (int*)alloc((size_t)E * 4);
    int* iperml= (int*)alloc((size_t)E * 4);
    int* ssrcl = (int*)alloc((size_t)E * 4);
    int* sdstl = (int*)alloc((size_t)E * 4);
    float* psumW = (float*)alloc((size_t)NPART_MAX * 128 * 4);
    float* psqW  = (float*)alloc((size_t)NPART_MAX * 128 * 4);
    float* psumL = (float*)alloc((size_t)NPART_MAX * 128 * 4);
    float* psqL  = (float*)alloc((size_t)NPART_MAX * 128 * 4);
    float* psumN = (float*)alloc((size_t)512 * 256 * 4);
    float* psqN  = (float*)alloc((size_t)512 * 256 * 4);
    float* scal1 = (float*)alloc(256 * 4);
    float* shif1 = (float*)alloc(256 * 4);
    float* scal2 = (float*)alloc(256 * 4);
    float* shif2 = (float*)alloc(256 * 4);
    ushort* Wp1 = (ushort*)alloc((size_t)256 * 128 * 2);
    ushort* Wp2 = (ushort*)alloc((size_t)256 * 128 * 2);
    float* beff1 = (float*)alloc(128 * 4);
    float* beff2 = (float*)alloc(128 * 4);
    ushort* Xbf1 = (ushort*)alloc((size_t)E * 128 * 2);
    if (off_b > ws_size) return;           // base layout must fit
    size_t off_one = off_b;
    ushort* Xbf2 = (ushort*)alloc((size_t)E * 128 * 2);
    const bool have_x2 = (off_b <= ws_size);
    if (!have_x2) off_b = off_one;

    const int gE = (E + 127) / 128;
    const int gN = (N + 127) / 128;
    const int NBF = 1024;   // convert-stats blocks per etype
    const int NBG = 2048;   // gather-stats blocks per etype
    const int NBN = 512;    // node-stats blocks

    // phase 0: counting sort (both etypes)
    hipMemsetAsync(cntw, 0, (size_t)N * 4, stream);
    hipMemsetAsync(cntl, 0, (size_t)N * 4, stream);
    hipMemsetAsync(hacc, 0, (size_t)N * 128 * 4, stream);
    hist2<<<2048, 256, 0, stream>>>(win_dst, loss_dst, E, cntw, cntl);
    scan2<<<2, 256, 0, stream>>>(cntw, cntl, N, offw, curw, offl, curl);
    scatter2<<<2048, 256, 0, stream>>>(win_src, win_dst, loss_src, loss_dst, E,
                                       curw, curl, ipermw, ssrcw, sdstw, iperml, ssrcl, sdstl);

    // initial edge blocks
    if (have_x2) {
        convert_two<<<2 * NBF, 256, 0, stream>>>(
            (const float4*)win_f, ipermw, (uint2*)Xbf1, psumW, psqW,
            (const float4*)loss_f, iperml, (uint2*)Xbf2, psumL, psqL, E);
        reduce_stats2<<<256, 256, 0, stream>>>(
            psumW, psqW, NBF, 128, E, wi.g, wi.b, scal1, shif1,
            psumL, psqL, NBF, 128, E, li.g, li.b, scal2, shif2);
        pack_fold2<<<24, 256, 0, stream>>>(scal1, shif1, 128, wi.W, wi.bias, Wp1, beff1,
                                           scal2, shif2, 128, li.W, li.bias, Wp2, beff2);
        gemm_seg2<false><<<2 * gE, 256, 0, stream>>>(
            Xbf1, nullptr, sdstw, cntw, Wp1, beff1, E,
            Xbf2, nullptr, sdstl, cntl, Wp2, beff2, E,
            nullptr, nullptr, hacc);
    } else {
        convert_one<<<NBF, 256, 0, stream>>>((const float4*)win_f, ipermw, E, (uint2*)Xbf1, psumW, psqW);
        reduce_stats<<<128, 256, 0, stream>>>(psumW, psqW, NBF, 128, E, wi.g, wi.b, scal1, shif1,
                                              nullptr, nullptr, nullptr, nullptr);
        pack_fold_par<<<12, 256, 0, stream>>>(scal1, shif1, 128, wi.W, wi.bias, Wp1, beff1);
        gemm_seg2<false><<<2 * gE, 256, 0, stream>>>(
            Xbf1, nullptr, sdstw, cntw, Wp1, beff1, E,
            Xbf1, nullptr, sdstw, cntw, Wp1, beff1, 0,
            nullptr, nullptr, hacc);
        convert_one<<<NBF, 256, 0, stream>>>((const float4*)loss_f, iperml, E, (uint2*)Xbf1, psumW, psqW);
        reduce_stats<<<128, 256, 0, stream>>>(psumW, psqW, NBF, 128, E, li.g, li.b, scal1, shif1,
                                              nullptr, nullptr, nullptr, nullptr);
        pack_fold_par<<<12, 256, 0, stream>>>(scal1, shif1, 128, li.W, li.bias, Wp1, beff1);
        gemm_seg2<false><<<2 * gE, 256, 0, stream>>>(
            Xbf1, nullptr, sdstl, cntl, Wp1, beff1, E,
            Xbf1, nullptr, sdstl, cntl, Wp1, beff1, 0,
            nullptr, nullptr, hacc);
    }
    finalize_hacc<<<512, 256, 0, stream>>>((float2*)hacc, (uint*)h, (uint*)fh, 0, N);

    for (int it = 0; it < 3; ++it) {
        colstats_b128<<<NBN, 256, 0, stream>>>((const uint*)h, N, psumN, psqN);
        reduce_stats<<<128, 256, 0, stream>>>(psumN, psqN, NBN, 128, N, srcp.g, srcp.b, scal1, shif1,
                                              dstp.g, dstp.b, scal2, shif2);
        pack_fold2<<<24, 256, 0, stream>>>(scal1, shif1, 128, srcp.W, srcp.bias, Wp1, beff1,
                                           scal2, shif2, 128, dstp.W, dstp.bias, Wp2, beff2);
        gemm_dual<<<2 * gN, 256, 0, stream>>>(h, Wp1, beff1, hu, Wp2, beff2, hv, N);

        gather_stats2<<<2 * NBG, 256, 0, stream>>>(
            (const uint2*)hu, (const uint2*)hv,
            ssrcw, sdstw, psumW, psqW, ssrcl, sdstl, psumL, psqL, E);
        reduce_stats2<<<256, 256, 0, stream>>>(
            psumW, psqW, NBG, 128, E, wl.g, wl.b, scal1, shif1,
            psumL, psqL, NBG, 128, E, ll.g, ll.b, scal2, shif2);
        pack_fold2<<<24, 256, 0, stream>>>(scal1, shif1, 128, wl.W, wl.bias, Wp1, beff1,
                                           scal2, shif2, 128, ll.W, ll.bias, Wp2, beff2);
        gemm_seg2<true><<<2 * gE, 256, 0, stream>>>(
            nullptr, ssrcw, sdstw, cntw, Wp1, beff1, E,
            nullptr, ssrcl, sdstl, cntl, Wp2, beff2, E,
            hu, hv, hacc);
        finalize_hacc<<<512, 256, 0, stream>>>((float2*)hacc, (uint*)h, (uint*)fh,
                                               (it == 2) ? 1 : -1, N);
    }

    colstats_b256<<<NBN, 256, 0, stream>>>((const uint*)fh, N, psumN, psqN);
    reduce_stats<<<256, 256, 0, stream>>>(psumN, psqN, NBN, 256, N, outp.g, outp.b, scal1, shif1,
                                          nullptr, nullptr, nullptr, nullptr);
    pack_fold_par<<<16, 256, 0, stream>>>(scal1, shif1, 256, outp.W, outp.bias, Wp1, beff1);
    gemm_final<<<gN, 256, 0, stream>>>(fh, Wp1, beff1, (float*)d_out, N);
}

// Round 10
// 901.052 us; speedup vs baseline: 5.2369x; 1.0977x over previous
//
#include <hip/hip_runtime.h>

#define NPART_MAX 2048

typedef __attribute__((ext_vector_type(8))) short short8;
typedef __attribute__((ext_vector_type(4))) float f32x4;

__device__ __forceinline__ float bf2f(uint u) {
    union { uint u; float f; } v; v.u = u << 16; return v.f;
}
__device__ __forceinline__ ushort f2bf(float f) {
    union { float f; uint u; } v; v.f = f;
    uint r = v.u + 0x7fffu + ((v.u >> 16) & 1u);
    return (ushort)(r >> 16);
}

// ---------------- phase 0: counting sort by dst (both etypes per launch) ----------------
__global__ __launch_bounds__(256) void hist2(const int* __restrict__ dw, const int* __restrict__ dl,
                                             int E, int* __restrict__ cw, int* __restrict__ cl) {
    const int half = gridDim.x >> 1;
    const bool second = (int)blockIdx.x >= half;
    const int* dst = second ? dl : dw;
    int* cnt = second ? cl : cw;
    const int b = second ? blockIdx.x - half : blockIdx.x;
    for (int e = b * 256 + threadIdx.x; e < E; e += half * 256)
        atomicAdd(&cnt[dst[e]], 1);
}

__global__ __launch_bounds__(256) void scan2(const int* __restrict__ cw, const int* __restrict__ cl,
                                             int n, int* offw, int* curw, int* offl, int* curl) {
    const int* cnt = blockIdx.x ? cl : cw;
    int* off = blockIdx.x ? offl : offw;
    int* cur = blockIdx.x ? curl : curw;
    __shared__ int warpsums[4];
    __shared__ int s_carry;
    if (threadIdx.x == 0) s_carry = 0;
    __syncthreads();
    for (int base = 0; base < n; base += 1024) {
        int i0 = base + threadIdx.x * 4;
        int v0 = (i0 + 0 < n) ? cnt[i0 + 0] : 0;
        int v1 = (i0 + 1 < n) ? cnt[i0 + 1] : 0;
        int v2 = (i0 + 2 < n) ? cnt[i0 + 2] : 0;
        int v3 = (i0 + 3 < n) ? cnt[i0 + 3] : 0;
        int tsum = v0 + v1 + v2 + v3;
        int lane = threadIdx.x & 63, w = threadIdx.x >> 6;
        int x = tsum;
        for (int d = 1; d < 64; d <<= 1) {
            int y = __shfl_up(x, d);
            if (lane >= d) x += y;
        }
        if (lane == 63) warpsums[w] = x;
        __syncthreads();
        int woff = 0;
        for (int k = 0; k < w; ++k) woff += warpsums[k];
        int excl = x - tsum + woff + s_carry;
        if (i0 + 0 < n) { off[i0 + 0] = excl; cur[i0 + 0] = excl; } excl += v0;
        if (i0 + 1 < n) { off[i0 + 1] = excl; cur[i0 + 1] = excl; } excl += v1;
        if (i0 + 2 < n) { off[i0 + 2] = excl; cur[i0 + 2] = excl; } excl += v2;
        if (i0 + 3 < n) { off[i0 + 3] = excl; cur[i0 + 3] = excl; } excl += v3;
        __syncthreads();
        if (threadIdx.x == 255) s_carry = excl;
        __syncthreads();
    }
    if (threadIdx.x == 0) off[n] = s_carry;
}

__global__ __launch_bounds__(256) void scatter2(
    const int* __restrict__ sw, const int* __restrict__ dw,
    const int* __restrict__ sl, const int* __restrict__ dl, int E,
    int* __restrict__ curw, int* __restrict__ curl,
    int* __restrict__ ipermw, int* __restrict__ ssrcw, int* __restrict__ sdstw,
    int* __restrict__ iperml, int* __restrict__ ssrcl, int* __restrict__ sdstl) {
    const int half = gridDim.x >> 1;
    const bool second = (int)blockIdx.x >= half;
    const int* src = second ? sl : sw;
    const int* dst = second ? dl : dw;
    int* cursor = second ? curl : curw;
    int* iperm = second ? iperml : ipermw;
    int* ssrc = second ? ssrcl : ssrcw;
    int* sdst = second ? sdstl : sdstw;
    const int b = second ? blockIdx.x - half : blockIdx.x;
    for (int e = b * 256 + threadIdx.x; e < E; e += half * 256) {
        int d = dst[e];
        int p = atomicAdd(&cursor[d], 1);
        iperm[e] = p;
        ssrc[p] = src[e];
        sdst[p] = d;
    }
}

// ---------------- fused fp32 col-stats + bf16 convert into sorted slots ----------------
__device__ __forceinline__ void convert_body(
    int b, int nb, const float4* __restrict__ x4, const int* __restrict__ iperm, int M,
    uint2* __restrict__ xb4, float* __restrict__ psum, float* __restrict__ psq) {
    const int cg = threadIdx.x & 31;
    const int sub = threadIdx.x >> 5;
    float s0=0,s1=0,s2=0,s3=0,q0=0,q1=0,q2=0,q3=0;
    for (int r = b * 8 + sub; r < M; r += nb * 8) {
        float4 v = x4[(size_t)r * 32 + cg];
        int p = iperm[r];
        uint2 o;
        o.x = (uint)f2bf(v.x) | ((uint)f2bf(v.y) << 16);
        o.y = (uint)f2bf(v.z) | ((uint)f2bf(v.w) << 16);
        xb4[(size_t)p * 32 + cg] = o;
        s0 += v.x; q0 += v.x * v.x;
        s1 += v.y; q1 += v.y * v.y;
        s2 += v.z; q2 += v.z * v.z;
        s3 += v.w; q3 += v.w * v.w;
    }
    __shared__ float rs[256][4], rq[256][4];
    rs[threadIdx.x][0]=s0; rs[threadIdx.x][1]=s1; rs[threadIdx.x][2]=s2; rs[threadIdx.x][3]=s3;
    rq[threadIdx.x][0]=q0; rq[threadIdx.x][1]=q1; rq[threadIdx.x][2]=q2; rq[threadIdx.x][3]=q3;
    __syncthreads();
    if (sub == 0) {
        #pragma unroll
        for (int k = 1; k < 8; ++k) {
            s0 += rs[k*32+cg][0]; s1 += rs[k*32+cg][1];
            s2 += rs[k*32+cg][2]; s3 += rs[k*32+cg][3];
            q0 += rq[k*32+cg][0]; q1 += rq[k*32+cg][1];
            q2 += rq[k*32+cg][2]; q3 += rq[k*32+cg][3];
        }
        psum[b*128 + cg*4+0] = s0; psq[b*128 + cg*4+0] = q0;
        psum[b*128 + cg*4+1] = s1; psq[b*128 + cg*4+1] = q1;
        psum[b*128 + cg*4+2] = s2; psq[b*128 + cg*4+2] = q2;
        psum[b*128 + cg*4+3] = s3; psq[b*128 + cg*4+3] = q3;
    }
}

__global__ __launch_bounds__(256) void convert_one(
    const float4* x4, const int* iperm, int M, uint2* xb4, float* psum, float* psq) {
    convert_body(blockIdx.x, gridDim.x, x4, iperm, M, xb4, psum, psq);
}

__global__ __launch_bounds__(256) void convert_two(
    const float4* x4a, const int* iperma, uint2* xb4a, float* psuma, float* psqa,
    const float4* x4b, const int* ipermb, uint2* xb4b, float* psumb, float* psqb, int M) {
    const int half = gridDim.x >> 1;
    const bool second = (int)blockIdx.x >= half;
    const int b = second ? blockIdx.x - half : blockIdx.x;
    convert_body(b, half,
                 second ? x4b : x4a, second ? ipermb : iperma, M,
                 second ? xb4b : xb4a, second ? psumb : psuma, second ? psqb : psqa);
}

// ---------------- vectorized bf16 col-stats ----------------
__global__ __launch_bounds__(256) void colstats_b128(const uint* __restrict__ x2, int M,
                                                     float* __restrict__ psum, float* __restrict__ psq) {
    const int cl = threadIdx.x & 63;
    const int sub = threadIdx.x >> 6;
    float s0=0,s1=0,q0=0,q1=0;
    for (int r = blockIdx.x * 4 + sub; r < M; r += gridDim.x * 4) {
        uint u = x2[(size_t)r * 64 + cl];
        float a = bf2f(u & 0xffffu), b = bf2f(u >> 16);
        s0 += a; q0 += a * a;
        s1 += b; q1 += b * b;
    }
    __shared__ float red[4][64][4];
    red[sub][cl][0]=s0; red[sub][cl][1]=s1; red[sub][cl][2]=q0; red[sub][cl][3]=q1;
    __syncthreads();
    if (sub == 0) {
        #pragma unroll
        for (int k = 1; k < 4; ++k) {
            s0 += red[k][cl][0]; s1 += red[k][cl][1];
            q0 += red[k][cl][2]; q1 += red[k][cl][3];
        }
        psum[blockIdx.x*128 + 2*cl]   = s0; psq[blockIdx.x*128 + 2*cl]   = q0;
        psum[blockIdx.x*128 + 2*cl+1] = s1; psq[blockIdx.x*128 + 2*cl+1] = q1;
    }
}

__global__ __launch_bounds__(256) void colstats_b256(const uint* __restrict__ x2, int M,
                                                     float* __restrict__ psum, float* __restrict__ psq) {
    const int cl = threadIdx.x & 127;
    const int sub = threadIdx.x >> 7;
    float s0=0,s1=0,q0=0,q1=0;
    for (int r = blockIdx.x * 2 + sub; r < M; r += gridDim.x * 2) {
        uint u = x2[(size_t)r * 128 + cl];
        float a = bf2f(u & 0xffffu), b = bf2f(u >> 16);
        s0 += a; q0 += a * a;
        s1 += b; q1 += b * b;
    }
    __shared__ float red[2][128][4];
    red[sub][cl][0]=s0; red[sub][cl][1]=s1; red[sub][cl][2]=q0; red[sub][cl][3]=q1;
    __syncthreads();
    if (sub == 0) {
        s0 += red[1][cl][0]; s1 += red[1][cl][1];
        q0 += red[1][cl][2]; q1 += red[1][cl][3];
        psum[blockIdx.x*256 + 2*cl]   = s0; psq[blockIdx.x*256 + 2*cl]   = q0;
        psum[blockIdx.x*256 + 2*cl+1] = s1; psq[blockIdx.x*256 + 2*cl+1] = q1;
    }
}

// ---------------- dual gather stats (pure stats) ----------------
__global__ __launch_bounds__(256) void gather_stats2(
    const uint2* __restrict__ hu4, const uint2* __restrict__ hv4,
    const int* __restrict__ sw, const int* __restrict__ dw,
    float* __restrict__ psumW, float* __restrict__ psqW,
    const int* __restrict__ sl, const int* __restrict__ dl,
    float* __restrict__ psumL, float* __restrict__ psqL, int E) {
    const int gh = gridDim.x >> 1;
    const bool second = (int)blockIdx.x >= gh;
    const int* sidx = second ? sl : sw;
    const int* didx = second ? dl : dw;
    float* psum = second ? psumL : psumW;
    float* psq  = second ? psqL  : psqW;
    const int b = second ? blockIdx.x - gh : blockIdx.x;

    const int lane = threadIdx.x & 63;
    const int w = threadIdx.x >> 6;
    const int half = lane >> 5;
    const int cg = lane & 31;
    const int gwave = (b * 256 + threadIdx.x) >> 6;
    const int nwave = (gh * 256) >> 6;
    float s0=0,s1=0,s2=0,s3=0,q0=0,q1=0,q2=0,q3=0;
    for (int base = gwave * 64; base < E; base += nwave * 64) {
        int e = base + lane;
        int su = (e < E) ? sidx[e] : 0;
        int dv = (e < E) ? didx[e] : 0;
        int cnt = min(64, E - base);
        #pragma unroll 4
        for (int j = 0; j < 32; ++j) {
            int eidx = 2 * j + half;
            int a = __shfl(su, eidx), bb = __shfl(dv, eidx);
            if (eidx < cnt) {
                uint2 uu = hu4[(size_t)a * 32 + cg];
                uint2 vv = hv4[(size_t)bb * 32 + cg];
                float v0 = bf2f(uu.x & 0xffffu) + bf2f(vv.x & 0xffffu);
                float v1 = bf2f(uu.x >> 16)     + bf2f(vv.x >> 16);
                float v2 = bf2f(uu.y & 0xffffu) + bf2f(vv.y & 0xffffu);
                float v3 = bf2f(uu.y >> 16)     + bf2f(vv.y >> 16);
                s0 += v0; q0 += v0 * v0;
                s1 += v1; q1 += v1 * v1;
                s2 += v2; q2 += v2 * v2;
                s3 += v3; q3 += v3 * v3;
            }
        }
    }
    __shared__ float redS[8][32][4], redQ[8][32][4];
    const int ri = w * 2 + half;
    redS[ri][cg][0]=s0; redS[ri][cg][1]=s1; redS[ri][cg][2]=s2; redS[ri][cg][3]=s3;
    redQ[ri][cg][0]=q0; redQ[ri][cg][1]=q1; redQ[ri][cg][2]=q2; redQ[ri][cg][3]=q3;
    __syncthreads();
    if (threadIdx.x < 128) {
        int c = threadIdx.x;
        int cgg = c >> 2, k = c & 3;
        float s = 0.f, q = 0.f;
        #pragma unroll
        for (int i = 0; i < 8; ++i) { s += redS[i][cgg][k]; q += redQ[i][cgg][k]; }
        psum[(size_t)b * 128 + c] = s;
        psq [(size_t)b * 128 + c] = q;
    }
}

// ---------------- per-column reduce of partials -> scale/shift ----------------
__device__ __forceinline__ void reduce_body(
    int c, const float* __restrict__ psum, const float* __restrict__ psq,
    int nblk, int C, int M,
    const float* __restrict__ g1, const float* __restrict__ b1,
    float* __restrict__ scale1, float* __restrict__ shift1,
    const float* g2, const float* b2, float* scale2, float* shift2) {
    double s = 0.0, q = 0.0;
    for (int i = threadIdx.x; i < nblk; i += 256) {
        s += (double)psum[(size_t)i * C + c];
        q += (double)psq [(size_t)i * C + c];
    }
    __shared__ double ss[256], qs[256];
    ss[threadIdx.x] = s; qs[threadIdx.x] = q;
    __syncthreads();
    for (int d = 128; d > 0; d >>= 1) {
        if (threadIdx.x < d) {
            ss[threadIdx.x] += ss[threadIdx.x + d];
            qs[threadIdx.x] += qs[threadIdx.x + d];
        }
        __syncthreads();
    }
    if (threadIdx.x == 0) {
        double m = ss[0] / (double)M;
        double v = qs[0] / (double)M - m * m;
        if (v < 0.0) v = 0.0;
        double rs = 1.0 / sqrt(v + 1e-5);
        float mf = (float)m;
        float sc1 = (float)(rs * (double)g1[c]);
        scale1[c] = sc1;
        shift1[c] = b1[c] - mf * sc1;
        if (g2) {
            float sc2 = (float)(rs * (double)g2[c]);
            scale2[c] = sc2;
            shift2[c] = b2[c] - mf * sc2;
        }
    }
}

__global__ __launch_bounds__(256) void reduce_stats(
    const float* psum, const float* psq, int nblk, int C, int M,
    const float* g1, const float* b1, float* scale1, float* shift1,
    const float* g2, const float* b2, float* scale2, float* shift2) {
    reduce_body(blockIdx.x, psum, psq, nblk, C, M, g1, b1, scale1, shift1, g2, b2, scale2, shift2);
}

__global__ __launch_bounds__(256) void reduce_stats2(
    const float* psumA, const float* psqA, int nblkA, int CA, int MA,
    const float* gA, const float* bA, float* scaleA, float* shiftA,
    const float* psumB, const float* psqB, int nblkB, int CB, int MB,
    const float* gB, const float* bB, float* scaleB, float* shiftB) {
    if ((int)blockIdx.x < CA)
        reduce_body(blockIdx.x, psumA, psqA, nblkA, CA, MA, gA, bA, scaleA, shiftA,
                    nullptr, nullptr, nullptr, nullptr);
    else
        reduce_body(blockIdx.x - CA, psumB, psqB, nblkB, CB, MB, gB, bB, scaleB, shiftB,
                    nullptr, nullptr, nullptr, nullptr);
}

// ---------------- parallel BN fold + MFMA-fragment pack ----------------
__device__ __forceinline__ void fold_body(
    int b, const float* __restrict__ scale, const float* __restrict__ shift, int C,
    const float* __restrict__ W, const float* __restrict__ bias,
    ushort* __restrict__ Wp, float* __restrict__ beff) {
    const int KT = C / 32;
    __shared__ float slab[32 * 128];
    if (b < KT) {
        const int kt = b;
        for (int i = threadIdx.x; i < 32 * 128; i += 256) {
            int kr = i >> 7, d = i & 127;
            int c = kt * 32 + kr;
            slab[i] = W[(size_t)c * 128 + d] * scale[c];
        }
        __syncthreads();
        #pragma unroll
        for (int t0 = 0; t0 < 512; t0 += 256) {
            int t = t0 + threadIdx.x;
            int lane = t & 63, dt = t >> 6;
            int d = dt * 16 + (lane & 15);
            int kb = (lane >> 4) * 8;
            uint4 o;
            o.x = (uint)f2bf(slab[(kb+0)*128 + d]) | ((uint)f2bf(slab[(kb+1)*128 + d]) << 16);
            o.y = (uint)f2bf(slab[(kb+2)*128 + d]) | ((uint)f2bf(slab[(kb+3)*128 + d]) << 16);
            o.z = (uint)f2bf(slab[(kb+4)*128 + d]) | ((uint)f2bf(slab[(kb+5)*128 + d]) << 16);
            o.w = (uint)f2bf(slab[(kb+6)*128 + d]) | ((uint)f2bf(slab[(kb+7)*128 + d]) << 16);
            *(uint4*)(Wp + (size_t)((dt * KT + kt) * 64 + lane) * 8) = o;
        }
    } else {
        const int bb = b - KT;
        const int dl = threadIdx.x & 15, ci = threadIdx.x >> 4;
        const int d = bb * 16 + dl;
        float a = 0.f;
        for (int c = ci; c < C; c += 16)
            a += shift[c] * W[(size_t)c * 128 + d];
        float* red = slab;
        red[threadIdx.x] = a;
        __syncthreads();
        if (ci == 0) {
            #pragma unroll
            for (int k = 1; k < 16; ++k) a += red[k * 16 + dl];
            beff[d] = bias[d] + a;
        }
    }
}

__global__ __launch_bounds__(256) void pack_fold_par(
    const float* scale, const float* shift, int C,
    const float* W, const float* bias, ushort* Wp, float* beff) {
    fold_body(blockIdx.x, scale, shift, C, W, bias, Wp, beff);
}

__global__ __launch_bounds__(256) void pack_fold2(
    const float* scaleA, const float* shiftA, int CA, const float* WA, const float* biasA,
    ushort* WpA, float* beffA,
    const float* scaleB, const float* shiftB, int CB, const float* WB, const float* biasB,
    ushort* WpB, float* beffB) {
    const int nA = CA / 32 + 8;
    const bool second = (int)blockIdx.x >= nA;
    fold_body(second ? blockIdx.x - nA : blockIdx.x,
              second ? scaleB : scaleA, second ? shiftB : shiftA, second ? CB : CA,
              second ? WB : WA, second ? biasB : biasA,
              second ? WpB : WpA, second ? beffB : beffA);
}

// ---------------- plain MFMA GEMM. MODE: 0=bf16 bias+relu, 1=f32 bias+relu, 2=bf16 plain ----------------
template<int KT, int MODE>
__device__ __forceinline__ void gemm_body(
    int b, const ushort* __restrict__ X,
    const ushort* __restrict__ Wp, const float* __restrict__ beff,
    ushort* __restrict__ Yb, float* __restrict__ Yf, int M) {
    constexpr int K = KT * 32;
    const int lane = threadIdx.x & 63;
    const int w = threadIdx.x >> 6;
    const int r0 = b * 128 + w * 32;
    const int rlo = lane & 15, khi = lane >> 4;

    f32x4 acc[2][8];
    #pragma unroll
    for (int rt = 0; rt < 2; ++rt)
        #pragma unroll
        for (int dt = 0; dt < 8; ++dt)
            acc[rt][dt] = (f32x4){0.f, 0.f, 0.f, 0.f};

    int row[2], idx[2];
    bool ok[2];
    #pragma unroll
    for (int rt = 0; rt < 2; ++rt) {
        row[rt] = r0 + rt * 16 + rlo;
        ok[rt] = row[rt] < M;
        idx[rt] = ok[rt] ? row[rt] : 0;
    }

    for (int kt = 0; kt < KT; ++kt) {
        short8 wf[8];
        #pragma unroll
        for (int dt = 0; dt < 8; ++dt)
            wf[dt] = *(const short8*)(Wp + (size_t)((dt * KT + kt) * 64 + lane) * 8);
        #pragma unroll
        for (int rt = 0; rt < 2; ++rt) {
            short8 bv = *(const short8*)(X + (size_t)idx[rt] * K + kt * 32 + khi * 8);
            #pragma unroll
            for (int dt = 0; dt < 8; ++dt)
                acc[rt][dt] = __builtin_amdgcn_mfma_f32_16x16x32_bf16(wf[dt], bv, acc[rt][dt], 0, 0, 0);
        }
    }

    #pragma unroll
    for (int rt = 0; rt < 2; ++rt) {
        if (!ok[rt]) continue;
        #pragma unroll
        for (int dt = 0; dt < 8; ++dt) {
            float v0, v1, v2, v3;
            if constexpr (MODE == 2) {
                v0 = acc[rt][dt][0]; v1 = acc[rt][dt][1];
                v2 = acc[rt][dt][2]; v3 = acc[rt][dt][3];
            } else {
                const float4 bz = *(const float4*)(beff + dt * 16 + khi * 4);
                v0 = fmaxf(acc[rt][dt][0] + bz.x, 0.f);
                v1 = fmaxf(acc[rt][dt][1] + bz.y, 0.f);
                v2 = fmaxf(acc[rt][dt][2] + bz.z, 0.f);
                v3 = fmaxf(acc[rt][dt][3] + bz.w, 0.f);
            }
            if constexpr (MODE == 1) {
                *(float4*)(Yf + (size_t)row[rt] * 128 + dt * 16 + khi * 4) = make_float4(v0, v1, v2, v3);
            } else {
                uint2 pk;
                pk.x = (uint)f2bf(v0) | ((uint)f2bf(v1) << 16);
                pk.y = (uint)f2bf(v2) | ((uint)f2bf(v3) << 16);
                *(uint2*)(Yb + (size_t)row[rt] * 128 + dt * 16 + khi * 4) = pk;
            }
        }
    }
}

__global__ __launch_bounds__(256) void gemm_final(
    const ushort* X, const ushort* Wp, const float* beff, float* Yf, int M) {
    gemm_body<8, 1>(blockIdx.x, X, Wp, beff, nullptr, Yf, M);
}

__global__ __launch_bounds__(256) void gemm_dual(
    const ushort* X,
    const ushort* Wp1, const float* beff1, ushort* Y1,
    const ushort* Wp2, const float* beff2, ushort* Y2, int M) {
    const int half = gridDim.x >> 1;
    const bool second = (int)blockIdx.x >= half;
    gemm_body<4, 0>(second ? blockIdx.x - half : blockIdx.x, X,
                    second ? Wp2 : Wp1, second ? beff2 : beff1,
                    second ? Y2 : Y1, nullptr, M);
}

// 4 node GEMMs (no bias/relu): hu@Wp1->HUw, hv@Wp1->HVw, hu@Wp2->HUl, hv@Wp2->HVl
__global__ __launch_bounds__(256) void gemm_quad(
    const ushort* hu, const ushort* hv,
    const ushort* Wp1, const ushort* Wp2,
    ushort* HUw, ushort* HVw, ushort* HUl, ushort* HVl, int M) {
    const int gq = gridDim.x >> 2;
    const int q = blockIdx.x / gq;
    const int b = blockIdx.x - q * gq;
    const ushort* X = (q & 1) ? hv : hu;
    const ushort* Wp = (q >= 2) ? Wp2 : Wp1;
    ushort* Y = (q == 0) ? HUw : (q == 1) ? HVw : (q == 2) ? HUl : HVl;
    gemm_body<4, 2>(b, X, Wp, nullptr, Y, nullptr, M);
}

// ---------------- seg-GEMM (linear edge features, fused segmented-mean), dual ----------------
__device__ __forceinline__ void gemm_seg_body(
    int b, const ushort* __restrict__ X,
    const int* __restrict__ sdst, const int* __restrict__ cnt,
    const ushort* __restrict__ Wp, const float* __restrict__ beff,
    float* __restrict__ hacc, int M) {
    constexpr int KT = 4;
    __shared__ ushort tile[128 * 132];
    __shared__ int   s_node[128];
    __shared__ float s_scale[128];
    const int tid = threadIdx.x;
    const int lane = tid & 63;
    const int w = tid >> 6;
    const int rb = b * 128;
    const int r0 = rb + w * 32;
    const int rlo = lane & 15, khi = lane >> 4;

    if (tid < 128) {
        int r = rb + tid;
        int nd = (r < M) ? sdst[r] : -1;
        s_node[tid] = nd;
        s_scale[tid] = (nd >= 0) ? 0.5f / fmaxf((float)cnt[nd], 1.f) : 0.f;
    }

    f32x4 acc[2][8];
    #pragma unroll
    for (int rt = 0; rt < 2; ++rt)
        #pragma unroll
        for (int dt = 0; dt < 8; ++dt)
            acc[rt][dt] = (f32x4){0.f, 0.f, 0.f, 0.f};

    int row[2], idx[2];
    bool ok[2];
    #pragma unroll
    for (int rt = 0; rt < 2; ++rt) {
        row[rt] = r0 + rt * 16 + rlo;
        ok[rt] = row[rt] < M;
        idx[rt] = ok[rt] ? row[rt] : 0;
    }

    for (int kt = 0; kt < KT; ++kt) {
        short8 wf[8];
        #pragma unroll
        for (int dt = 0; dt < 8; ++dt)
            wf[dt] = *(const short8*)(Wp + (size_t)((dt * KT + kt) * 64 + lane) * 8);
        #pragma unroll
        for (int rt = 0; rt < 2; ++rt) {
            short8 bv = *(const short8*)(X + (size_t)idx[rt] * 128 + kt * 32 + khi * 8);
            #pragma unroll
            for (int dt = 0; dt < 8; ++dt)
                acc[rt][dt] = __builtin_amdgcn_mfma_f32_16x16x32_bf16(wf[dt], bv, acc[rt][dt], 0, 0, 0);
        }
    }

    #pragma unroll
    for (int rt = 0; rt < 2; ++rt) {
        const int rl = w * 32 + rt * 16 + rlo;
        #pragma unroll
        for (int dt = 0; dt < 8; ++dt) {
            const float4 bz = *(const float4*)(beff + dt * 16 + khi * 4);
            float v0 = 0.f, v1 = 0.f, v2 = 0.f, v3 = 0.f;
            if (ok[rt]) {
                v0 = fmaxf(acc[rt][dt][0] + bz.x, 0.f);
                v1 = fmaxf(acc[rt][dt][1] + bz.y, 0.f);
                v2 = fmaxf(acc[rt][dt][2] + bz.z, 0.f);
                v3 = fmaxf(acc[rt][dt][3] + bz.w, 0.f);
            }
            uint2 pk;
            pk.x = (uint)f2bf(v0) | ((uint)f2bf(v1) << 16);
            pk.y = (uint)f2bf(v2) | ((uint)f2bf(v3) << 16);
            *(uint2*)&tile[rl * 132 + dt * 16 + khi * 4] = pk;
        }
    }
    __syncthreads();

    const int col = tid & 127;
    const int rs = (tid >> 7) * 64;
    int cur = s_node[rs];
    float scl = s_scale[rs];
    float sum = 0.f;
    for (int r = rs; r < rs + 64; ++r) {
        int nd = s_node[r];
        if (nd != cur) {
            if (cur >= 0)
                atomicAdd(&hacc[(size_t)cur * 128 + col], sum * scl);
            cur = nd; scl = s_scale[r]; sum = 0.f;
        }
        sum += bf2f(tile[r * 132 + col]);
    }
    if (cur >= 0)
        atomicAdd(&hacc[(size_t)cur * 128 + col], sum * scl);
}

__global__ __launch_bounds__(256) void gemm_seg2(
    const ushort* XA, const int* sdstA, const int* cntA,
    const ushort* WpA, const float* beffA, int MA,
    const ushort* XB, const int* sdstB, const int* cntB,
    const ushort* WpB, const float* beffB, int MB,
    float* hacc) {
    const int half = gridDim.x >> 1;
    const bool second = (int)blockIdx.x >= half;
    gemm_seg_body(second ? blockIdx.x - half : blockIdx.x,
                  second ? XB : XA,
                  second ? sdstB : sdstA, second ? cntB : cntA,
                  second ? WpB : WpA, second ? beffB : beffA,
                  hacc, second ? MB : MA);
}

// ---------------- edge gather-add-relu + segmented mean (dual) ----------------
// out_e = relu(HU'[s_e] + HV'[d_e] + beff); runs of sorted d accumulate; scaled atomics.
__global__ __launch_bounds__(256) void edge_seg2(
    const uint* __restrict__ HUw, const uint* __restrict__ HVw,
    const int* __restrict__ sw, const int* __restrict__ dw,
    const int* __restrict__ cw, const float* __restrict__ bw,
    const uint* __restrict__ HUl, const uint* __restrict__ HVl,
    const int* __restrict__ sl, const int* __restrict__ dl,
    const int* __restrict__ cl, const float* __restrict__ bl,
    float* __restrict__ hacc, int E) {
    const int gh = gridDim.x >> 1;
    const bool second = (int)blockIdx.x >= gh;
    const uint* HU = second ? HUl : HUw;
    const uint* HV = second ? HVl : HVw;
    const int* sidx = second ? sl : sw;
    const int* didx = second ? dl : dw;
    const int* cnt = second ? cl : cw;
    const float* beff = second ? bl : bw;
    const int b = second ? blockIdx.x - gh : blockIdx.x;

    const int lane = threadIdx.x & 63;
    const int gwave = (b * 256 + threadIdx.x) >> 6;
    const int nwave = (gh * 256) >> 6;
    const float bz0 = beff[2 * lane];
    const float bz1 = beff[2 * lane + 1];

    for (int base = gwave * 64; base < E; base += nwave * 64) {
        int e = base + lane;
        int su = (e < E) ? sidx[e] : 0;
        int dv = (e < E) ? didx[e] : 0;
        int cn = min(64, E - base);
        int cur = -1; float scl = 0.f, a0 = 0.f, a1 = 0.f;
        auto body = [&](int j) {
            int aa = __shfl(su, j), dd = __shfl(dv, j);
            if (dd != cur) {               // wave-uniform branch (shfl broadcast)
                if (cur >= 0) {
                    atomicAdd(&hacc[(size_t)cur * 128 + 2 * lane],     a0 * scl);
                    atomicAdd(&hacc[(size_t)cur * 128 + 2 * lane + 1], a1 * scl);
                }
                cur = dd; scl = 0.5f / fmaxf((float)cnt[dd], 1.f); a0 = 0.f; a1 = 0.f;
            }
            uint uu = HU[(size_t)aa * 64 + lane];
            uint vv = HV[(size_t)dd * 64 + lane];
            a0 += fmaxf(bf2f(uu & 0xffffu) + bf2f(vv & 0xffffu) + bz0, 0.f);
            a1 += fmaxf(bf2f(uu >> 16)     + bf2f(vv >> 16)     + bz1, 0.f);
        };
        if (cn == 64) {
            #pragma unroll 8
            for (int j = 0; j < 64; ++j) body(j);
        } else {
            for (int j = 0; j < cn; ++j) body(j);
        }
        if (cur >= 0) {
            atomicAdd(&hacc[(size_t)cur * 128 + 2 * lane],     a0 * scl);
            atomicAdd(&hacc[(size_t)cur * 128 + 2 * lane + 1], a1 * scl);
        }
    }
}

// ---------------- hacc -> bf16 h (+fh half), re-zero hacc ----------------
__global__ __launch_bounds__(256) void finalize_hacc(
    float2* __restrict__ hacc2, uint* __restrict__ h2, uint* __restrict__ fh2,
    int fhsel, int N) {
    const int total = N * 64;
    for (int i = blockIdx.x * 256 + threadIdx.x; i < total; i += gridDim.x * 256) {
        float2 v = hacc2[i];
        uint pk = (uint)f2bf(v.x) | ((uint)f2bf(v.y) << 16);
        h2[i] = pk;
        if (fhsel >= 0) fh2[((size_t)(i >> 6)) * 128 + fhsel * 64 + (i & 63)] = pk;
        hacc2[i] = make_float2(0.f, 0.f);
    }
}

// ---------------- launch ----------------
extern "C" void kernel_launch(void* const* d_in, const int* in_sizes, int n_in,
                              void* d_out, int out_size, void* d_ws, size_t ws_size,
                              hipStream_t stream) {
    const float* win_f  = (const float*)d_in[0];
    const float* loss_f = (const float*)d_in[1];
    struct BP { const float *g, *b, *W, *bias; };
    auto bp = [&](int i) { return BP{ (const float*)d_in[i], (const float*)d_in[i+1],
                                      (const float*)d_in[i+2], (const float*)d_in[i+3] }; };
    BP wi = bp(2), li = bp(6), srcp = bp(10), dstp = bp(14), wl = bp(18), ll = bp(22), outp = bp(26);
    const int* win_src  = (const int*)d_in[30];
    const int* win_dst  = (const int*)d_in[31];
    const int* loss_src = (const int*)d_in[32];
    const int* loss_dst = (const int*)d_in[33];
    const int E = in_sizes[30];
    const int N = out_size / 128;
    (void)n_in;

    char* base = (char*)d_ws;
    size_t off_b = 0;
    auto alloc = [&](size_t bytes) {
        size_t cur = off_b;
        off_b += (bytes + 255) & ~(size_t)255;
        return (void*)(base + cur);
    };
    float*  hacc = (float*)alloc((size_t)N * 128 * 4);
    ushort* h    = (ushort*)alloc((size_t)N * 128 * 2);
    ushort* hu   = (ushort*)alloc((size_t)N * 128 * 2);
    ushort* hv   = (ushort*)alloc((size_t)N * 128 * 2);
    ushort* fh   = (ushort*)alloc((size_t)N * 256 * 2);
    ushort* HUw  = (ushort*)alloc((size_t)N * 128 * 2);
    ushort* HVw  = (ushort*)alloc((size_t)N * 128 * 2);
    ushort* HUl  = (ushort*)alloc((size_t)N * 128 * 2);
    ushort* HVl  = (ushort*)alloc((size_t)N * 128 * 2);
    int* cntw  = (int*)alloc((size_t)N * 4);
    int* cntl  = (int*)alloc((size_t)N * 4);
    int* offw  = (int*)alloc((size_t)(N + 1) * 4);
    int* offl  = (int*)alloc((size_t)(N + 1) * 4);
    int* curw  = (int*)alloc((size_t)N * 4);
    int* curl  = (int*)alloc((size_t)N * 4);
    int* ipermw= (int*)alloc((size_t)E * 4);
    int* ssrcw = (int*)alloc((size_t)E * 4);
    int* sdstw = (int*)alloc((size_t)E * 4);
    int* iperml= (int*)alloc((size_t)E * 4);
    int* ssrcl = (int*)alloc((size_t)E * 4);
    int* sdstl = (int*)alloc((size_t)E * 4);
    float* psumW = (float*)alloc((size_t)NPART_MAX * 128 * 4);
    float* psqW  = (float*)alloc((size_t)NPART_MAX * 128 * 4);
    float* psumL = (float*)alloc((size_t)NPART_MAX * 128 * 4);
    float* psqL  = (float*)alloc((size_t)NPART_MAX * 128 * 4);
    float* psumN = (float*)alloc((size_t)512 * 256 * 4);
    float* psqN  = (float*)alloc((size_t)512 * 256 * 4);
    float* scal1 = (float*)alloc(256 * 4);
    float* shif1 = (float*)alloc(256 * 4);
    float* scal2 = (float*)alloc(256 * 4);
    float* shif2 = (float*)alloc(256 * 4);
    ushort* Wp1 = (ushort*)alloc((size_t)256 * 128 * 2);
    ushort* Wp2 = (ushort*)alloc((size_t)256 * 128 * 2);
    float* beff1 = (float*)alloc(128 * 4);
    float* beff2 = (float*)alloc(128 * 4);
    ushort* Xbf1 = (ushort*)alloc((size_t)E * 128 * 2);
    if (off_b > ws_size) return;           // base layout must fit
    size_t off_one = off_b;
    ushort* Xbf2 = (ushort*)alloc((size_t)E * 128 * 2);
    const bool have_x2 = (off_b <= ws_size);
    if (!have_x2) off_b = off_one;

    const int gE = (E + 127) / 128;
    const int gN = (N + 127) / 128;
    const int NBF = 1024;   // convert-stats blocks per etype
    const int NBG = 2048;   // gather/edge blocks per etype
    const int NBN = 512;    // node-stats blocks

    // phase 0: counting sort (both etypes)
    hipMemsetAsync(cntw, 0, (size_t)N * 4, stream);
    hipMemsetAsync(cntl, 0, (size_t)N * 4, stream);
    hipMemsetAsync(hacc, 0, (size_t)N * 128 * 4, stream);
    hist2<<<2048, 256, 0, stream>>>(win_dst, loss_dst, E, cntw, cntl);
    scan2<<<2, 256, 0, stream>>>(cntw, cntl, N, offw, curw, offl, curl);
    scatter2<<<2048, 256, 0, stream>>>(win_src, win_dst, loss_src, loss_dst, E,
                                       curw, curl, ipermw, ssrcw, sdstw, iperml, ssrcl, sdstl);

    // initial edge blocks (E-row GEMM unavoidable here: true edge features)
    if (have_x2) {
        convert_two<<<2 * NBF, 256, 0, stream>>>(
            (const float4*)win_f, ipermw, (uint2*)Xbf1, psumW, psqW,
            (const float4*)loss_f, iperml, (uint2*)Xbf2, psumL, psqL, E);
        reduce_stats2<<<256, 256, 0, stream>>>(
            psumW, psqW, NBF, 128, E, wi.g, wi.b, scal1, shif1,
            psumL, psqL, NBF, 128, E, li.g, li.b, scal2, shif2);
        pack_fold2<<<24, 256, 0, stream>>>(scal1, shif1, 128, wi.W, wi.bias, Wp1, beff1,
                                           scal2, shif2, 128, li.W, li.bias, Wp2, beff2);
        gemm_seg2<<<2 * gE, 256, 0, stream>>>(
            Xbf1, sdstw, cntw, Wp1, beff1, E,
            Xbf2, sdstl, cntl, Wp2, beff2, E, hacc);
    } else {
        convert_one<<<NBF, 256, 0, stream>>>((const float4*)win_f, ipermw, E, (uint2*)Xbf1, psumW, psqW);
        reduce_stats<<<128, 256, 0, stream>>>(psumW, psqW, NBF, 128, E, wi.g, wi.b, scal1, shif1,
                                              nullptr, nullptr, nullptr, nullptr);
        pack_fold_par<<<12, 256, 0, stream>>>(scal1, shif1, 128, wi.W, wi.bias, Wp1, beff1);
        gemm_seg2<<<2 * gE, 256, 0, stream>>>(
            Xbf1, sdstw, cntw, Wp1, beff1, E,
            Xbf1, sdstw, cntw, Wp1, beff1, 0, hacc);
        convert_one<<<NBF, 256, 0, stream>>>((const float4*)loss_f, iperml, E, (uint2*)Xbf1, psumW, psqW);
        reduce_stats<<<128, 256, 0, stream>>>(psumW, psqW, NBF, 128, E, li.g, li.b, scal1, shif1,
                                              nullptr, nullptr, nullptr, nullptr);
        pack_fold_par<<<12, 256, 0, stream>>>(scal1, shif1, 128, li.W, li.bias, Wp1, beff1);
        gemm_seg2<<<2 * gE, 256, 0, stream>>>(
            Xbf1, sdstl, cntl, Wp1, beff1, E,
            Xbf1, sdstl, cntl, Wp1, beff1, 0, hacc);
    }
    finalize_hacc<<<512, 256, 0, stream>>>((float2*)hacc, (uint*)h, (uint*)fh, 0, N);

    for (int it = 0; it < 3; ++it) {
        colstats_b128<<<NBN, 256, 0, stream>>>((const uint*)h, N, psumN, psqN);
        reduce_stats<<<128, 256, 0, stream>>>(psumN, psqN, NBN, 128, N, srcp.g, srcp.b, scal1, shif1,
                                              dstp.g, dstp.b, scal2, shif2);
        pack_fold2<<<24, 256, 0, stream>>>(scal1, shif1, 128, srcp.W, srcp.bias, Wp1, beff1,
                                           scal2, shif2, 128, dstp.W, dstp.bias, Wp2, beff2);
        gemm_dual<<<2 * gN, 256, 0, stream>>>(h, Wp1, beff1, hu, Wp2, beff2, hv, N);

        gather_stats2<<<2 * NBG, 256, 0, stream>>>(
            (const uint2*)hu, (const uint2*)hv,
            ssrcw, sdstw, psumW, psqW, ssrcl, sdstl, psumL, psqL, E);
        reduce_stats2<<<256, 256, 0, stream>>>(
            psumW, psqW, NBG, 128, E, wl.g, wl.b, scal1, shif1,
            psumL, psqL, NBG, 128, E, ll.g, ll.b, scal2, shif2);
        pack_fold2<<<24, 256, 0, stream>>>(scal1, shif1, 128, wl.W, wl.bias, Wp1, beff1,
                                           scal2, shif2, 128, ll.W, ll.bias, Wp2, beff2);
        gemm_quad<<<4 * gN, 256, 0, stream>>>(hu, hv, Wp1, Wp2, HUw, HVw, HUl, HVl, N);
        edge_seg2<<<2 * NBG, 256, 0, stream>>>(
            (const uint*)HUw, (const uint*)HVw, ssrcw, sdstw, cntw, beff1,
            (const uint*)HUl, (const uint*)HVl, ssrcl, sdstl, cntl, beff2,
            hacc, E);
        finalize_hacc<<<512, 256, 0, stream>>>((float2*)hacc, (uint*)h, (uint*)fh,
                                               (it == 2) ? 1 : -1, N);
    }

    colstats_b256<<<NBN, 256, 0, stream>>>((const uint*)fh, N, psumN, psqN);
    reduce_stats<<<256, 256, 0, stream>>>(psumN, psqN, NBN, 256, N, outp.g, outp.b, scal1, shif1,
                                          nullptr, nullptr, nullptr, nullptr);
    pack_fold_par<<<16, 256, 0, stream>>>(scal1, shif1, 256, outp.W, outp.bias, Wp1, beff1);
    gemm_final<<<gN, 256, 0, stream>>>(fh, Wp1, beff1, (float*)d_out, N);
}

// Round 11
// 840.527 us; speedup vs baseline: 5.6141x; 1.0720x over previous
//
#include <hip/hip_runtime.h>

#define NPART_MAX 2048

typedef __attribute__((ext_vector_type(8))) short short8;
typedef __attribute__((ext_vector_type(4))) float f32x4;

__device__ __forceinline__ float bf2f(uint u) {
    union { uint u; float f; } v; v.u = u << 16; return v.f;
}
__device__ __forceinline__ ushort f2bf(float f) {
    union { float f; uint u; } v; v.f = f;
    uint r = v.u + 0x7fffu + ((v.u >> 16) & 1u);
    return (ushort)(r >> 16);
}

// ---------------- phase 0: counting sort by dst (both etypes per launch) ----------------
__global__ __launch_bounds__(256) void hist2(const int* __restrict__ dw, const int* __restrict__ dl,
                                             int E, int* __restrict__ cw, int* __restrict__ cl) {
    const int half = gridDim.x >> 1;
    const bool second = (int)blockIdx.x >= half;
    const int* dst = second ? dl : dw;
    int* cnt = second ? cl : cw;
    const int b = second ? blockIdx.x - half : blockIdx.x;
    for (int e = b * 256 + threadIdx.x; e < E; e += half * 256)
        atomicAdd(&cnt[dst[e]], 1);
}

__global__ __launch_bounds__(256) void scan2(const int* __restrict__ cw, const int* __restrict__ cl,
                                             int n, int* offw, int* curw, int* offl, int* curl) {
    const int* cnt = blockIdx.x ? cl : cw;
    int* off = blockIdx.x ? offl : offw;
    int* cur = blockIdx.x ? curl : curw;
    __shared__ int warpsums[4];
    __shared__ int s_carry;
    if (threadIdx.x == 0) s_carry = 0;
    __syncthreads();
    for (int base = 0; base < n; base += 1024) {
        int i0 = base + threadIdx.x * 4;
        int v0 = (i0 + 0 < n) ? cnt[i0 + 0] : 0;
        int v1 = (i0 + 1 < n) ? cnt[i0 + 1] : 0;
        int v2 = (i0 + 2 < n) ? cnt[i0 + 2] : 0;
        int v3 = (i0 + 3 < n) ? cnt[i0 + 3] : 0;
        int tsum = v0 + v1 + v2 + v3;
        int lane = threadIdx.x & 63, w = threadIdx.x >> 6;
        int x = tsum;
        for (int d = 1; d < 64; d <<= 1) {
            int y = __shfl_up(x, d);
            if (lane >= d) x += y;
        }
        if (lane == 63) warpsums[w] = x;
        __syncthreads();
        int woff = 0;
        for (int k = 0; k < w; ++k) woff += warpsums[k];
        int excl = x - tsum + woff + s_carry;
        if (i0 + 0 < n) { off[i0 + 0] = excl; cur[i0 + 0] = excl; } excl += v0;
        if (i0 + 1 < n) { off[i0 + 1] = excl; cur[i0 + 1] = excl; } excl += v1;
        if (i0 + 2 < n) { off[i0 + 2] = excl; cur[i0 + 2] = excl; } excl += v2;
        if (i0 + 3 < n) { off[i0 + 3] = excl; cur[i0 + 3] = excl; } excl += v3;
        __syncthreads();
        if (threadIdx.x == 255) s_carry = excl;
        __syncthreads();
    }
    if (threadIdx.x == 0) off[n] = s_carry;
}

__global__ __launch_bounds__(256) void scatter2(
    const int* __restrict__ sw, const int* __restrict__ dw,
    const int* __restrict__ sl, const int* __restrict__ dl, int E,
    int* __restrict__ curw, int* __restrict__ curl,
    int* __restrict__ ipermw, int* __restrict__ ssrcw, int* __restrict__ sdstw,
    int* __restrict__ iperml, int* __restrict__ ssrcl, int* __restrict__ sdstl) {
    const int half = gridDim.x >> 1;
    const bool second = (int)blockIdx.x >= half;
    const int* src = second ? sl : sw;
    const int* dst = second ? dl : dw;
    int* cursor = second ? curl : curw;
    int* iperm = second ? iperml : ipermw;
    int* ssrc = second ? ssrcl : ssrcw;
    int* sdst = second ? sdstl : sdstw;
    const int b = second ? blockIdx.x - half : blockIdx.x;
    for (int e = b * 256 + threadIdx.x; e < E; e += half * 256) {
        int d = dst[e];
        int p = atomicAdd(&cursor[d], 1);
        iperm[e] = p;
        ssrc[p] = src[e];
        sdst[p] = d;
    }
}

// ---------------- fused fp32 col-stats + bf16 convert into sorted slots ----------------
__device__ __forceinline__ void convert_body(
    int b, int nb, const float4* __restrict__ x4, const int* __restrict__ iperm, int M,
    uint2* __restrict__ xb4, float* __restrict__ psum, float* __restrict__ psq) {
    const int cg = threadIdx.x & 31;
    const int sub = threadIdx.x >> 5;
    float s0=0,s1=0,s2=0,s3=0,q0=0,q1=0,q2=0,q3=0;
    for (int r = b * 8 + sub; r < M; r += nb * 8) {
        float4 v = x4[(size_t)r * 32 + cg];
        int p = iperm[r];
        uint2 o;
        o.x = (uint)f2bf(v.x) | ((uint)f2bf(v.y) << 16);
        o.y = (uint)f2bf(v.z) | ((uint)f2bf(v.w) << 16);
        xb4[(size_t)p * 32 + cg] = o;
        s0 += v.x; q0 += v.x * v.x;
        s1 += v.y; q1 += v.y * v.y;
        s2 += v.z; q2 += v.z * v.z;
        s3 += v.w; q3 += v.w * v.w;
    }
    __shared__ float rs[256][4], rq[256][4];
    rs[threadIdx.x][0]=s0; rs[threadIdx.x][1]=s1; rs[threadIdx.x][2]=s2; rs[threadIdx.x][3]=s3;
    rq[threadIdx.x][0]=q0; rq[threadIdx.x][1]=q1; rq[threadIdx.x][2]=q2; rq[threadIdx.x][3]=q3;
    __syncthreads();
    if (sub == 0) {
        #pragma unroll
        for (int k = 1; k < 8; ++k) {
            s0 += rs[k*32+cg][0]; s1 += rs[k*32+cg][1];
            s2 += rs[k*32+cg][2]; s3 += rs[k*32+cg][3];
            q0 += rq[k*32+cg][0]; q1 += rq[k*32+cg][1];
            q2 += rq[k*32+cg][2]; q3 += rq[k*32+cg][3];
        }
        psum[b*128 + cg*4+0] = s0; psq[b*128 + cg*4+0] = q0;
        psum[b*128 + cg*4+1] = s1; psq[b*128 + cg*4+1] = q1;
        psum[b*128 + cg*4+2] = s2; psq[b*128 + cg*4+2] = q2;
        psum[b*128 + cg*4+3] = s3; psq[b*128 + cg*4+3] = q3;
    }
}

__global__ __launch_bounds__(256) void convert_one(
    const float4* x4, const int* iperm, int M, uint2* xb4, float* psum, float* psq) {
    convert_body(blockIdx.x, gridDim.x, x4, iperm, M, xb4, psum, psq);
}

__global__ __launch_bounds__(256) void convert_two(
    const float4* x4a, const int* iperma, uint2* xb4a, float* psuma, float* psqa,
    const float4* x4b, const int* ipermb, uint2* xb4b, float* psumb, float* psqb, int M) {
    const int half = gridDim.x >> 1;
    const bool second = (int)blockIdx.x >= half;
    const int b = second ? blockIdx.x - half : blockIdx.x;
    convert_body(b, half,
                 second ? x4b : x4a, second ? ipermb : iperma, M,
                 second ? xb4b : xb4a, second ? psumb : psuma, second ? psqb : psqa);
}

// ---------------- vectorized bf16 col-stats ----------------
__global__ __launch_bounds__(256) void colstats_b128(const uint* __restrict__ x2, int M,
                                                     float* __restrict__ psum, float* __restrict__ psq) {
    const int cl = threadIdx.x & 63;
    const int sub = threadIdx.x >> 6;
    float s0=0,s1=0,q0=0,q1=0;
    for (int r = blockIdx.x * 4 + sub; r < M; r += gridDim.x * 4) {
        uint u = x2[(size_t)r * 64 + cl];
        float a = bf2f(u & 0xffffu), b = bf2f(u >> 16);
        s0 += a; q0 += a * a;
        s1 += b; q1 += b * b;
    }
    __shared__ float red[4][64][4];
    red[sub][cl][0]=s0; red[sub][cl][1]=s1; red[sub][cl][2]=q0; red[sub][cl][3]=q1;
    __syncthreads();
    if (sub == 0) {
        #pragma unroll
        for (int k = 1; k < 4; ++k) {
            s0 += red[k][cl][0]; s1 += red[k][cl][1];
            q0 += red[k][cl][2]; q1 += red[k][cl][3];
        }
        psum[blockIdx.x*128 + 2*cl]   = s0; psq[blockIdx.x*128 + 2*cl]   = q0;
        psum[blockIdx.x*128 + 2*cl+1] = s1; psq[blockIdx.x*128 + 2*cl+1] = q1;
    }
}

__global__ __launch_bounds__(256) void colstats_b256(const uint* __restrict__ x2, int M,
                                                     float* __restrict__ psum, float* __restrict__ psq) {
    const int cl = threadIdx.x & 127;
    const int sub = threadIdx.x >> 7;
    float s0=0,s1=0,q0=0,q1=0;
    for (int r = blockIdx.x * 2 + sub; r < M; r += gridDim.x * 2) {
        uint u = x2[(size_t)r * 128 + cl];
        float a = bf2f(u & 0xffffu), b = bf2f(u >> 16);
        s0 += a; q0 += a * a;
        s1 += b; q1 += b * b;
    }
    __shared__ float red[2][128][4];
    red[sub][cl][0]=s0; red[sub][cl][1]=s1; red[sub][cl][2]=q0; red[sub][cl][3]=q1;
    __syncthreads();
    if (sub == 0) {
        s0 += red[1][cl][0]; s1 += red[1][cl][1];
        q0 += red[1][cl][2]; q1 += red[1][cl][3];
        psum[blockIdx.x*256 + 2*cl]   = s0; psq[blockIdx.x*256 + 2*cl]   = q0;
        psum[blockIdx.x*256 + 2*cl+1] = s1; psq[blockIdx.x*256 + 2*cl+1] = q1;
    }
}

// ---------------- dual gather stats with run-hoisted hv (sorted by dst) ----------------
// Per run of equal d: Σ(hu+hv)^2 = Σhu^2 + 2·hv·Σhu + len·hv^2 ; hv loaded once per run.
__global__ __launch_bounds__(256) void gather_stats2(
    const uint2* __restrict__ hu4, const uint2* __restrict__ hv4,
    const int* __restrict__ sw, const int* __restrict__ dw,
    float* __restrict__ psumW, float* __restrict__ psqW,
    const int* __restrict__ sl, const int* __restrict__ dl,
    float* __restrict__ psumL, float* __restrict__ psqL, int E) {
    const int gh = gridDim.x >> 1;
    const bool second = (int)blockIdx.x >= gh;
    const int* sidx = second ? sl : sw;
    const int* didx = second ? dl : dw;
    float* psum = second ? psumL : psumW;
    float* psq  = second ? psqL  : psqW;
    const int b = second ? blockIdx.x - gh : blockIdx.x;

    const int lane = threadIdx.x & 63;
    const int w = threadIdx.x >> 6;
    const int half = lane >> 5;
    const int cg = lane & 31;
    const int gwave = (b * 256 + threadIdx.x) >> 6;
    const int nwave = (gh * 256) >> 6;
    float s0=0,s1=0,s2=0,s3=0,q0=0,q1=0,q2=0,q3=0;
    for (int base = gwave * 64; base < E; base += nwave * 64) {
        int e = base + lane;
        int su = (e < E) ? sidx[e] : 0;
        int dv = (e < E) ? didx[e] : 0;
        int cnt = min(64, E - base);
        int curd = -1;
        float hv0=0,hv1=0,hv2=0,hv3=0;
        float rs0=0,rs1=0,rs2=0,rs3=0,rq0=0,rq1=0,rq2=0,rq3=0,rlen=0;
        auto flush = [&]() {
            if (curd >= 0) {
                s0 += rs0 + rlen*hv0; q0 += rq0 + 2.f*hv0*rs0 + rlen*hv0*hv0;
                s1 += rs1 + rlen*hv1; q1 += rq1 + 2.f*hv1*rs1 + rlen*hv1*hv1;
                s2 += rs2 + rlen*hv2; q2 += rq2 + 2.f*hv2*rs2 + rlen*hv2*hv2;
                s3 += rs3 + rlen*hv3; q3 += rq3 + 2.f*hv3*rs3 + rlen*hv3*hv3;
            }
        };
        #pragma unroll 4
        for (int j = 0; j < 32; ++j) {
            int eidx = 2 * j + half;
            int a = __shfl(su, eidx), dd = __shfl(dv, eidx);
            if (eidx < cnt) {
                if (dd != curd) {                 // uniform across the 32-lane half-wave
                    flush();
                    curd = dd;
                    uint2 vv = hv4[(size_t)dd * 32 + cg];
                    hv0 = bf2f(vv.x & 0xffffu); hv1 = bf2f(vv.x >> 16);
                    hv2 = bf2f(vv.y & 0xffffu); hv3 = bf2f(vv.y >> 16);
                    rs0=rs1=rs2=rs3=0; rq0=rq1=rq2=rq3=0; rlen=0;
                }
                uint2 uu = hu4[(size_t)a * 32 + cg];
                float u0 = bf2f(uu.x & 0xffffu), u1 = bf2f(uu.x >> 16);
                float u2 = bf2f(uu.y & 0xffffu), u3 = bf2f(uu.y >> 16);
                rs0 += u0; rq0 += u0*u0;
                rs1 += u1; rq1 += u1*u1;
                rs2 += u2; rq2 += u2*u2;
                rs3 += u3; rq3 += u3*u3;
                rlen += 1.f;
            }
        }
        flush();
    }
    __shared__ float redS[8][32][4], redQ[8][32][4];
    const int ri = w * 2 + half;
    redS[ri][cg][0]=s0; redS[ri][cg][1]=s1; redS[ri][cg][2]=s2; redS[ri][cg][3]=s3;
    redQ[ri][cg][0]=q0; redQ[ri][cg][1]=q1; redQ[ri][cg][2]=q2; redQ[ri][cg][3]=q3;
    __syncthreads();
    if (threadIdx.x < 128) {
        int c = threadIdx.x;
        int cgg = c >> 2, k = c & 3;
        float s = 0.f, q = 0.f;
        #pragma unroll
        for (int i = 0; i < 8; ++i) { s += redS[i][cgg][k]; q += redQ[i][cgg][k]; }
        psum[(size_t)b * 128 + c] = s;
        psq [(size_t)b * 128 + c] = q;
    }
}

// ---------------- per-column reduce of partials -> scale/shift ----------------
__device__ __forceinline__ void reduce_body(
    int c, const float* __restrict__ psum, const float* __restrict__ psq,
    int nblk, int C, int M,
    const float* __restrict__ g1, const float* __restrict__ b1,
    float* __restrict__ scale1, float* __restrict__ shift1,
    const float* g2, const float* b2, float* scale2, float* shift2) {
    double s = 0.0, q = 0.0;
    for (int i = threadIdx.x; i < nblk; i += 256) {
        s += (double)psum[(size_t)i * C + c];
        q += (double)psq [(size_t)i * C + c];
    }
    __shared__ double ss[256], qs[256];
    ss[threadIdx.x] = s; qs[threadIdx.x] = q;
    __syncthreads();
    for (int d = 128; d > 0; d >>= 1) {
        if (threadIdx.x < d) {
            ss[threadIdx.x] += ss[threadIdx.x + d];
            qs[threadIdx.x] += qs[threadIdx.x + d];
        }
        __syncthreads();
    }
    if (threadIdx.x == 0) {
        double m = ss[0] / (double)M;
        double v = qs[0] / (double)M - m * m;
        if (v < 0.0) v = 0.0;
        double rs = 1.0 / sqrt(v + 1e-5);
        float mf = (float)m;
        float sc1 = (float)(rs * (double)g1[c]);
        scale1[c] = sc1;
        shift1[c] = b1[c] - mf * sc1;
        if (g2) {
            float sc2 = (float)(rs * (double)g2[c]);
            scale2[c] = sc2;
            shift2[c] = b2[c] - mf * sc2;
        }
    }
}

__global__ __launch_bounds__(256) void reduce_stats(
    const float* psum, const float* psq, int nblk, int C, int M,
    const float* g1, const float* b1, float* scale1, float* shift1,
    const float* g2, const float* b2, float* scale2, float* shift2) {
    reduce_body(blockIdx.x, psum, psq, nblk, C, M, g1, b1, scale1, shift1, g2, b2, scale2, shift2);
}

__global__ __launch_bounds__(256) void reduce_stats2(
    const float* psumA, const float* psqA, int nblkA, int CA, int MA,
    const float* gA, const float* bA, float* scaleA, float* shiftA,
    const float* psumB, const float* psqB, int nblkB, int CB, int MB,
    const float* gB, const float* bB, float* scaleB, float* shiftB) {
    if ((int)blockIdx.x < CA)
        reduce_body(blockIdx.x, psumA, psqA, nblkA, CA, MA, gA, bA, scaleA, shiftA,
                    nullptr, nullptr, nullptr, nullptr);
    else
        reduce_body(blockIdx.x - CA, psumB, psqB, nblkB, CB, MB, gB, bB, scaleB, shiftB,
                    nullptr, nullptr, nullptr, nullptr);
}

// ---------------- parallel BN fold + MFMA-fragment pack ----------------
__device__ __forceinline__ void fold_body(
    int b, const float* __restrict__ scale, const float* __restrict__ shift, int C,
    const float* __restrict__ W, const float* __restrict__ bias,
    ushort* __restrict__ Wp, float* __restrict__ beff) {
    const int KT = C / 32;
    __shared__ float slab[32 * 128];
    if (b < KT) {
        const int kt = b;
        for (int i = threadIdx.x; i < 32 * 128; i += 256) {
            int kr = i >> 7, d = i & 127;
            int c = kt * 32 + kr;
            slab[i] = W[(size_t)c * 128 + d] * scale[c];
        }
        __syncthreads();
        #pragma unroll
        for (int t0 = 0; t0 < 512; t0 += 256) {
            int t = t0 + threadIdx.x;
            int lane = t & 63, dt = t >> 6;
            int d = dt * 16 + (lane & 15);
            int kb = (lane >> 4) * 8;
            uint4 o;
            o.x = (uint)f2bf(slab[(kb+0)*128 + d]) | ((uint)f2bf(slab[(kb+1)*128 + d]) << 16);
            o.y = (uint)f2bf(slab[(kb+2)*128 + d]) | ((uint)f2bf(slab[(kb+3)*128 + d]) << 16);
            o.z = (uint)f2bf(slab[(kb+4)*128 + d]) | ((uint)f2bf(slab[(kb+5)*128 + d]) << 16);
            o.w = (uint)f2bf(slab[(kb+6)*128 + d]) | ((uint)f2bf(slab[(kb+7)*128 + d]) << 16);
            *(uint4*)(Wp + (size_t)((dt * KT + kt) * 64 + lane) * 8) = o;
        }
    } else {
        const int bb = b - KT;
        const int dl = threadIdx.x & 15, ci = threadIdx.x >> 4;
        const int d = bb * 16 + dl;
        float a = 0.f;
        for (int c = ci; c < C; c += 16)
            a += shift[c] * W[(size_t)c * 128 + d];
        float* red = slab;
        red[threadIdx.x] = a;
        __syncthreads();
        if (ci == 0) {
            #pragma unroll
            for (int k = 1; k < 16; ++k) a += red[k * 16 + dl];
            beff[d] = bias[d] + a;
        }
    }
}

__global__ __launch_bounds__(256) void pack_fold_par(
    const float* scale, const float* shift, int C,
    const float* W, const float* bias, ushort* Wp, float* beff) {
    fold_body(blockIdx.x, scale, shift, C, W, bias, Wp, beff);
}

__global__ __launch_bounds__(256) void pack_fold2(
    const float* scaleA, const float* shiftA, int CA, const float* WA, const float* biasA,
    ushort* WpA, float* beffA,
    const float* scaleB, const float* shiftB, int CB, const float* WB, const float* biasB,
    ushort* WpB, float* beffB) {
    const int nA = CA / 32 + 8;
    const bool second = (int)blockIdx.x >= nA;
    fold_body(second ? blockIdx.x - nA : blockIdx.x,
              second ? scaleB : scaleA, second ? shiftB : shiftA, second ? CB : CA,
              second ? WB : WA, second ? biasB : biasA,
              second ? WpB : WpA, second ? beffB : beffA);
}

// ---------------- plain MFMA GEMM. MODE: 0=bf16 bias+relu, 1=f32 bias+relu, 2=bf16 plain ----------------
template<int KT, int MODE>
__device__ __forceinline__ void gemm_body(
    int b, const ushort* __restrict__ X,
    const ushort* __restrict__ Wp, const float* __restrict__ beff,
    ushort* __restrict__ Yb, float* __restrict__ Yf, int M) {
    constexpr int K = KT * 32;
    const int lane = threadIdx.x & 63;
    const int w = threadIdx.x >> 6;
    const int r0 = b * 128 + w * 32;
    const int rlo = lane & 15, khi = lane >> 4;

    f32x4 acc[2][8];
    #pragma unroll
    for (int rt = 0; rt < 2; ++rt)
        #pragma unroll
        for (int dt = 0; dt < 8; ++dt)
            acc[rt][dt] = (f32x4){0.f, 0.f, 0.f, 0.f};

    int row[2], idx[2];
    bool ok[2];
    #pragma unroll
    for (int rt = 0; rt < 2; ++rt) {
        row[rt] = r0 + rt * 16 + rlo;
        ok[rt] = row[rt] < M;
        idx[rt] = ok[rt] ? row[rt] : 0;
    }

    for (int kt = 0; kt < KT; ++kt) {
        short8 wf[8];
        #pragma unroll
        for (int dt = 0; dt < 8; ++dt)
            wf[dt] = *(const short8*)(Wp + (size_t)((dt * KT + kt) * 64 + lane) * 8);
        #pragma unroll
        for (int rt = 0; rt < 2; ++rt) {
            short8 bv = *(const short8*)(X + (size_t)idx[rt] * K + kt * 32 + khi * 8);
            #pragma unroll
            for (int dt = 0; dt < 8; ++dt)
                acc[rt][dt] = __builtin_amdgcn_mfma_f32_16x16x32_bf16(wf[dt], bv, acc[rt][dt], 0, 0, 0);
        }
    }

    #pragma unroll
    for (int rt = 0; rt < 2; ++rt) {
        if (!ok[rt]) continue;
        #pragma unroll
        for (int dt = 0; dt < 8; ++dt) {
            float v0, v1, v2, v3;
            if constexpr (MODE == 2) {
                v0 = acc[rt][dt][0]; v1 = acc[rt][dt][1];
                v2 = acc[rt][dt][2]; v3 = acc[rt][dt][3];
            } else {
                const float4 bz = *(const float4*)(beff + dt * 16 + khi * 4);
                v0 = fmaxf(acc[rt][dt][0] + bz.x, 0.f);
                v1 = fmaxf(acc[rt][dt][1] + bz.y, 0.f);
                v2 = fmaxf(acc[rt][dt][2] + bz.z, 0.f);
                v3 = fmaxf(acc[rt][dt][3] + bz.w, 0.f);
            }
            if constexpr (MODE == 1) {
                *(float4*)(Yf + (size_t)row[rt] * 128 + dt * 16 + khi * 4) = make_float4(v0, v1, v2, v3);
            } else {
                uint2 pk;
                pk.x = (uint)f2bf(v0) | ((uint)f2bf(v1) << 16);
                pk.y = (uint)f2bf(v2) | ((uint)f2bf(v3) << 16);
                *(uint2*)(Yb + (size_t)row[rt] * 128 + dt * 16 + khi * 4) = pk;
            }
        }
    }
}

__global__ __launch_bounds__(256) void gemm_final(
    const ushort* X, const ushort* Wp, const float* beff, float* Yf, int M) {
    gemm_body<8, 1>(blockIdx.x, X, Wp, beff, nullptr, Yf, M);
}

__global__ __launch_bounds__(256) void gemm_dual(
    const ushort* X,
    const ushort* Wp1, const float* beff1, ushort* Y1,
    const ushort* Wp2, const float* beff2, ushort* Y2, int M) {
    const int half = gridDim.x >> 1;
    const bool second = (int)blockIdx.x >= half;
    gemm_body<4, 0>(second ? blockIdx.x - half : blockIdx.x, X,
                    second ? Wp2 : Wp1, second ? beff2 : beff1,
                    second ? Y2 : Y1, nullptr, M);
}

// 4 node GEMMs (no bias/relu): hu@Wp1->HUw, hv@Wp1->HVw, hu@Wp2->HUl, hv@Wp2->HVl
__global__ __launch_bounds__(256) void gemm_quad(
    const ushort* hu, const ushort* hv,
    const ushort* Wp1, const ushort* Wp2,
    ushort* HUw, ushort* HVw, ushort* HUl, ushort* HVl, int M) {
    const int gq = gridDim.x >> 2;
    const int q = blockIdx.x / gq;
    const int b = blockIdx.x - q * gq;
    const ushort* X = (q & 1) ? hv : hu;
    const ushort* Wp = (q >= 2) ? Wp2 : Wp1;
    ushort* Y = (q == 0) ? HUw : (q == 1) ? HVw : (q == 2) ? HUl : HVl;
    gemm_body<4, 2>(b, X, Wp, nullptr, Y, nullptr, M);
}

// ---------------- seg-GEMM: 64-row blocks, 1 row-tile/wave, fused segmented mean ----------------
__device__ __forceinline__ void gemm_seg_body(
    int b, const ushort* __restrict__ X,
    const int* __restrict__ sdst, const int* __restrict__ cnt,
    const ushort* __restrict__ Wp, const float* __restrict__ beff,
    float* __restrict__ hacc, int M) {
    constexpr int KT = 4;
    __shared__ ushort tile[64 * 132];
    __shared__ int   s_node[64];
    __shared__ float s_scale[64];
    const int tid = threadIdx.x;
    const int lane = tid & 63;
    const int w = tid >> 6;
    const int rb = b * 64;
    const int rlo = lane & 15, khi = lane >> 4;

    if (tid < 64) {
        int r = rb + tid;
        int nd = (r < M) ? sdst[r] : -1;
        s_node[tid] = nd;
        s_scale[tid] = (nd >= 0) ? 0.5f / fmaxf((float)cnt[nd], 1.f) : 0.f;
    }

    f32x4 acc[8];
    #pragma unroll
    for (int dt = 0; dt < 8; ++dt)
        acc[dt] = (f32x4){0.f, 0.f, 0.f, 0.f};

    const int row = rb + w * 16 + rlo;
    const bool ok = row < M;
    const int idx = ok ? row : 0;

    for (int kt = 0; kt < KT; ++kt) {
        short8 bv = *(const short8*)(X + (size_t)idx * 128 + kt * 32 + khi * 8);
        #pragma unroll 4
        for (int dt = 0; dt < 8; ++dt) {
            short8 wf = *(const short8*)(Wp + (size_t)((dt * KT + kt) * 64 + lane) * 8);
            acc[dt] = __builtin_amdgcn_mfma_f32_16x16x32_bf16(wf, bv, acc[dt], 0, 0, 0);
        }
    }

    const int rl = w * 16 + rlo;
    #pragma unroll
    for (int dt = 0; dt < 8; ++dt) {
        const float4 bz = *(const float4*)(beff + dt * 16 + khi * 4);
        float v0 = 0.f, v1 = 0.f, v2 = 0.f, v3 = 0.f;
        if (ok) {
            v0 = fmaxf(acc[dt][0] + bz.x, 0.f);
            v1 = fmaxf(acc[dt][1] + bz.y, 0.f);
            v2 = fmaxf(acc[dt][2] + bz.z, 0.f);
            v3 = fmaxf(acc[dt][3] + bz.w, 0.f);
        }
        uint2 pk;
        pk.x = (uint)f2bf(v0) | ((uint)f2bf(v1) << 16);
        pk.y = (uint)f2bf(v2) | ((uint)f2bf(v3) << 16);
        *(uint2*)&tile[rl * 132 + dt * 16 + khi * 4] = pk;
    }
    __syncthreads();

    const int col = tid & 127;
    const int rs = (tid >> 7) * 32;
    int cur = s_node[rs];
    float scl = s_scale[rs];
    float sum = 0.f;
    for (int r = rs; r < rs + 32; ++r) {
        int nd = s_node[r];
        if (nd != cur) {
            if (cur >= 0)
                atomicAdd(&hacc[(size_t)cur * 128 + col], sum * scl);
            cur = nd; scl = s_scale[r]; sum = 0.f;
        }
        sum += bf2f(tile[r * 132 + col]);
    }
    if (cur >= 0)
        atomicAdd(&hacc[(size_t)cur * 128 + col], sum * scl);
}

__global__ __launch_bounds__(256) void gemm_seg2(
    const ushort* XA, const int* sdstA, const int* cntA,
    const ushort* WpA, const float* beffA, int MA,
    const ushort* XB, const int* sdstB, const int* cntB,
    const ushort* WpB, const float* beffB, int MB,
    float* hacc) {
    const int half = gridDim.x >> 1;
    const bool second = (int)blockIdx.x >= half;
    gemm_seg_body(second ? blockIdx.x - half : blockIdx.x,
                  second ? XB : XA,
                  second ? sdstB : sdstA, second ? cntB : cntA,
                  second ? WpB : WpA, second ? beffB : beffA,
                  hacc, second ? MB : MA);
}

// ---------------- edge gather-add-relu + segmented mean (dual, run-hoisted HV) ----------------
__global__ __launch_bounds__(256) void edge_seg2(
    const uint* __restrict__ HUw, const uint* __restrict__ HVw,
    const int* __restrict__ sw, const int* __restrict__ dw,
    const int* __restrict__ cw, const float* __restrict__ bw,
    const uint* __restrict__ HUl, const uint* __restrict__ HVl,
    const int* __restrict__ sl, const int* __restrict__ dl,
    const int* __restrict__ cl, const float* __restrict__ bl,
    float* __restrict__ hacc, int E) {
    const int gh = gridDim.x >> 1;
    const bool second = (int)blockIdx.x >= gh;
    const uint* HU = second ? HUl : HUw;
    const uint* HV = second ? HVl : HVw;
    const int* sidx = second ? sl : sw;
    const int* didx = second ? dl : dw;
    const int* cnt = second ? cl : cw;
    const float* beff = second ? bl : bw;
    const int b = second ? blockIdx.x - gh : blockIdx.x;

    const int lane = threadIdx.x & 63;
    const int gwave = (b * 256 + threadIdx.x) >> 6;
    const int nwave = (gh * 256) >> 6;
    const float bz0 = beff[2 * lane];
    const float bz1 = beff[2 * lane + 1];

    for (int base = gwave * 64; base < E; base += nwave * 64) {
        int e = base + lane;
        int su = (e < E) ? sidx[e] : 0;
        int dv = (e < E) ? didx[e] : 0;
        int cn = min(64, E - base);
        int cur = -1; float scl = 0.f, a0 = 0.f, a1 = 0.f, hv0 = 0.f, hv1 = 0.f;
        auto body = [&](int j) {
            int aa = __shfl(su, j), dd = __shfl(dv, j);
            if (dd != cur) {               // wave-uniform branch (shfl broadcast)
                if (cur >= 0) {
                    atomicAdd(&hacc[(size_t)cur * 128 + 2 * lane],     a0 * scl);
                    atomicAdd(&hacc[(size_t)cur * 128 + 2 * lane + 1], a1 * scl);
                }
                cur = dd; scl = 0.5f / fmaxf((float)cnt[dd], 1.f); a0 = 0.f; a1 = 0.f;
                uint vv = HV[(size_t)dd * 64 + lane];
                hv0 = bf2f(vv & 0xffffu); hv1 = bf2f(vv >> 16);
            }
            uint uu = HU[(size_t)aa * 64 + lane];
            a0 += fmaxf(bf2f(uu & 0xffffu) + hv0 + bz0, 0.f);
            a1 += fmaxf(bf2f(uu >> 16)     + hv1 + bz1, 0.f);
        };
        if (cn == 64) {
            #pragma unroll 4
            for (int j = 0; j < 64; ++j) body(j);
        } else {
            for (int j = 0; j < cn; ++j) body(j);
        }
        if (cur >= 0) {
            atomicAdd(&hacc[(size_t)cur * 128 + 2 * lane],     a0 * scl);
            atomicAdd(&hacc[(size_t)cur * 128 + 2 * lane + 1], a1 * scl);
        }
    }
}

// ---------------- hacc -> bf16 h (+fh half), re-zero hacc ----------------
__global__ __launch_bounds__(256) void finalize_hacc(
    float2* __restrict__ hacc2, uint* __restrict__ h2, uint* __restrict__ fh2,
    int fhsel, int N) {
    const int total = N * 64;
    for (int i = blockIdx.x * 256 + threadIdx.x; i < total; i += gridDim.x * 256) {
        float2 v = hacc2[i];
        uint pk = (uint)f2bf(v.x) | ((uint)f2bf(v.y) << 16);
        h2[i] = pk;
        if (fhsel >= 0) fh2[((size_t)(i >> 6)) * 128 + fhsel * 64 + (i & 63)] = pk;
        hacc2[i] = make_float2(0.f, 0.f);
    }
}

// ---------------- launch ----------------
extern "C" void kernel_launch(void* const* d_in, const int* in_sizes, int n_in,
                              void* d_out, int out_size, void* d_ws, size_t ws_size,
                              hipStream_t stream) {
    const float* win_f  = (const float*)d_in[0];
    const float* loss_f = (const float*)d_in[1];
    struct BP { const float *g, *b, *W, *bias; };
    auto bp = [&](int i) { return BP{ (const float*)d_in[i], (const float*)d_in[i+1],
                                      (const float*)d_in[i+2], (const float*)d_in[i+3] }; };
    BP wi = bp(2), li = bp(6), srcp = bp(10), dstp = bp(14), wl = bp(18), ll = bp(22), outp = bp(26);
    const int* win_src  = (const int*)d_in[30];
    const int* win_dst  = (const int*)d_in[31];
    const int* loss_src = (const int*)d_in[32];
    const int* loss_dst = (const int*)d_in[33];
    const int E = in_sizes[30];
    const int N = out_size / 128;
    (void)n_in;

    char* base = (char*)d_ws;
    size_t off_b = 0;
    auto alloc = [&](size_t bytes) {
        size_t cur = off_b;
        off_b += (bytes + 255) & ~(size_t)255;
        return (void*)(base + cur);
    };
    float*  hacc = (float*)alloc((size_t)N * 128 * 4);
    ushort* h    = (ushort*)alloc((size_t)N * 128 * 2);
    ushort* hu   = (ushort*)alloc((size_t)N * 128 * 2);
    ushort* hv   = (ushort*)alloc((size_t)N * 128 * 2);
    ushort* fh   = (ushort*)alloc((size_t)N * 256 * 2);
    ushort* HUw  = (ushort*)alloc((size_t)N * 128 * 2);
    ushort* HVw  = (ushort*)alloc((size_t)N * 128 * 2);
    ushort* HUl  = (ushort*)alloc((size_t)N * 128 * 2);
    ushort* HVl  = (ushort*)alloc((size_t)N * 128 * 2);
    int* cntw  = (int*)alloc((size_t)N * 4);
    int* cntl  = (int*)alloc((size_t)N * 4);
    int* offw  = (int*)alloc((size_t)(N + 1) * 4);
    int* offl  = (int*)alloc((size_t)(N + 1) * 4);
    int* curw  = (int*)alloc((size_t)N * 4);
    int* curl  = (int*)alloc((size_t)N * 4);
    int* ipermw= (int*)alloc((size_t)E * 4);
    int* ssrcw = (int*)alloc((size_t)E * 4);
    int* sdstw = (int*)alloc((size_t)E * 4);
    int* iperml= (int*)alloc((size_t)E * 4);
    int* ssrcl = (int*)alloc((size_t)E * 4);
    int* sdstl = (int*)alloc((size_t)E * 4);
    float* psumW = (float*)alloc((size_t)NPART_MAX * 128 * 4);
    float* psqW  = (float*)alloc((size_t)NPART_MAX * 128 * 4);
    float* psumL = (float*)alloc((size_t)NPART_MAX * 128 * 4);
    float* psqL  = (float*)alloc((size_t)NPART_MAX * 128 * 4);
    float* psumN = (float*)alloc((size_t)512 * 256 * 4);
    float* psqN  = (float*)alloc((size_t)512 * 256 * 4);
    float* scal1 = (float*)alloc(256 * 4);
    float* shif1 = (float*)alloc(256 * 4);
    float* scal2 = (float*)alloc(256 * 4);
    float* shif2 = (float*)alloc(256 * 4);
    ushort* Wp1 = (ushort*)alloc((size_t)256 * 128 * 2);
    ushort* Wp2 = (ushort*)alloc((size_t)256 * 128 * 2);
    float* beff1 = (float*)alloc(128 * 4);
    float* beff2 = (float*)alloc(128 * 4);
    ushort* Xbf1 = (ushort*)alloc((size_t)E * 128 * 2);
    if (off_b > ws_size) return;           // base layout must fit
    size_t off_one = off_b;
    ushort* Xbf2 = (ushort*)alloc((size_t)E * 128 * 2);
    const bool have_x2 = (off_b <= ws_size);
    if (!have_x2) off_b = off_one;

    const int gE64 = (E + 63) / 64;
    const int gN = (N + 127) / 128;
    const int NBF = 1024;   // convert-stats blocks per etype
    const int NBG = 2048;   // gather/edge blocks per etype
    const int NBN = 512;    // node-stats blocks

    // phase 0: counting sort (both etypes)
    hipMemsetAsync(cntw, 0, (size_t)N * 4, stream);
    hipMemsetAsync(cntl, 0, (size_t)N * 4, stream);
    hipMemsetAsync(hacc, 0, (size_t)N * 128 * 4, stream);
    hist2<<<2048, 256, 0, stream>>>(win_dst, loss_dst, E, cntw, cntl);
    scan2<<<2, 256, 0, stream>>>(cntw, cntl, N, offw, curw, offl, curl);
    scatter2<<<2048, 256, 0, stream>>>(win_src, win_dst, loss_src, loss_dst, E,
                                       curw, curl, ipermw, ssrcw, sdstw, iperml, ssrcl, sdstl);

    // initial edge blocks (E-row GEMM unavoidable here: true edge features)
    if (have_x2) {
        convert_two<<<2 * NBF, 256, 0, stream>>>(
            (const float4*)win_f, ipermw, (uint2*)Xbf1, psumW, psqW,
            (const float4*)loss_f, iperml, (uint2*)Xbf2, psumL, psqL, E);
        reduce_stats2<<<256, 256, 0, stream>>>(
            psumW, psqW, NBF, 128, E, wi.g, wi.b, scal1, shif1,
            psumL, psqL, NBF, 128, E, li.g, li.b, scal2, shif2);
        pack_fold2<<<24, 256, 0, stream>>>(scal1, shif1, 128, wi.W, wi.bias, Wp1, beff1,
                                           scal2, shif2, 128, li.W, li.bias, Wp2, beff2);
        gemm_seg2<<<2 * gE64, 256, 0, stream>>>(
            Xbf1, sdstw, cntw, Wp1, beff1, E,
            Xbf2, sdstl, cntl, Wp2, beff2, E, hacc);
    } else {
        convert_one<<<NBF, 256, 0, stream>>>((const float4*)win_f, ipermw, E, (uint2*)Xbf1, psumW, psqW);
        reduce_stats<<<128, 256, 0, stream>>>(psumW, psqW, NBF, 128, E, wi.g, wi.b, scal1, shif1,
                                              nullptr, nullptr, nullptr, nullptr);
        pack_fold_par<<<12, 256, 0, stream>>>(scal1, shif1, 128, wi.W, wi.bias, Wp1, beff1);
        gemm_seg2<<<2 * gE64, 256, 0, stream>>>(
            Xbf1, sdstw, cntw, Wp1, beff1, E,
            Xbf1, sdstw, cntw, Wp1, beff1, 0, hacc);
        convert_one<<<NBF, 256, 0, stream>>>((const float4*)loss_f, iperml, E, (uint2*)Xbf1, psumW, psqW);
        reduce_stats<<<128, 256, 0, stream>>>(psumW, psqW, NBF, 128, E, li.g, li.b, scal1, shif1,
                                              nullptr, nullptr, nullptr, nullptr);
        pack_fold_par<<<12, 256, 0, stream>>>(scal1, shif1, 128, li.W, li.bias, Wp1, beff1);
        gemm_seg2<<<2 * gE64, 256, 0, stream>>>(
            Xbf1, sdstl, cntl, Wp1, beff1, E,
            Xbf1, sdstl, cntl, Wp1, beff1, 0, hacc);
    }
    finalize_hacc<<<512, 256, 0, stream>>>((float2*)hacc, (uint*)h, (uint*)fh, 0, N);

    for (int it = 0; it < 3; ++it) {
        colstats_b128<<<NBN, 256, 0, stream>>>((const uint*)h, N, psumN, psqN);
        reduce_stats<<<128, 256, 0, stream>>>(psumN, psqN, NBN, 128, N, srcp.g, srcp.b, scal1, shif1,
                                              dstp.g, dstp.b, scal2, shif2);
        pack_fold2<<<24, 256, 0, stream>>>(scal1, shif1, 128, srcp.W, srcp.bias, Wp1, beff1,
                                           scal2, shif2, 128, dstp.W, dstp.bias, Wp2, beff2);
        gemm_dual<<<2 * gN, 256, 0, stream>>>(h, Wp1, beff1, hu, Wp2, beff2, hv, N);

        gather_stats2<<<2 * NBG, 256, 0, stream>>>(
            (const uint2*)hu, (const uint2*)hv,
            ssrcw, sdstw, psumW, psqW, ssrcl, sdstl, psumL, psqL, E);
        reduce_stats2<<<256, 256, 0, stream>>>(
            psumW, psqW, NBG, 128, E, wl.g, wl.b, scal1, shif1,
            psumL, psqL, NBG, 128, E, ll.g, ll.b, scal2, shif2);
        pack_fold2<<<24, 256, 0, stream>>>(scal1, shif1, 128, wl.W, wl.bias, Wp1, beff1,
                                           scal2, shif2, 128, ll.W, ll.bias, Wp2, beff2);
        gemm_quad<<<4 * gN, 256, 0, stream>>>(hu, hv, Wp1, Wp2, HUw, HVw, HUl, HVl, N);
        edge_seg2<<<2 * NBG, 256, 0, stream>>>(
            (const uint*)HUw, (const uint*)HVw, ssrcw, sdstw, cntw, beff1,
            (const uint*)HUl, (const uint*)HVl, ssrcl, sdstl, cntl, beff2,
            hacc, E);
        finalize_hacc<<<512, 256, 0, stream>>>((float2*)hacc, (uint*)h, (uint*)fh,
                                               (it == 2) ? 1 : -1, N);
    }

    colstats_b256<<<NBN, 256, 0, stream>>>((const uint*)fh, N, psumN, psqN);
    reduce_stats<<<256, 256, 0, stream>>>(psumN, psqN, NBN, 256, N, outp.g, outp.b, scal1, shif1,
                                          nullptr, nullptr, nullptr, nullptr);
    pack_fold_par<<<16, 256, 0, stream>>>(scal1, shif1, 256, outp.W, outp.bias, Wp1, beff1);
    gemm_final<<<gN, 256, 0, stream>>>(fh, Wp1, beff1, (float*)d_out, N);
}

// Round 12
// 810.291 us; speedup vs baseline: 5.8235x; 1.0373x over previous
//
#include <hip/hip_runtime.h>

#define NPART_MAX 2048

typedef __attribute__((ext_vector_type(8))) short short8;
typedef __attribute__((ext_vector_type(4))) float f32x4;

__device__ __forceinline__ float bf2f(uint u) {
    union { uint u; float f; } v; v.u = u << 16; return v.f;
}
__device__ __forceinline__ ushort f2bf(float f) {
    union { float f; uint u; } v; v.f = f;
    uint r = v.u + 0x7fffu + ((v.u >> 16) & 1u);
    return (ushort)(r >> 16);
}

// ---------------- phase 0: counting sort by dst (both etypes per launch) ----------------
__global__ __launch_bounds__(256) void hist2(const int* __restrict__ dw, const int* __restrict__ dl,
                                             int E, int* __restrict__ cw, int* __restrict__ cl) {
    const int half = gridDim.x >> 1;
    const bool second = (int)blockIdx.x >= half;
    const int* dst = second ? dl : dw;
    int* cnt = second ? cl : cw;
    const int b = second ? blockIdx.x - half : blockIdx.x;
    for (int e = b * 256 + threadIdx.x; e < E; e += half * 256)
        atomicAdd(&cnt[dst[e]], 1);
}

__global__ __launch_bounds__(256) void scan2(const int* __restrict__ cw, const int* __restrict__ cl,
                                             int n, int* offw, int* curw, int* offl, int* curl) {
    const int* cnt = blockIdx.x ? cl : cw;
    int* off = blockIdx.x ? offl : offw;
    int* cur = blockIdx.x ? curl : curw;
    __shared__ int warpsums[4];
    __shared__ int s_carry;
    if (threadIdx.x == 0) s_carry = 0;
    __syncthreads();
    for (int base = 0; base < n; base += 1024) {
        int i0 = base + threadIdx.x * 4;
        int v0 = (i0 + 0 < n) ? cnt[i0 + 0] : 0;
        int v1 = (i0 + 1 < n) ? cnt[i0 + 1] : 0;
        int v2 = (i0 + 2 < n) ? cnt[i0 + 2] : 0;
        int v3 = (i0 + 3 < n) ? cnt[i0 + 3] : 0;
        int tsum = v0 + v1 + v2 + v3;
        int lane = threadIdx.x & 63, w = threadIdx.x >> 6;
        int x = tsum;
        for (int d = 1; d < 64; d <<= 1) {
            int y = __shfl_up(x, d);
            if (lane >= d) x += y;
        }
        if (lane == 63) warpsums[w] = x;
        __syncthreads();
        int woff = 0;
        for (int k = 0; k < w; ++k) woff += warpsums[k];
        int excl = x - tsum + woff + s_carry;
        if (i0 + 0 < n) { off[i0 + 0] = excl; cur[i0 + 0] = excl; } excl += v0;
        if (i0 + 1 < n) { off[i0 + 1] = excl; cur[i0 + 1] = excl; } excl += v1;
        if (i0 + 2 < n) { off[i0 + 2] = excl; cur[i0 + 2] = excl; } excl += v2;
        if (i0 + 3 < n) { off[i0 + 3] = excl; cur[i0 + 3] = excl; } excl += v3;
        __syncthreads();
        if (threadIdx.x == 255) s_carry = excl;
        __syncthreads();
    }
    if (threadIdx.x == 0) off[n] = s_carry;
}

__global__ __launch_bounds__(256) void scatter2(
    const int* __restrict__ sw, const int* __restrict__ dw,
    const int* __restrict__ sl, const int* __restrict__ dl, int E,
    int* __restrict__ curw, int* __restrict__ curl,
    int* __restrict__ permw, int* __restrict__ ssrcw, int* __restrict__ sdstw,
    int* __restrict__ perml, int* __restrict__ ssrcl, int* __restrict__ sdstl) {
    const int half = gridDim.x >> 1;
    const bool second = (int)blockIdx.x >= half;
    const int* src = second ? sl : sw;
    const int* dst = second ? dl : dw;
    int* cursor = second ? curl : curw;
    int* perm = second ? perml : permw;
    int* ssrc = second ? ssrcl : ssrcw;
    int* sdst = second ? sdstl : sdstw;
    const int b = second ? blockIdx.x - half : blockIdx.x;
    for (int e = b * 256 + threadIdx.x; e < E; e += half * 256) {
        int d = dst[e];
        int p = atomicAdd(&cursor[d], 1);
        perm[p] = e;
        ssrc[p] = src[e];
        sdst[p] = d;
    }
}

// ---------------- dual linear fp32 col-stats (no writes) ----------------
__device__ __forceinline__ void statsf_body(
    int b, int nb, const float4* __restrict__ x4, int M,
    float* __restrict__ psum, float* __restrict__ psq) {
    const int cg = threadIdx.x & 31;
    const int sub = threadIdx.x >> 5;
    float s0=0,s1=0,s2=0,s3=0,q0=0,q1=0,q2=0,q3=0;
    for (int r = b * 8 + sub; r < M; r += nb * 8) {
        float4 v = x4[(size_t)r * 32 + cg];
        s0 += v.x; q0 += v.x * v.x;
        s1 += v.y; q1 += v.y * v.y;
        s2 += v.z; q2 += v.z * v.z;
        s3 += v.w; q3 += v.w * v.w;
    }
    __shared__ float rs[256][4], rq[256][4];
    rs[threadIdx.x][0]=s0; rs[threadIdx.x][1]=s1; rs[threadIdx.x][2]=s2; rs[threadIdx.x][3]=s3;
    rq[threadIdx.x][0]=q0; rq[threadIdx.x][1]=q1; rq[threadIdx.x][2]=q2; rq[threadIdx.x][3]=q3;
    __syncthreads();
    if (sub == 0) {
        #pragma unroll
        for (int k = 1; k < 8; ++k) {
            s0 += rs[k*32+cg][0]; s1 += rs[k*32+cg][1];
            s2 += rs[k*32+cg][2]; s3 += rs[k*32+cg][3];
            q0 += rq[k*32+cg][0]; q1 += rq[k*32+cg][1];
            q2 += rq[k*32+cg][2]; q3 += rq[k*32+cg][3];
        }
        psum[b*128 + cg*4+0] = s0; psq[b*128 + cg*4+0] = q0;
        psum[b*128 + cg*4+1] = s1; psq[b*128 + cg*4+1] = q1;
        psum[b*128 + cg*4+2] = s2; psq[b*128 + cg*4+2] = q2;
        psum[b*128 + cg*4+3] = s3; psq[b*128 + cg*4+3] = q3;
    }
}

__global__ __launch_bounds__(256) void stats_f32_2(
    const float4* xa, float* psa, float* pqa,
    const float4* xb, float* psb, float* pqb, int M) {
    const int half = gridDim.x >> 1;
    const bool second = (int)blockIdx.x >= half;
    statsf_body(second ? blockIdx.x - half : blockIdx.x, half,
                second ? xb : xa, M, second ? psb : psa, second ? pqb : pqa);
}

// ---------------- dual gather stats with run-hoisted hv (sorted by dst) ----------------
__global__ __launch_bounds__(256) void gather_stats2(
    const uint2* __restrict__ hu4, const uint2* __restrict__ hv4,
    const int* __restrict__ sw, const int* __restrict__ dw,
    float* __restrict__ psumW, float* __restrict__ psqW,
    const int* __restrict__ sl, const int* __restrict__ dl,
    float* __restrict__ psumL, float* __restrict__ psqL, int E) {
    const int gh = gridDim.x >> 1;
    const bool second = (int)blockIdx.x >= gh;
    const int* sidx = second ? sl : sw;
    const int* didx = second ? dl : dw;
    float* psum = second ? psumL : psumW;
    float* psq  = second ? psqL  : psqW;
    const int b = second ? blockIdx.x - gh : blockIdx.x;

    const int lane = threadIdx.x & 63;
    const int w = threadIdx.x >> 6;
    const int half = lane >> 5;
    const int cg = lane & 31;
    const int gwave = (b * 256 + threadIdx.x) >> 6;
    const int nwave = (gh * 256) >> 6;
    float s0=0,s1=0,s2=0,s3=0,q0=0,q1=0,q2=0,q3=0;
    for (int base = gwave * 64; base < E; base += nwave * 64) {
        int e = base + lane;
        int su = (e < E) ? sidx[e] : 0;
        int dv = (e < E) ? didx[e] : 0;
        int cnt = min(64, E - base);
        int curd = -1;
        float hv0=0,hv1=0,hv2=0,hv3=0;
        float rs0=0,rs1=0,rs2=0,rs3=0,rq0=0,rq1=0,rq2=0,rq3=0,rlen=0;
        auto flush = [&]() {
            if (curd >= 0) {
                s0 += rs0 + rlen*hv0; q0 += rq0 + 2.f*hv0*rs0 + rlen*hv0*hv0;
                s1 += rs1 + rlen*hv1; q1 += rq1 + 2.f*hv1*rs1 + rlen*hv1*hv1;
                s2 += rs2 + rlen*hv2; q2 += rq2 + 2.f*hv2*rs2 + rlen*hv2*hv2;
                s3 += rs3 + rlen*hv3; q3 += rq3 + 2.f*hv3*rs3 + rlen*hv3*hv3;
            }
        };
        #pragma unroll 4
        for (int j = 0; j < 32; ++j) {
            int eidx = 2 * j + half;
            int a = __shfl(su, eidx), dd = __shfl(dv, eidx);
            if (eidx < cnt) {
                if (dd != curd) {
                    flush();
                    curd = dd;
                    uint2 vv = hv4[(size_t)dd * 32 + cg];
                    hv0 = bf2f(vv.x & 0xffffu); hv1 = bf2f(vv.x >> 16);
                    hv2 = bf2f(vv.y & 0xffffu); hv3 = bf2f(vv.y >> 16);
                    rs0=rs1=rs2=rs3=0; rq0=rq1=rq2=rq3=0; rlen=0;
                }
                uint2 uu = hu4[(size_t)a * 32 + cg];
                float u0 = bf2f(uu.x & 0xffffu), u1 = bf2f(uu.x >> 16);
                float u2 = bf2f(uu.y & 0xffffu), u3 = bf2f(uu.y >> 16);
                rs0 += u0; rq0 += u0*u0;
                rs1 += u1; rq1 += u1*u1;
                rs2 += u2; rq2 += u2*u2;
                rs3 += u3; rq3 += u3*u3;
                rlen += 1.f;
            }
        }
        flush();
    }
    __shared__ float redS[8][32][4], redQ[8][32][4];
    const int ri = w * 2 + half;
    redS[ri][cg][0]=s0; redS[ri][cg][1]=s1; redS[ri][cg][2]=s2; redS[ri][cg][3]=s3;
    redQ[ri][cg][0]=q0; redQ[ri][cg][1]=q1; redQ[ri][cg][2]=q2; redQ[ri][cg][3]=q3;
    __syncthreads();
    if (threadIdx.x < 128) {
        int c = threadIdx.x;
        int cgg = c >> 2, k = c & 3;
        float s = 0.f, q = 0.f;
        #pragma unroll
        for (int i = 0; i < 8; ++i) { s += redS[i][cgg][k]; q += redQ[i][cgg][k]; }
        psum[(size_t)b * 128 + c] = s;
        psq [(size_t)b * 128 + c] = q;
    }
}

// ---------------- per-column reduce of partials -> scale/shift ----------------
__device__ __forceinline__ void reduce_body(
    int c, const float* __restrict__ psum, const float* __restrict__ psq,
    int nblk, int C, int M,
    const float* __restrict__ g1, const float* __restrict__ b1,
    float* __restrict__ scale1, float* __restrict__ shift1,
    const float* g2, const float* b2, float* scale2, float* shift2) {
    double s = 0.0, q = 0.0;
    for (int i = threadIdx.x; i < nblk; i += 256) {
        s += (double)psum[(size_t)i * C + c];
        q += (double)psq [(size_t)i * C + c];
    }
    __shared__ double ss[256], qs[256];
    ss[threadIdx.x] = s; qs[threadIdx.x] = q;
    __syncthreads();
    for (int d = 128; d > 0; d >>= 1) {
        if (threadIdx.x < d) {
            ss[threadIdx.x] += ss[threadIdx.x + d];
            qs[threadIdx.x] += qs[threadIdx.x + d];
        }
        __syncthreads();
    }
    if (threadIdx.x == 0) {
        double m = ss[0] / (double)M;
        double v = qs[0] / (double)M - m * m;
        if (v < 0.0) v = 0.0;
        double rs = 1.0 / sqrt(v + 1e-5);
        float mf = (float)m;
        float sc1 = (float)(rs * (double)g1[c]);
        scale1[c] = sc1;
        shift1[c] = b1[c] - mf * sc1;
        if (g2) {
            float sc2 = (float)(rs * (double)g2[c]);
            scale2[c] = sc2;
            shift2[c] = b2[c] - mf * sc2;
        }
    }
}

__global__ __launch_bounds__(256) void reduce_stats(
    const float* psum, const float* psq, int nblk, int C, int M,
    const float* g1, const float* b1, float* scale1, float* shift1,
    const float* g2, const float* b2, float* scale2, float* shift2) {
    reduce_body(blockIdx.x, psum, psq, nblk, C, M, g1, b1, scale1, shift1, g2, b2, scale2, shift2);
}

__global__ __launch_bounds__(256) void reduce_stats2(
    const float* psumA, const float* psqA, int nblkA, int CA, int MA,
    const float* gA, const float* bA, float* scaleA, float* shiftA,
    const float* psumB, const float* psqB, int nblkB, int CB, int MB,
    const float* gB, const float* bB, float* scaleB, float* shiftB) {
    if ((int)blockIdx.x < CA)
        reduce_body(blockIdx.x, psumA, psqA, nblkA, CA, MA, gA, bA, scaleA, shiftA,
                    nullptr, nullptr, nullptr, nullptr);
    else
        reduce_body(blockIdx.x - CA, psumB, psqB, nblkB, CB, MB, gB, bB, scaleB, shiftB,
                    nullptr, nullptr, nullptr, nullptr);
}

// ---------------- parallel BN fold + MFMA-fragment pack ----------------
__device__ __forceinline__ void fold_body(
    int b, const float* __restrict__ scale, const float* __restrict__ shift, int C,
    const float* __restrict__ W, const float* __restrict__ bias,
    ushort* __restrict__ Wp, float* __restrict__ beff) {
    const int KT = C / 32;
    __shared__ float slab[32 * 128];
    if (b < KT) {
        const int kt = b;
        for (int i = threadIdx.x; i < 32 * 128; i += 256) {
            int kr = i >> 7, d = i & 127;
            int c = kt * 32 + kr;
            slab[i] = W[(size_t)c * 128 + d] * scale[c];
        }
        __syncthreads();
        #pragma unroll
        for (int t0 = 0; t0 < 512; t0 += 256) {
            int t = t0 + threadIdx.x;
            int lane = t & 63, dt = t >> 6;
            int d = dt * 16 + (lane & 15);
            int kb = (lane >> 4) * 8;
            uint4 o;
            o.x = (uint)f2bf(slab[(kb+0)*128 + d]) | ((uint)f2bf(slab[(kb+1)*128 + d]) << 16);
            o.y = (uint)f2bf(slab[(kb+2)*128 + d]) | ((uint)f2bf(slab[(kb+3)*128 + d]) << 16);
            o.z = (uint)f2bf(slab[(kb+4)*128 + d]) | ((uint)f2bf(slab[(kb+5)*128 + d]) << 16);
            o.w = (uint)f2bf(slab[(kb+6)*128 + d]) | ((uint)f2bf(slab[(kb+7)*128 + d]) << 16);
            *(uint4*)(Wp + (size_t)((dt * KT + kt) * 64 + lane) * 8) = o;
        }
    } else {
        const int bb = b - KT;
        const int dl = threadIdx.x & 15, ci = threadIdx.x >> 4;
        const int d = bb * 16 + dl;
        float a = 0.f;
        for (int c = ci; c < C; c += 16)
            a += shift[c] * W[(size_t)c * 128 + d];
        float* red = slab;
        red[threadIdx.x] = a;
        __syncthreads();
        if (ci == 0) {
            #pragma unroll
            for (int k = 1; k < 16; ++k) a += red[k * 16 + dl];
            beff[d] = bias[d] + a;
        }
    }
}

__global__ __launch_bounds__(256) void pack_fold_par(
    const float* scale, const float* shift, int C,
    const float* W, const float* bias, ushort* Wp, float* beff) {
    fold_body(blockIdx.x, scale, shift, C, W, bias, Wp, beff);
}

__global__ __launch_bounds__(256) void pack_fold2(
    const float* scaleA, const float* shiftA, int CA, const float* WA, const float* biasA,
    ushort* WpA, float* beffA,
    const float* scaleB, const float* shiftB, int CB, const float* WB, const float* biasB,
    ushort* WpB, float* beffB) {
    const int nA = CA / 32 + 8;
    const bool second = (int)blockIdx.x >= nA;
    fold_body(second ? blockIdx.x - nA : blockIdx.x,
              second ? scaleB : scaleA, second ? shiftB : shiftA, second ? CB : CA,
              second ? WB : WA, second ? biasB : biasA,
              second ? WpB : WpA, second ? beffB : beffA);
}

// ---------------- plain MFMA GEMM. MODE: 0=bf16 bias+relu, 1=f32 bias+relu, 2=bf16 plain ----------------
template<int KT, int MODE>
__device__ __forceinline__ void gemm_body(
    int b, const ushort* __restrict__ X,
    const ushort* __restrict__ Wp, const float* __restrict__ beff,
    ushort* __restrict__ Yb, float* __restrict__ Yf, int M) {
    constexpr int K = KT * 32;
    const int lane = threadIdx.x & 63;
    const int w = threadIdx.x >> 6;
    const int r0 = b * 128 + w * 32;
    const int rlo = lane & 15, khi = lane >> 4;

    f32x4 acc[2][8];
    #pragma unroll
    for (int rt = 0; rt < 2; ++rt)
        #pragma unroll
        for (int dt = 0; dt < 8; ++dt)
            acc[rt][dt] = (f32x4){0.f, 0.f, 0.f, 0.f};

    int row[2], idx[2];
    bool ok[2];
    #pragma unroll
    for (int rt = 0; rt < 2; ++rt) {
        row[rt] = r0 + rt * 16 + rlo;
        ok[rt] = row[rt] < M;
        idx[rt] = ok[rt] ? row[rt] : 0;
    }

    for (int kt = 0; kt < KT; ++kt) {
        short8 wf[8];
        #pragma unroll
        for (int dt = 0; dt < 8; ++dt)
            wf[dt] = *(const short8*)(Wp + (size_t)((dt * KT + kt) * 64 + lane) * 8);
        #pragma unroll
        for (int rt = 0; rt < 2; ++rt) {
            short8 bv = *(const short8*)(X + (size_t)idx[rt] * K + kt * 32 + khi * 8);
            #pragma unroll
            for (int dt = 0; dt < 8; ++dt)
                acc[rt][dt] = __builtin_amdgcn_mfma_f32_16x16x32_bf16(wf[dt], bv, acc[rt][dt], 0, 0, 0);
        }
    }

    #pragma unroll
    for (int rt = 0; rt < 2; ++rt) {
        if (!ok[rt]) continue;
        #pragma unroll
        for (int dt = 0; dt < 8; ++dt) {
            float v0, v1, v2, v3;
            if constexpr (MODE == 2) {
                v0 = acc[rt][dt][0]; v1 = acc[rt][dt][1];
                v2 = acc[rt][dt][2]; v3 = acc[rt][dt][3];
            } else {
                const float4 bz = *(const float4*)(beff + dt * 16 + khi * 4);
                v0 = fmaxf(acc[rt][dt][0] + bz.x, 0.f);
                v1 = fmaxf(acc[rt][dt][1] + bz.y, 0.f);
                v2 = fmaxf(acc[rt][dt][2] + bz.z, 0.f);
                v3 = fmaxf(acc[rt][dt][3] + bz.w, 0.f);
            }
            if constexpr (MODE == 1) {
                *(float4*)(Yf + (size_t)row[rt] * 128 + dt * 16 + khi * 4) = make_float4(v0, v1, v2, v3);
            } else {
                uint2 pk;
                pk.x = (uint)f2bf(v0) | ((uint)f2bf(v1) << 16);
                pk.y = (uint)f2bf(v2) | ((uint)f2bf(v3) << 16);
                *(uint2*)(Yb + (size_t)row[rt] * 128 + dt * 16 + khi * 4) = pk;
            }
        }
    }
}

__global__ __launch_bounds__(256) void gemm_final(
    const ushort* X, const ushort* Wp, const float* beff, float* Yf, int M) {
    gemm_body<8, 1>(blockIdx.x, X, Wp, beff, nullptr, Yf, M);
}

__global__ __launch_bounds__(256) void gemm_dual(
    const ushort* X,
    const ushort* Wp1, const float* beff1, ushort* Y1,
    const ushort* Wp2, const float* beff2, ushort* Y2, int M) {
    const int half = gridDim.x >> 1;
    const bool second = (int)blockIdx.x >= half;
    gemm_body<4, 0>(second ? blockIdx.x - half : blockIdx.x, X,
                    second ? Wp2 : Wp1, second ? beff2 : beff1,
                    second ? Y2 : Y1, nullptr, M);
}

// 4 node GEMMs (no bias/relu): hu@Wp1->HUw, hv@Wp1->HVw, hu@Wp2->HUl, hv@Wp2->HVl
__global__ __launch_bounds__(256) void gemm_quad(
    const ushort* hu, const ushort* hv,
    const ushort* Wp1, const ushort* Wp2,
    ushort* HUw, ushort* HVw, ushort* HUl, ushort* HVl, int M) {
    const int gq = gridDim.x >> 2;
    const int q = blockIdx.x / gq;
    const int b = blockIdx.x - q * gq;
    const ushort* X = (q & 1) ? hv : hu;
    const ushort* Wp = (q >= 2) ? Wp2 : Wp1;
    ushort* Y = (q == 0) ? HUw : (q == 1) ? HVw : (q == 2) ? HUl : HVl;
    gemm_body<4, 2>(b, X, Wp, nullptr, Y, nullptr, M);
}

// ---------------- seg-GEMM: 64-row blocks, fp32 rows gathered via perm, fused segmented mean ----------------
__device__ __forceinline__ void gemm_seg_body(
    int b, const float* __restrict__ XF, const int* __restrict__ perm,
    const int* __restrict__ sdst, const int* __restrict__ cnt,
    const ushort* __restrict__ Wp, const float* __restrict__ beff,
    float* __restrict__ hacc, int M) {
    constexpr int KT = 4;
    __shared__ ushort tile[64 * 132];
    __shared__ int   s_node[64];
    __shared__ float s_scale[64];
    const int tid = threadIdx.x;
    const int lane = tid & 63;
    const int w = tid >> 6;
    const int rb = b * 64;
    const int rlo = lane & 15, khi = lane >> 4;

    if (tid < 64) {
        int r = rb + tid;
        int nd = (r < M) ? sdst[r] : -1;
        s_node[tid] = nd;
        s_scale[tid] = (nd >= 0) ? 0.5f / fmaxf((float)cnt[nd], 1.f) : 0.f;
    }

    f32x4 acc[8];
    #pragma unroll
    for (int dt = 0; dt < 8; ++dt)
        acc[dt] = (f32x4){0.f, 0.f, 0.f, 0.f};

    const int row = rb + w * 16 + rlo;
    const bool ok = row < M;
    const int pidx = ok ? perm[row] : 0;

    for (int kt = 0; kt < KT; ++kt) {
        const float* p = XF + (size_t)pidx * 128 + kt * 32 + khi * 8;
        float4 xa = *(const float4*)p;
        float4 xb = *(const float4*)(p + 4);
        short8 bv;
        bv[0] = (short)f2bf(xa.x); bv[1] = (short)f2bf(xa.y);
        bv[2] = (short)f2bf(xa.z); bv[3] = (short)f2bf(xa.w);
        bv[4] = (short)f2bf(xb.x); bv[5] = (short)f2bf(xb.y);
        bv[6] = (short)f2bf(xb.z); bv[7] = (short)f2bf(xb.w);
        #pragma unroll 4
        for (int dt = 0; dt < 8; ++dt) {
            short8 wf = *(const short8*)(Wp + (size_t)((dt * KT + kt) * 64 + lane) * 8);
            acc[dt] = __builtin_amdgcn_mfma_f32_16x16x32_bf16(wf, bv, acc[dt], 0, 0, 0);
        }
    }

    const int rl = w * 16 + rlo;
    #pragma unroll
    for (int dt = 0; dt < 8; ++dt) {
        const float4 bz = *(const float4*)(beff + dt * 16 + khi * 4);
        float v0 = 0.f, v1 = 0.f, v2 = 0.f, v3 = 0.f;
        if (ok) {
            v0 = fmaxf(acc[dt][0] + bz.x, 0.f);
            v1 = fmaxf(acc[dt][1] + bz.y, 0.f);
            v2 = fmaxf(acc[dt][2] + bz.z, 0.f);
            v3 = fmaxf(acc[dt][3] + bz.w, 0.f);
        }
        uint2 pk;
        pk.x = (uint)f2bf(v0) | ((uint)f2bf(v1) << 16);
        pk.y = (uint)f2bf(v2) | ((uint)f2bf(v3) << 16);
        *(uint2*)&tile[rl * 132 + dt * 16 + khi * 4] = pk;
    }
    __syncthreads();

    const int col = tid & 127;
    const int rs = (tid >> 7) * 32;
    int cur = s_node[rs];
    float scl = s_scale[rs];
    float sum = 0.f;
    for (int r = rs; r < rs + 32; ++r) {
        int nd = s_node[r];
        if (nd != cur) {
            if (cur >= 0)
                atomicAdd(&hacc[(size_t)cur * 128 + col], sum * scl);
            cur = nd; scl = s_scale[r]; sum = 0.f;
        }
        sum += bf2f(tile[r * 132 + col]);
    }
    if (cur >= 0)
        atomicAdd(&hacc[(size_t)cur * 128 + col], sum * scl);
}

__global__ __launch_bounds__(256) void gemm_seg2(
    const float* XA, const int* permA, const int* sdstA, const int* cntA,
    const ushort* WpA, const float* beffA, int MA,
    const float* XB, const int* permB, const int* sdstB, const int* cntB,
    const ushort* WpB, const float* beffB, int MB,
    float* hacc) {
    const int half = gridDim.x >> 1;
    const bool second = (int)blockIdx.x >= half;
    gemm_seg_body(second ? blockIdx.x - half : blockIdx.x,
                  second ? XB : XA, second ? permB : permA,
                  second ? sdstB : sdstA, second ? cntB : cntA,
                  second ? WpB : WpA, second ? beffB : beffA,
                  hacc, second ? MB : MA);
}

// ---------------- edge gather-add-relu + segmented mean (dual, run-hoisted HV) ----------------
__global__ __launch_bounds__(256) void edge_seg2(
    const uint* __restrict__ HUw, const uint* __restrict__ HVw,
    const int* __restrict__ sw, const int* __restrict__ dw,
    const int* __restrict__ cw, const float* __restrict__ bw,
    const uint* __restrict__ HUl, const uint* __restrict__ HVl,
    const int* __restrict__ sl, const int* __restrict__ dl,
    const int* __restrict__ cl, const float* __restrict__ bl,
    float* __restrict__ hacc, int E) {
    const int gh = gridDim.x >> 1;
    const bool second = (int)blockIdx.x >= gh;
    const uint* HU = second ? HUl : HUw;
    const uint* HV = second ? HVl : HVw;
    const int* sidx = second ? sl : sw;
    const int* didx = second ? dl : dw;
    const int* cnt = second ? cl : cw;
    const float* beff = second ? bl : bw;
    const int b = second ? blockIdx.x - gh : blockIdx.x;

    const int lane = threadIdx.x & 63;
    const int gwave = (b * 256 + threadIdx.x) >> 6;
    const int nwave = (gh * 256) >> 6;
    const float bz0 = beff[2 * lane];
    const float bz1 = beff[2 * lane + 1];

    for (int base = gwave * 64; base < E; base += nwave * 64) {
        int e = base + lane;
        int su = (e < E) ? sidx[e] : 0;
        int dv = (e < E) ? didx[e] : 0;
        int cn = min(64, E - base);
        int cur = -1; float scl = 0.f, a0 = 0.f, a1 = 0.f, hv0 = 0.f, hv1 = 0.f;
        auto body = [&](int j) {
            int aa = __shfl(su, j), dd = __shfl(dv, j);
            if (dd != cur) {
                if (cur >= 0) {
                    atomicAdd(&hacc[(size_t)cur * 128 + 2 * lane],     a0 * scl);
                    atomicAdd(&hacc[(size_t)cur * 128 + 2 * lane + 1], a1 * scl);
                }
                cur = dd; scl = 0.5f / fmaxf((float)cnt[dd], 1.f); a0 = 0.f; a1 = 0.f;
                uint vv = HV[(size_t)dd * 64 + lane];
                hv0 = bf2f(vv & 0xffffu); hv1 = bf2f(vv >> 16);
            }
            uint uu = HU[(size_t)aa * 64 + lane];
            a0 += fmaxf(bf2f(uu & 0xffffu) + hv0 + bz0, 0.f);
            a1 += fmaxf(bf2f(uu >> 16)     + hv1 + bz1, 0.f);
        };
        if (cn == 64) {
            #pragma unroll 4
            for (int j = 0; j < 64; ++j) body(j);
        } else {
            for (int j = 0; j < cn; ++j) body(j);
        }
        if (cur >= 0) {
            atomicAdd(&hacc[(size_t)cur * 128 + 2 * lane],     a0 * scl);
            atomicAdd(&hacc[(size_t)cur * 128 + 2 * lane + 1], a1 * scl);
        }
    }
}

// ---------------- hacc -> bf16 h (+fh half) + fused column stats, re-zero hacc ----------------
__global__ __launch_bounds__(256) void finalize_hacc_stats(
    float2* __restrict__ hacc2, uint* __restrict__ h2, uint* __restrict__ fh2,
    int fhsel, int N,
    float* __restrict__ psA, float* __restrict__ pqA, int strideA, int offA,
    float* __restrict__ psB, float* __restrict__ pqB, int strideB, int offB) {
    const int cl = threadIdx.x & 63;
    const int sub = threadIdx.x >> 6;
    float s0=0,s1=0,q0=0,q1=0;
    for (int n = blockIdx.x * 4 + sub; n < N; n += gridDim.x * 4) {
        int i = n * 64 + cl;
        float2 v = hacc2[i];
        uint pk = (uint)f2bf(v.x) | ((uint)f2bf(v.y) << 16);
        h2[i] = pk;
        if (fhsel >= 0) fh2[(size_t)n * 128 + fhsel * 64 + cl] = pk;
        hacc2[i] = make_float2(0.f, 0.f);
        s0 += v.x; q0 += v.x * v.x;
        s1 += v.y; q1 += v.y * v.y;
    }
    __shared__ float red[4][64][4];
    red[sub][cl][0]=s0; red[sub][cl][1]=s1; red[sub][cl][2]=q0; red[sub][cl][3]=q1;
    __syncthreads();
    if (sub == 0) {
        #pragma unroll
        for (int k = 1; k < 4; ++k) {
            s0 += red[k][cl][0]; s1 += red[k][cl][1];
            q0 += red[k][cl][2]; q1 += red[k][cl][3];
        }
        psA[(size_t)blockIdx.x * strideA + offA + 2*cl]     = s0;
        psA[(size_t)blockIdx.x * strideA + offA + 2*cl + 1] = s1;
        pqA[(size_t)blockIdx.x * strideA + offA + 2*cl]     = q0;
        pqA[(size_t)blockIdx.x * strideA + offA + 2*cl + 1] = q1;
        if (psB) {
            psB[(size_t)blockIdx.x * strideB + offB + 2*cl]     = s0;
            psB[(size_t)blockIdx.x * strideB + offB + 2*cl + 1] = s1;
            pqB[(size_t)blockIdx.x * strideB + offB + 2*cl]     = q0;
            pqB[(size_t)blockIdx.x * strideB + offB + 2*cl + 1] = q1;
        }
    }
}

// ---------------- launch ----------------
extern "C" void kernel_launch(void* const* d_in, const int* in_sizes, int n_in,
                              void* d_out, int out_size, void* d_ws, size_t ws_size,
                              hipStream_t stream) {
    const float* win_f  = (const float*)d_in[0];
    const float* loss_f = (const float*)d_in[1];
    struct BP { const float *g, *b, *W, *bias; };
    auto bp = [&](int i) { return BP{ (const float*)d_in[i], (const float*)d_in[i+1],
                                      (const float*)d_in[i+2], (const float*)d_in[i+3] }; };
    BP wi = bp(2), li = bp(6), srcp = bp(10), dstp = bp(14), wl = bp(18), ll = bp(22), outp = bp(26);
    const int* win_src  = (const int*)d_in[30];
    const int* win_dst  = (const int*)d_in[31];
    const int* loss_src = (const int*)d_in[32];
    const int* loss_dst = (const int*)d_in[33];
    const int E = in_sizes[30];
    const int N = out_size / 128;
    (void)n_in;

    char* base = (char*)d_ws;
    size_t off_b = 0;
    auto alloc = [&](size_t bytes) {
        size_t cur = off_b;
        off_b += (bytes + 255) & ~(size_t)255;
        return (void*)(base + cur);
    };
    float*  hacc = (float*)alloc((size_t)N * 128 * 4);
    ushort* h    = (ushort*)alloc((size_t)N * 128 * 2);
    ushort* hu   = (ushort*)alloc((size_t)N * 128 * 2);
    ushort* hv   = (ushort*)alloc((size_t)N * 128 * 2);
    ushort* fh   = (ushort*)alloc((size_t)N * 256 * 2);
    ushort* HUw  = (ushort*)alloc((size_t)N * 128 * 2);
    ushort* HVw  = (ushort*)alloc((size_t)N * 128 * 2);
    ushort* HUl  = (ushort*)alloc((size_t)N * 128 * 2);
    ushort* HVl  = (ushort*)alloc((size_t)N * 128 * 2);
    int* cntw  = (int*)alloc((size_t)N * 4);
    int* cntl  = (int*)alloc((size_t)N * 4);
    int* offw  = (int*)alloc((size_t)(N + 1) * 4);
    int* offl  = (int*)alloc((size_t)(N + 1) * 4);
    int* curw  = (int*)alloc((size_t)N * 4);
    int* curl  = (int*)alloc((size_t)N * 4);
    int* permw = (int*)alloc((size_t)E * 4);
    int* ssrcw = (int*)alloc((size_t)E * 4);
    int* sdstw = (int*)alloc((size_t)E * 4);
    int* perml = (int*)alloc((size_t)E * 4);
    int* ssrcl = (int*)alloc((size_t)E * 4);
    int* sdstl = (int*)alloc((size_t)E * 4);
    float* psumW = (float*)alloc((size_t)NPART_MAX * 128 * 4);
    float* psqW  = (float*)alloc((size_t)NPART_MAX * 128 * 4);
    float* psumL = (float*)alloc((size_t)NPART_MAX * 128 * 4);
    float* psqL  = (float*)alloc((size_t)NPART_MAX * 128 * 4);
    float* psumN = (float*)alloc((size_t)512 * 128 * 4);
    float* psqN  = (float*)alloc((size_t)512 * 128 * 4);
    float* psum256 = (float*)alloc((size_t)512 * 256 * 4);
    float* psq256  = (float*)alloc((size_t)512 * 256 * 4);
    float* scal1 = (float*)alloc(256 * 4);
    float* shif1 = (float*)alloc(256 * 4);
    float* scal2 = (float*)alloc(256 * 4);
    float* shif2 = (float*)alloc(256 * 4);
    ushort* Wp1 = (ushort*)alloc((size_t)256 * 128 * 2);
    ushort* Wp2 = (ushort*)alloc((size_t)256 * 128 * 2);
    float* beff1 = (float*)alloc(128 * 4);
    float* beff2 = (float*)alloc(128 * 4);
    if (off_b > ws_size) return;   // workspace must fit

    const int gE64 = (E + 63) / 64;
    const int gN = (N + 127) / 128;
    const int NBF = 1024;   // fp32-stats blocks per etype
    const int NBG = 2048;   // gather/edge blocks per etype
    const int NBN = 512;    // finalize/stats blocks

    // phase 0: counting sort (both etypes)
    hipMemsetAsync(cntw, 0, (size_t)N * 4, stream);
    hipMemsetAsync(cntl, 0, (size_t)N * 4, stream);
    hipMemsetAsync(hacc, 0, (size_t)N * 128 * 4, stream);
    hist2<<<2048, 256, 0, stream>>>(win_dst, loss_dst, E, cntw, cntl);
    scan2<<<2, 256, 0, stream>>>(cntw, cntl, N, offw, curw, offl, curl);
    scatter2<<<2048, 256, 0, stream>>>(win_src, win_dst, loss_src, loss_dst, E,
                                       curw, curl, permw, ssrcw, sdstw, perml, ssrcl, sdstl);

    // initial edge blocks: linear fp32 stats + fp32-gather seg-GEMM
    stats_f32_2<<<2 * NBF, 256, 0, stream>>>(
        (const float4*)win_f, psumW, psqW,
        (const float4*)loss_f, psumL, psqL, E);
    reduce_stats2<<<256, 256, 0, stream>>>(
        psumW, psqW, NBF, 128, E, wi.g, wi.b, scal1, shif1,
        psumL, psqL, NBF, 128, E, li.g, li.b, scal2, shif2);
    pack_fold2<<<24, 256, 0, stream>>>(scal1, shif1, 128, wi.W, wi.bias, Wp1, beff1,
                                       scal2, shif2, 128, li.W, li.bias, Wp2, beff2);
    gemm_seg2<<<2 * gE64, 256, 0, stream>>>(
        win_f, permw, sdstw, cntw, Wp1, beff1, E,
        loss_f, perml, sdstl, cntl, Wp2, beff2, E, hacc);
    // finalize: h + fh(f-half) + h-stats (for iter0) + f-half stats (for final layer)
    finalize_hacc_stats<<<NBN, 256, 0, stream>>>(
        (float2*)hacc, (uint*)h, (uint*)fh, 0, N,
        psumN, psqN, 128, 0, psum256, psq256, 256, 0);

    for (int it = 0; it < 3; ++it) {
        reduce_stats<<<128, 256, 0, stream>>>(psumN, psqN, NBN, 128, N, srcp.g, srcp.b, scal1, shif1,
                                              dstp.g, dstp.b, scal2, shif2);
        pack_fold2<<<24, 256, 0, stream>>>(scal1, shif1, 128, srcp.W, srcp.bias, Wp1, beff1,
                                           scal2, shif2, 128, dstp.W, dstp.bias, Wp2, beff2);
        gemm_dual<<<2 * gN, 256, 0, stream>>>(h, Wp1, beff1, hu, Wp2, beff2, hv, N);

        gather_stats2<<<2 * NBG, 256, 0, stream>>>(
            (const uint2*)hu, (const uint2*)hv,
            ssrcw, sdstw, psumW, psqW, ssrcl, sdstl, psumL, psqL, E);
        reduce_stats2<<<256, 256, 0, stream>>>(
            psumW, psqW, NBG, 128, E, wl.g, wl.b, scal1, shif1,
            psumL, psqL, NBG, 128, E, ll.g, ll.b, scal2, shif2);
        pack_fold2<<<24, 256, 0, stream>>>(scal1, shif1, 128, wl.W, wl.bias, Wp1, beff1,
                                           scal2, shif2, 128, ll.W, ll.bias, Wp2, beff2);
        gemm_quad<<<4 * gN, 256, 0, stream>>>(hu, hv, Wp1, Wp2, HUw, HVw, HUl, HVl, N);
        edge_seg2<<<2 * NBG, 256, 0, stream>>>(
            (const uint*)HUw, (const uint*)HVw, ssrcw, sdstw, cntw, beff1,
            (const uint*)HUl, (const uint*)HVl, ssrcl, sdstl, cntl, beff2,
            hacc, E);
        if (it < 2) {
            finalize_hacc_stats<<<NBN, 256, 0, stream>>>(
                (float2*)hacc, (uint*)h, (uint*)fh, -1, N,
                psumN, psqN, 128, 0, nullptr, nullptr, 0, 0);
        } else {
            finalize_hacc_stats<<<NBN, 256, 0, stream>>>(
                (float2*)hacc, (uint*)h, (uint*)fh, 1, N,
                psum256, psq256, 256, 128, nullptr, nullptr, 0, 0);
        }
    }

    reduce_stats<<<256, 256, 0, stream>>>(psum256, psq256, NBN, 256, N, outp.g, outp.b, scal1, shif1,
                                          nullptr, nullptr, nullptr, nullptr);
    pack_fold_par<<<16, 256, 0, stream>>>(scal1, shif1, 256, outp.W, outp.bias, Wp1, beff1);
    gemm_final<<<gN, 256, 0, stream>>>(fh, Wp1, beff1, (float*)d_out, N);
}